// Round 2
// baseline (1315.252 us; speedup 1.0000x reference)
//
#include <hip/hip_runtime.h>
#include <hip/hip_bf16.h>

#define Ee 1024
#define Hh 16
#define Ff 4608
#define Ll 4096
#define Bb 2
#define NCc 16
#define CHk 256

typedef short bf16x8 __attribute__((ext_vector_type(8)));
typedef float f32x4 __attribute__((ext_vector_type(4)));

__device__ __forceinline__ unsigned short f2bf(float f){
  unsigned int u = __builtin_bit_cast(unsigned int, f);
  u += 0x7fffu + ((u >> 16) & 1u);
  return (unsigned short)(u >> 16);
}
__device__ __forceinline__ float bf2f(unsigned short h){
  unsigned int u = ((unsigned int)h) << 16;
  return __builtin_bit_cast(float, u);
}
__device__ __forceinline__ float fixv(float v){
  return (__builtin_isnan(v) || __builtin_isinf(v)) ? 0.f : v;
}

// ---------------- RMSNorm fp32 in -> bf16 out ----------------
__global__ __launch_bounds__(256) void rmsnorm_kernel(const float* __restrict__ x,
    const float* __restrict__ g, unsigned short* __restrict__ out){
  int row = blockIdx.x; int t = threadIdx.x;
  float4 v = ((const float4*)(x + (size_t)row*Ee))[t];
  v.x=fixv(v.x); v.y=fixv(v.y); v.z=fixv(v.z); v.w=fixv(v.w);
  float ss = v.x*v.x + v.y*v.y + v.z*v.z + v.w*v.w;
  #pragma unroll
  for (int off=32; off>0; off>>=1) ss += __shfl_down(ss, off);
  __shared__ float red[4];
  if ((t&63)==0) red[t>>6] = ss;
  __syncthreads();
  float tot = red[0]+red[1]+red[2]+red[3];
  float rms = sqrtf(tot*(1.f/Ee) + 1e-6f);
  rms = fminf(fmaxf(rms, 1e-6f), 1e6f);
  float inv = 1.f/rms;
  float4 gv = ((const float4*)g)[t];
  uint2 o;
  o.x = (unsigned)f2bf(v.x*inv*gv.x) | ((unsigned)f2bf(v.y*inv*gv.y)<<16);
  o.y = (unsigned)f2bf(v.z*inv*gv.z) | ((unsigned)f2bf(v.w*inv*gv.w)<<16);
  ((uint2*)(out + (size_t)row*Ee))[t] = o;
}

// ---------------- bf16-A GEMM: C[M,N] = A @ B ----------------
// MODE 0: C bf16, no residual (qkv).
// MODE 1: C fp32 = acc + res (out-proj).
// MODE 2: A scaled by rowscale[m]*colscale[k]; C fp32 = acc + res (down-proj).
template<int MODE>
__global__ __launch_bounds__(256) void gemm_kernel(
    const unsigned short* __restrict__ A, const float* __restrict__ Bm,
    void* __restrict__ Cv, int M, int N, int K,
    const float* __restrict__ res, const float* __restrict__ rowscale,
    const float* __restrict__ colscale){
  __shared__ __align__(16) unsigned short As[128][40];
  __shared__ __align__(16) unsigned short Bs[128][40];
  int tid = threadIdx.x;
  int m0 = blockIdx.y*128, n0 = blockIdx.x*128;
  int lane = tid & 63, wave = tid >> 6;
  int wm = (wave>>1)*64, wn = (wave&1)*64;
  int lrow = lane & 15, lk = (lane>>4)*8;
  f32x4 acc[4][4] = {};
  int arow = tid>>2, acolg = (tid&3)*8;
  int brow = tid>>3, bcol = (tid&7)*16;
  float rs0 = 1.f, rs1 = 1.f;
  if (MODE==2){ rs0 = rowscale[m0+arow]; rs1 = rowscale[m0+arow+64]; }
  for (int k0=0; k0<K; k0+=32){
    #pragma unroll
    for (int p=0;p<2;p++){
      int r = arow + p*64;
      bf16x8 av = *(const bf16x8*)(A + (size_t)(m0+r)*K + k0 + acolg);
      if (MODE==2){
        float rs = p ? rs1 : rs0;
        #pragma unroll
        for (int j=0;j<8;j++){
          float f = bf2f((unsigned short)av[j]) * rs * colscale[k0+acolg+j];
          av[j] = (short)f2bf(f);
        }
      }
      *(bf16x8*)&As[r][acolg] = av;
    }
    const float* bs = Bm + (size_t)(k0+brow)*N + n0 + bcol;
    #pragma unroll
    for (int i=0;i<16;i+=4){
      float4 v = *(const float4*)(bs + i);
      Bs[bcol+i+0][brow] = f2bf(v.x);
      Bs[bcol+i+1][brow] = f2bf(v.y);
      Bs[bcol+i+2][brow] = f2bf(v.z);
      Bs[bcol+i+3][brow] = f2bf(v.w);
    }
    __syncthreads();
    bf16x8 af[4], bfr[4];
    #pragma unroll
    for (int i=0;i<4;i++){
      af[i]  = *(const bf16x8*)&As[wm + i*16 + lrow][lk];
      bfr[i] = *(const bf16x8*)&Bs[wn + i*16 + lrow][lk];
    }
    #pragma unroll
    for (int mi=0;mi<4;mi++)
      #pragma unroll
      for (int ni=0;ni<4;ni++)
        acc[mi][ni] = __builtin_amdgcn_mfma_f32_16x16x32_bf16(af[mi], bfr[ni], acc[mi][ni], 0,0,0);
    __syncthreads();
  }
  int rbase = m0 + wm + ((lane>>4)<<2);
  int cbase = n0 + wn + (lane&15);
  #pragma unroll
  for (int mi=0;mi<4;mi++){
    #pragma unroll
    for (int r=0;r<4;r++){
      int row = rbase + mi*16 + r;
      #pragma unroll
      for (int ni=0;ni<4;ni++){
        int col = cbase + ni*16;
        float v = acc[mi][ni][r];
        if (MODE==0){
          ((unsigned short*)Cv)[(size_t)row*N + col] = f2bf(v);
        } else {
          ((float*)Cv)[(size_t)row*N + col] = v + res[(size_t)row*N + col];
        }
      }
    }
  }
}

// ---------------- RoPE + ELU+1 on q,k in bf16 qkv ----------------
__global__ __launch_bounds__(256) void rope_kernel(unsigned short* __restrict__ qkv){
  size_t idx = (size_t)blockIdx.x*256 + threadIdx.x;    // B*L*H*32
  int i = (int)(idx & 31);
  int h = (int)((idx>>5) & 15);
  size_t bl = idx >> 9;
  int pos = (int)(bl & (Ll-1));
  int d0 = 2*i, d1 = d0+1;
  size_t base = bl*3072 + (size_t)h*64 + d0;
  const float LOG1E4_D32 = 0.2878231366242557f;  // ln(10000)/32
  float e0 = (float)(d0 < 32 ? d0 : d0-32);
  float e1 = (float)(d1 < 32 ? d1 : d1-32);
  float f0 = pos * expf(-e0*LOG1E4_D32);
  float f1 = pos * expf(-e1*LOG1E4_D32);
  float s0,c0,s1,c1;
  sincosf(f0,&s0,&c0); sincosf(f1,&s1,&c1);
  unsigned int* qp = (unsigned int*)(qkv + base);
  unsigned int qv = *qp;
  float q0 = bf2f((unsigned short)(qv&0xffff)), q1 = bf2f((unsigned short)(qv>>16));
  float r0 = q0*c0 - q1*s0;
  float r1 = q1*c1 + q0*s1;
  r0 = r0>0.f ? r0+1.f : expf(r0);
  r1 = r1>0.f ? r1+1.f : expf(r1);
  *qp = (unsigned)f2bf(r0) | ((unsigned)f2bf(r1)<<16);
  unsigned int* kp = (unsigned int*)(qkv + base + 1024);
  unsigned int kv = *kp;
  float k0v = bf2f((unsigned short)(kv&0xffff)), k1v = bf2f((unsigned short)(kv>>16));
  float t0 = k0v*c0 - k1v*s0;
  float t1 = k1v*c1 + k0v*s1;
  t0 = t0>0.f ? t0+1.f : expf(t0);
  t1 = t1>0.f ? t1+1.f : expf(t1);
  *kp = (unsigned)f2bf(t0) | ((unsigned)f2bf(t1)<<16);
}

// ---------------- per-chunk K^T V (64x64) + K col sums; 2-pass LDS ----------------
__global__ __launch_bounds__(256) void chunksum_kernel(const unsigned short* __restrict__ qkv,
    float* __restrict__ Ssum){
  int c = blockIdx.x, bh = blockIdx.y;
  int b = bh >> 4, h = bh & 15;
  __shared__ __align__(16) unsigned short Ks[128][64];
  __shared__ __align__(16) unsigned short Vs[128][64];
  int t = threadIdx.x;
  int j = t >> 2, dg = (t&3)*16;
  float acc[16] = {}; float zacc = 0.f;
  for (int p=0;p<2;p++){
    __syncthreads();
    #pragma unroll
    for (int it=0; it<4; it++){
      int flat = it*256 + t;
      int row = flat >> 3, colg = (flat & 7)*8;
      size_t g = ((size_t)(b*Ll + c*CHk + p*128 + row))*3072 + h*64 + colg;
      *(bf16x8*)&Ks[row][colg] = *(const bf16x8*)(qkv + g + 1024);
      *(bf16x8*)&Vs[row][colg] = *(const bf16x8*)(qkv + g + 2048);
    }
    __syncthreads();
    for (int m=0;m<128;m++){
      float kv = bf2f(Ks[m][j]);
      zacc += kv;
      #pragma unroll
      for (int q8=0;q8<2;q8++){
        bf16x8 vv = *(const bf16x8*)&Vs[m][dg + q8*8];
        #pragma unroll
        for (int u=0;u<8;u++) acc[q8*8+u] += kv * bf2f((unsigned short)vv[u]);
      }
    }
  }
  float* S = Ssum + ((size_t)bh*NCc + c)*4160;
  #pragma unroll
  for (int d=0;d<16;d++) S[j*64 + dg + d] = acc[d];
  if ((t&3)==0) S[4096 + j] = zacc;
}

// ---------------- exclusive prefix over chunks ----------------
__global__ __launch_bounds__(256) void prefix_kernel(const float* __restrict__ Ssum,
    float* __restrict__ Spre){
  int bh = blockIdx.x; int t = threadIdx.x;
  size_t base = (size_t)bh*NCc*4160;
  for (int e=t; e<4160; e+=256){
    float acc = 0.f;
    #pragma unroll
    for (int c=0;c<NCc;c++){
      Spre[base + (size_t)c*4160 + e] = acc;
      acc += Ssum[base + (size_t)c*4160 + e];
    }
  }
}

// ---------------- per-chunk causal attention; 2-pass LDS ----------------
__global__ __launch_bounds__(256) void attnout_kernel(const unsigned short* __restrict__ qkv,
    const float* __restrict__ Spre, unsigned short* __restrict__ attn){
  int c = blockIdx.x, bh = blockIdx.y;
  int b = bh >> 4, h = bh & 15;
  __shared__ __align__(16) unsigned short Ks[128][64];
  __shared__ __align__(16) unsigned short Vs[128][64];
  int t = threadIdx.x;
  int wave = t >> 6;
  float q[64];
  size_t qg = ((size_t)(b*Ll + c*CHk + t))*3072 + (size_t)h*64;
  #pragma unroll
  for (int g8=0; g8<8; g8++){
    bf16x8 v = *(const bf16x8*)(qkv + qg + g8*8);
    #pragma unroll
    for (int u=0;u<8;u++) q[g8*8+u] = bf2f((unsigned short)v[u]);
  }
  const float* Sp = Spre + ((size_t)bh*NCc + c)*4160;
  float num[64];
  #pragma unroll
  for (int d=0;d<64;d++) num[d]=0.f;
  for (int j=0;j<64;j++){
    float qj = q[j];
    const float* Sr = Sp + j*64;
    #pragma unroll
    for (int d4=0; d4<16; d4++){
      float4 sv = *(const float4*)(Sr + d4*4);
      num[d4*4+0] += qj*sv.x; num[d4*4+1] += qj*sv.y;
      num[d4*4+2] += qj*sv.z; num[d4*4+3] += qj*sv.w;
    }
  }
  float den = 0.f;
  #pragma unroll
  for (int j=0;j<64;j++) den += q[j]*Sp[4096+j];
  for (int p=0;p<2;p++){
    __syncthreads();
    #pragma unroll
    for (int it=0; it<4; it++){
      int flat = it*256 + t;
      int row = flat >> 3, colg = (flat & 7)*8;
      size_t g = ((size_t)(b*Ll + c*CHk + p*128 + row))*3072 + h*64 + colg;
      *(bf16x8*)&Ks[row][colg] = *(const bf16x8*)(qkv + g + 1024);
      *(bf16x8*)&Vs[row][colg] = *(const bf16x8*)(qkv + g + 2048);
    }
    __syncthreads();
    int wtop = wave*64 + 63;
    if (wtop >= p*128){
      int wlim = wtop - p*128; if (wlim > 127) wlim = 127;
      int lim = t - p*128;
      for (int m=0; m<=wlim; m++){
        float qk = 0.f;
        #pragma unroll
        for (int g8=0; g8<8; g8++){
          bf16x8 kv8 = *(const bf16x8*)&Ks[m][g8*8];
          #pragma unroll
          for (int u=0;u<8;u++) qk += q[g8*8+u]*bf2f((unsigned short)kv8[u]);
        }
        float qkm = (m <= lim) ? qk : 0.f;
        den += qkm;
        #pragma unroll
        for (int g8=0; g8<8; g8++){
          bf16x8 vv8 = *(const bf16x8*)&Vs[m][g8*8];
          #pragma unroll
          for (int u=0;u<8;u++) num[g8*8+u] += qkm*bf2f((unsigned short)vv8[u]);
        }
      }
    }
  }
  den = fmaxf(den, 1e-6f);
  float inv = 1.f/den;
  unsigned short* o = attn + ((size_t)(b*Ll + c*CHk + t))*Ee + (size_t)h*64;
  #pragma unroll
  for (int g8=0; g8<8; g8++){
    bf16x8 ov;
    #pragma unroll
    for (int u=0;u<8;u++) ov[u] = (short)f2bf(num[g8*8+u]*inv);
    *(bf16x8*)(o + g8*8) = ov;
  }
}

// ---------------- column mean over L (bf16 in, fp32 atomic out) ----------------
__global__ __launch_bounds__(256) void colmean_kernel(const unsigned short* __restrict__ h2,
    float* __restrict__ xmean){
  int e = blockIdx.x*256 + threadIdx.x;
  int b = blockIdx.z;
  int l0 = blockIdx.y * 128;
  float s = 0.f;
  for (int l=l0; l<l0+128; l++) s += bf2f(h2[((size_t)(b*Ll + l))*Ee + e]);
  atomicAdd(&xmean[b*Ee + e], s * (1.f/Ll));
}

// ---------------- dim predictor -> floored size ----------------
__global__ __launch_bounds__(256) void dimpred_kernel(const float* __restrict__ xmean,
    const float* __restrict__ w_dp1, const float* __restrict__ w_dp2,
    float* __restrict__ scalars){
  __shared__ float red[256];
  __shared__ float ratio_s[2];
  int t = threadIdx.x;
  for (int b=0;b<2;b++){
    float s = 0.f;
    for (int k=0;k<1024;k++) s += xmean[b*Ee + k] * w_dp1[k*256 + t];
    float sil = s * (1.f/(1.f+expf(-s)));
    red[t] = sil * w_dp2[t];
    __syncthreads();
    for (int off=128; off>0; off>>=1){
      if (t<off) red[t] += red[t+off];
      __syncthreads();
    }
    if (t==0){
      float dr = 1.f/(1.f+expf(-red[0]));
      float ratio = 1.f + (dr-0.5f)*1.0f;       // 2*ADAPT = 1
      ratio = fminf(fmaxf(ratio, 0.5f), 1.5f);
      ratio_s[b] = ratio;
    }
    __syncthreads();
  }
  if (t==0){
    float rm = 0.5f*(ratio_s[0]+ratio_s[1]);
    float size_f = floorf(3072.f * rm);
    if (size_f < 1.f) size_f = 1.f;
    scalars[0] = size_f;
  }
}

// ---------------- fused gate+up GEMM -> hidden = silu(g)*u (masked) ----------------
__global__ __launch_bounds__(256) void gateup_kernel(
    const unsigned short* __restrict__ A, const float* __restrict__ Bg_,
    const float* __restrict__ Bu_, unsigned short* __restrict__ Hid,
    const float* __restrict__ scal){
  __shared__ __align__(16) unsigned short As[128][40];
  __shared__ __align__(16) unsigned short Bg[64][40];
  __shared__ __align__(16) unsigned short Bu[64][40];
  int tid = threadIdx.x;
  int n0 = blockIdx.x*64, m0 = blockIdx.y*128;
  int lane = tid & 63, wave = tid >> 6;
  int wm = (wave>>1)*64, wn = (wave&1)*32;
  int lrow = lane & 15, lk = (lane>>4)*8;
  f32x4 ag[4][2] = {}, au[4][2] = {};
  int arow = tid>>2, acolg = (tid&3)*8;
  int brow = tid>>3, bcol = (tid&7)*8;
  for (int k0=0; k0<1024; k0+=32){
    #pragma unroll
    for (int p=0;p<2;p++){
      int r = arow + p*64;
      *(bf16x8*)&As[r][acolg] = *(const bf16x8*)(A + (size_t)(m0+r)*Ee + k0 + acolg);
    }
    {
      const float* bg = Bg_ + (size_t)(k0+brow)*Ff + n0 + bcol;
      const float* bu = Bu_ + (size_t)(k0+brow)*Ff + n0 + bcol;
      #pragma unroll
      for (int i=0;i<8;i+=4){
        float4 vg = *(const float4*)(bg + i);
        Bg[bcol+i+0][brow] = f2bf(vg.x); Bg[bcol+i+1][brow] = f2bf(vg.y);
        Bg[bcol+i+2][brow] = f2bf(vg.z); Bg[bcol+i+3][brow] = f2bf(vg.w);
        float4 vu = *(const float4*)(bu + i);
        Bu[bcol+i+0][brow] = f2bf(vu.x); Bu[bcol+i+1][brow] = f2bf(vu.y);
        Bu[bcol+i+2][brow] = f2bf(vu.z); Bu[bcol+i+3][brow] = f2bf(vu.w);
      }
    }
    __syncthreads();
    bf16x8 af[4], bg2[2], bu2[2];
    #pragma unroll
    for (int i=0;i<4;i++) af[i] = *(const bf16x8*)&As[wm + i*16 + lrow][lk];
    #pragma unroll
    for (int i=0;i<2;i++){
      bg2[i] = *(const bf16x8*)&Bg[wn + i*16 + lrow][lk];
      bu2[i] = *(const bf16x8*)&Bu[wn + i*16 + lrow][lk];
    }
    #pragma unroll
    for (int mi=0;mi<4;mi++)
      #pragma unroll
      for (int ni=0;ni<2;ni++){
        ag[mi][ni] = __builtin_amdgcn_mfma_f32_16x16x32_bf16(af[mi], bg2[ni], ag[mi][ni], 0,0,0);
        au[mi][ni] = __builtin_amdgcn_mfma_f32_16x16x32_bf16(af[mi], bu2[ni], au[mi][ni], 0,0,0);
      }
    __syncthreads();
  }
  int size = (int)scal[0];
  int rbase = m0 + wm + ((lane>>4)<<2);
  int cbase = n0 + wn + (lane&15);
  #pragma unroll
  for (int mi=0;mi<4;mi++){
    #pragma unroll
    for (int r=0;r<4;r++){
      int row = rbase + mi*16 + r;
      #pragma unroll
      for (int ni=0;ni<2;ni++){
        int col = cbase + ni*16;
        float g = ag[mi][ni][r], u = au[mi][ni][r];
        float hv = (g * (1.f/(1.f+expf(-g)))) * u;
        if (col >= size) hv = 0.f;
        if (__builtin_isnan(hv) || __builtin_isinf(hv)) hv = 0.f;
        Hid[(size_t)row*Ff + col] = f2bf(hv);
      }
    }
  }
}

// ---------------- per-row sumsq of hidden -> inv_rms ----------------
__global__ __launch_bounds__(256) void rowrms_kernel(const unsigned short* __restrict__ Hid,
    const float* __restrict__ scal, float* __restrict__ invr){
  int row = blockIdx.x; int t = threadIdx.x;
  float ss = 0.f;
  for (int c8 = t; c8 < Ff/8; c8 += 256){
    bf16x8 v = *(const bf16x8*)(Hid + (size_t)row*Ff + c8*8);
    #pragma unroll
    for (int u=0;u<8;u++){ float f = bf2f((unsigned short)v[u]); ss += f*f; }
  }
  #pragma unroll
  for (int off=32; off>0; off>>=1) ss += __shfl_down(ss, off);
  __shared__ float red[4];
  if ((t&63)==0) red[t>>6] = ss;
  __syncthreads();
  if (t==0){
    float tot = red[0]+red[1]+red[2]+red[3];
    float rms = sqrtf(tot/scal[0] + 1e-6f);
    rms = fminf(fmaxf(rms, 1e-6f), 1e6f);
    invr[row] = 1.f/rms;
  }
}

extern "C" void kernel_launch(void* const* d_in, const int* in_sizes, int n_in,
                              void* d_out, int out_size, void* d_ws, size_t ws_size,
                              hipStream_t stream){
  const float* x      = (const float*)d_in[0];
  const float* w_qkv  = (const float*)d_in[1];
  const float* w_out  = (const float*)d_in[2];
  const float* g1     = (const float*)d_in[3];
  const float* g2     = (const float*)d_in[4];
  const float* w_dp1  = (const float*)d_in[5];
  const float* w_dp2  = (const float*)d_in[6];
  const float* w_gate = (const float*)d_in[7];
  const float* w_up   = (const float*)d_in[8];
  const float* w_down = (const float*)d_in[9];
  const float* g_hid  = (const float*)d_in[10];
  float* out = (float*)d_out;

  // ws layout (bytes), total ~125.9 MB:
  // R1 (16 MB): h -> attn -> h2 (bf16, lifetimes disjoint)
  // x2 (32 MB fp32)
  // R2 (72 MB): [qkv bf16 48MB | Ssum 8.1MB | Spre 8.1MB] then hidden bf16 72MB
  char* w = (char*)d_ws;
  unsigned short* R1 = (unsigned short*)w;
  float* x2   = (float*)(w + 16777216);
  char*  R2   = w + 16777216 + 33554432;
  unsigned short* qkv = (unsigned short*)R2;
  float* Ssum = (float*)(R2 + 50331648);
  float* Spre = Ssum + (size_t)512*4160;
  unsigned short* hidden = (unsigned short*)R2;
  float* xmean = (float*)(w + 16777216 + 33554432 + 75497472);
  float* scal  = xmean + 2048;
  float* invr  = scal + 16;

  hipMemsetAsync(xmean, 0, 2048*sizeof(float), stream);

  rmsnorm_kernel<<<8192,256,0,stream>>>(x, g1, R1);
  gemm_kernel<0><<<dim3(3072/128, 8192/128),256,0,stream>>>(R1, w_qkv, qkv,
      8192,3072,1024, nullptr,nullptr,nullptr);
  rope_kernel<<<16384,256,0,stream>>>(qkv);
  chunksum_kernel<<<dim3(NCc,Bb*Hh),256,0,stream>>>(qkv, Ssum);
  prefix_kernel<<<Bb*Hh,256,0,stream>>>(Ssum, Spre);
  attnout_kernel<<<dim3(NCc,Bb*Hh),256,0,stream>>>(qkv, Spre, R1);
  gemm_kernel<1><<<dim3(1024/128, 8192/128),256,0,stream>>>(R1, w_out, x2,
      8192,1024,1024, x,nullptr,nullptr);
  rmsnorm_kernel<<<8192,256,0,stream>>>(x2, g2, R1);
  colmean_kernel<<<dim3(4,32,2),256,0,stream>>>(R1, xmean);
  dimpred_kernel<<<1,256,0,stream>>>(xmean, w_dp1, w_dp2, scal);
  gateup_kernel<<<dim3(Ff/64, 8192/128),256,0,stream>>>(R1, w_gate, w_up, hidden, scal);
  rowrms_kernel<<<8192,256,0,stream>>>(hidden, scal, invr);
  gemm_kernel<2><<<dim3(1024/128, 8192/128),256,0,stream>>>(hidden, w_down, out,
      8192,1024,4608, x2, invr, g_hid);
}

// Round 3
// 1062.585 us; speedup vs baseline: 1.2378x; 1.2378x over previous
//
#include <hip/hip_runtime.h>
#include <hip/hip_bf16.h>

#define Ee 1024
#define Hh 16
#define Ff 4608
#define Ll 4096
#define Bb 2
#define NCc 16
#define CHk 256

typedef short bf16x8 __attribute__((ext_vector_type(8)));
typedef float f32x4 __attribute__((ext_vector_type(4)));

__device__ __forceinline__ unsigned short f2bf(float f){
  unsigned int u = __builtin_bit_cast(unsigned int, f);
  u += 0x7fffu + ((u >> 16) & 1u);
  return (unsigned short)(u >> 16);
}
__device__ __forceinline__ float bf2f(unsigned short h){
  unsigned int u = ((unsigned int)h) << 16;
  return __builtin_bit_cast(float, u);
}
__device__ __forceinline__ float fixv(float v){
  return (__builtin_isnan(v) || __builtin_isinf(v)) ? 0.f : v;
}

// ---------------- weight convert+transpose: W[K][N] fp32 -> WT[N][K] bf16 ----------------
// optional scale[k] folded in (for w_down * g_hidden).
__global__ __launch_bounds__(256) void wconv_kernel(const float* __restrict__ W,
    unsigned short* __restrict__ WT, int K, int N, const float* __restrict__ scale){
  __shared__ unsigned short T[64][72];
  int k0 = blockIdx.y*64, n0 = blockIdx.x*64;
  int t = threadIdx.x;
  int kr = t>>4, n4 = (t&15)*4;
  #pragma unroll
  for (int it=0; it<4; it++){
    int k = kr + it*16;
    float s = scale ? scale[k0+k] : 1.f;
    float4 v = *(const float4*)(W + (size_t)(k0+k)*N + n0 + n4);
    T[n4+0][k] = f2bf(v.x*s);
    T[n4+1][k] = f2bf(v.y*s);
    T[n4+2][k] = f2bf(v.z*s);
    T[n4+3][k] = f2bf(v.w*s);
  }
  __syncthreads();
  int u = t&7;
  #pragma unroll
  for (int it=0; it<2; it++){
    int n = (t>>3) + it*32;
    *(bf16x8*)(WT + (size_t)(n0+n)*K + k0 + u*8) = *(const bf16x8*)&T[n][u*8];
  }
}

// ---------------- RMSNorm fp32 in -> bf16 out ----------------
__global__ __launch_bounds__(256) void rmsnorm_kernel(const float* __restrict__ x,
    const float* __restrict__ g, unsigned short* __restrict__ out){
  int row = blockIdx.x; int t = threadIdx.x;
  float4 v = ((const float4*)(x + (size_t)row*Ee))[t];
  v.x=fixv(v.x); v.y=fixv(v.y); v.z=fixv(v.z); v.w=fixv(v.w);
  float ss = v.x*v.x + v.y*v.y + v.z*v.z + v.w*v.w;
  #pragma unroll
  for (int off=32; off>0; off>>=1) ss += __shfl_down(ss, off);
  __shared__ float red[4];
  if ((t&63)==0) red[t>>6] = ss;
  __syncthreads();
  float tot = red[0]+red[1]+red[2]+red[3];
  float rms = sqrtf(tot*(1.f/Ee) + 1e-6f);
  rms = fminf(fmaxf(rms, 1e-6f), 1e6f);
  float inv = 1.f/rms;
  float4 gv = ((const float4*)g)[t];
  uint2 o;
  o.x = (unsigned)f2bf(v.x*inv*gv.x) | ((unsigned)f2bf(v.y*inv*gv.y)<<16);
  o.y = (unsigned)f2bf(v.z*inv*gv.z) | ((unsigned)f2bf(v.w*inv*gv.w)<<16);
  ((uint2*)(out + (size_t)row*Ee))[t] = o;
}

// ---------------- bf16 GEMM: C[M,N] = A[M,K] @ Bt[N,K]^T ----------------
// MODE 0: C bf16. MODE 1: C fp32 = acc + res. MODE 2: C fp32 = acc*rowscale[m] + res.
template<int MODE>
__global__ __launch_bounds__(256) void gemm_kernel(
    const unsigned short* __restrict__ A, const unsigned short* __restrict__ Bt,
    void* __restrict__ Cv, int M, int N, int K,
    const float* __restrict__ res, const float* __restrict__ rowscale){
  __shared__ __align__(16) unsigned short As[128][40];
  __shared__ __align__(16) unsigned short Bs[128][40];
  int tid = threadIdx.x;
  int nbx = gridDim.x;
  int id = blockIdx.y * nbx + blockIdx.x;
  int chunk = (nbx * gridDim.y) >> 3;
  int wg = (id & 7) * chunk + (id >> 3);
  int m0 = (wg / nbx) * 128, n0 = (wg % nbx) * 128;
  int lane = tid & 63, wave = tid >> 6;
  int wm = (wave>>1)*64, wn = (wave&1)*64;
  int lrow = lane & 15, lk = (lane>>4)*8;
  f32x4 acc[4][4] = {};
  int arow = tid>>2, acolg = (tid&3)*8;
  for (int k0=0; k0<K; k0+=32){
    const unsigned short* ap = A  + (size_t)(m0+arow)*K + k0 + acolg;
    const unsigned short* bp = Bt + (size_t)(n0+arow)*K + k0 + acolg;
    *(bf16x8*)&As[arow][acolg]    = *(const bf16x8*)ap;
    *(bf16x8*)&As[arow+64][acolg] = *(const bf16x8*)(ap + (size_t)64*K);
    *(bf16x8*)&Bs[arow][acolg]    = *(const bf16x8*)bp;
    *(bf16x8*)&Bs[arow+64][acolg] = *(const bf16x8*)(bp + (size_t)64*K);
    __syncthreads();
    bf16x8 af[4], bfr[4];
    #pragma unroll
    for (int i=0;i<4;i++){
      af[i]  = *(const bf16x8*)&As[wm + i*16 + lrow][lk];
      bfr[i] = *(const bf16x8*)&Bs[wn + i*16 + lrow][lk];
    }
    #pragma unroll
    for (int mi=0;mi<4;mi++)
      #pragma unroll
      for (int ni=0;ni<4;ni++)
        acc[mi][ni] = __builtin_amdgcn_mfma_f32_16x16x32_bf16(af[mi], bfr[ni], acc[mi][ni], 0,0,0);
    __syncthreads();
  }
  int rbase = m0 + wm + ((lane>>4)<<2);
  int cbase = n0 + wn + (lane&15);
  #pragma unroll
  for (int mi=0;mi<4;mi++){
    #pragma unroll
    for (int r=0;r<4;r++){
      int row = rbase + mi*16 + r;
      float rs = (MODE==2) ? rowscale[row] : 1.f;
      #pragma unroll
      for (int ni=0;ni<4;ni++){
        int col = cbase + ni*16;
        float v = acc[mi][ni][r];
        if (MODE==0){
          ((unsigned short*)Cv)[(size_t)row*N + col] = f2bf(v);
        } else if (MODE==1){
          ((float*)Cv)[(size_t)row*N + col] = v + res[(size_t)row*N + col];
        } else {
          ((float*)Cv)[(size_t)row*N + col] = v*rs + res[(size_t)row*N + col];
        }
      }
    }
  }
}

// ---------------- fused gate+up GEMM (128x128) -> hidden = silu(g)*u masked ----------------
__global__ __launch_bounds__(256) void gateup_kernel(
    const unsigned short* __restrict__ A, const unsigned short* __restrict__ Gt,
    const unsigned short* __restrict__ Ut, unsigned short* __restrict__ Hid,
    const float* __restrict__ scal){
  __shared__ __align__(16) unsigned short As[128][40];
  __shared__ __align__(16) unsigned short Bg[128][40];
  __shared__ __align__(16) unsigned short Bu[128][40];
  int tid = threadIdx.x;
  int nbx = gridDim.x;
  int id = blockIdx.y * nbx + blockIdx.x;
  int chunk = (nbx * gridDim.y) >> 3;
  int wg = (id & 7) * chunk + (id >> 3);
  int m0 = (wg / nbx) * 128, n0 = (wg % nbx) * 128;
  int lane = tid & 63, wave = tid >> 6;
  int wm = (wave>>1)*64, wn = (wave&1)*64;
  int lrow = lane & 15, lk = (lane>>4)*8;
  f32x4 ag[4][4] = {}, au[4][4] = {};
  int arow = tid>>2, acolg = (tid&3)*8;
  for (int k0=0; k0<Ee; k0+=32){
    const unsigned short* ap = A  + (size_t)(m0+arow)*Ee + k0 + acolg;
    const unsigned short* gp = Gt + (size_t)(n0+arow)*Ee + k0 + acolg;
    const unsigned short* up = Ut + (size_t)(n0+arow)*Ee + k0 + acolg;
    *(bf16x8*)&As[arow][acolg]    = *(const bf16x8*)ap;
    *(bf16x8*)&As[arow+64][acolg] = *(const bf16x8*)(ap + (size_t)64*Ee);
    *(bf16x8*)&Bg[arow][acolg]    = *(const bf16x8*)gp;
    *(bf16x8*)&Bg[arow+64][acolg] = *(const bf16x8*)(gp + (size_t)64*Ee);
    *(bf16x8*)&Bu[arow][acolg]    = *(const bf16x8*)up;
    *(bf16x8*)&Bu[arow+64][acolg] = *(const bf16x8*)(up + (size_t)64*Ee);
    __syncthreads();
    bf16x8 af[4], bg4[4], bu4[4];
    #pragma unroll
    for (int i=0;i<4;i++){
      af[i]  = *(const bf16x8*)&As[wm + i*16 + lrow][lk];
      bg4[i] = *(const bf16x8*)&Bg[wn + i*16 + lrow][lk];
      bu4[i] = *(const bf16x8*)&Bu[wn + i*16 + lrow][lk];
    }
    #pragma unroll
    for (int mi=0;mi<4;mi++)
      #pragma unroll
      for (int ni=0;ni<4;ni++){
        ag[mi][ni] = __builtin_amdgcn_mfma_f32_16x16x32_bf16(af[mi], bg4[ni], ag[mi][ni], 0,0,0);
        au[mi][ni] = __builtin_amdgcn_mfma_f32_16x16x32_bf16(af[mi], bu4[ni], au[mi][ni], 0,0,0);
      }
    __syncthreads();
  }
  int size = (int)scal[0];
  int rbase = m0 + wm + ((lane>>4)<<2);
  int cbase = n0 + wn + (lane&15);
  #pragma unroll
  for (int mi=0;mi<4;mi++){
    #pragma unroll
    for (int r=0;r<4;r++){
      int row = rbase + mi*16 + r;
      #pragma unroll
      for (int ni=0;ni<4;ni++){
        int col = cbase + ni*16;
        float g = ag[mi][ni][r], u = au[mi][ni][r];
        float hv = (g * (1.f/(1.f+expf(-g)))) * u;
        if (col >= size) hv = 0.f;
        if (__builtin_isnan(hv) || __builtin_isinf(hv)) hv = 0.f;
        Hid[(size_t)row*Ff + col] = f2bf(hv);
      }
    }
  }
}

// ---------------- RoPE + ELU+1 on q,k in bf16 qkv ----------------
__global__ __launch_bounds__(256) void rope_kernel(unsigned short* __restrict__ qkv){
  size_t idx = (size_t)blockIdx.x*256 + threadIdx.x;    // B*L*H*32
  int i = (int)(idx & 31);
  int h = (int)((idx>>5) & 15);
  size_t bl = idx >> 9;
  int pos = (int)(bl & (Ll-1));
  int d0 = 2*i, d1 = d0+1;
  size_t base = bl*3072 + (size_t)h*64 + d0;
  const float LOG1E4_D32 = 0.2878231366242557f;  // ln(10000)/32
  float e0 = (float)(d0 < 32 ? d0 : d0-32);
  float e1 = (float)(d1 < 32 ? d1 : d1-32);
  float f0 = pos * expf(-e0*LOG1E4_D32);
  float f1 = pos * expf(-e1*LOG1E4_D32);
  float s0,c0,s1,c1;
  sincosf(f0,&s0,&c0); sincosf(f1,&s1,&c1);
  unsigned int* qp = (unsigned int*)(qkv + base);
  unsigned int qv = *qp;
  float q0 = bf2f((unsigned short)(qv&0xffff)), q1 = bf2f((unsigned short)(qv>>16));
  float r0 = q0*c0 - q1*s0;
  float r1 = q1*c1 + q0*s1;
  r0 = r0>0.f ? r0+1.f : expf(r0);
  r1 = r1>0.f ? r1+1.f : expf(r1);
  *qp = (unsigned)f2bf(r0) | ((unsigned)f2bf(r1)<<16);
  unsigned int* kp = (unsigned int*)(qkv + base + 1024);
  unsigned int kv = *kp;
  float k0v = bf2f((unsigned short)(kv&0xffff)), k1v = bf2f((unsigned short)(kv>>16));
  float t0 = k0v*c0 - k1v*s0;
  float t1 = k1v*c1 + k0v*s1;
  t0 = t0>0.f ? t0+1.f : expf(t0);
  t1 = t1>0.f ? t1+1.f : expf(t1);
  *kp = (unsigned)f2bf(t0) | ((unsigned)f2bf(t1)<<16);
}

// ---------------- per-chunk K^T V (64x64) + K col sums; 2-pass LDS ----------------
__global__ __launch_bounds__(256) void chunksum_kernel(const unsigned short* __restrict__ qkv,
    float* __restrict__ Ssum){
  int c = blockIdx.x, bh = blockIdx.y;
  int b = bh >> 4, h = bh & 15;
  __shared__ __align__(16) unsigned short Ks[128][64];
  __shared__ __align__(16) unsigned short Vs[128][64];
  int t = threadIdx.x;
  int j = t >> 2, dg = (t&3)*16;
  float acc[16] = {}; float zacc = 0.f;
  for (int p=0;p<2;p++){
    __syncthreads();
    #pragma unroll
    for (int it=0; it<4; it++){
      int flat = it*256 + t;
      int row = flat >> 3, colg = (flat & 7)*8;
      size_t g = ((size_t)(b*Ll + c*CHk + p*128 + row))*3072 + h*64 + colg;
      *(bf16x8*)&Ks[row][colg] = *(const bf16x8*)(qkv + g + 1024);
      *(bf16x8*)&Vs[row][colg] = *(const bf16x8*)(qkv + g + 2048);
    }
    __syncthreads();
    for (int m=0;m<128;m++){
      float kv = bf2f(Ks[m][j]);
      zacc += kv;
      #pragma unroll
      for (int q8=0;q8<2;q8++){
        bf16x8 vv = *(const bf16x8*)&Vs[m][dg + q8*8];
        #pragma unroll
        for (int u=0;u<8;u++) acc[q8*8+u] += kv * bf2f((unsigned short)vv[u]);
      }
    }
  }
  float* S = Ssum + ((size_t)bh*NCc + c)*4160;
  #pragma unroll
  for (int d=0;d<16;d++) S[j*64 + dg + d] = acc[d];
  if ((t&3)==0) S[4096 + j] = zacc;
}

// ---------------- exclusive prefix over chunks ----------------
__global__ __launch_bounds__(256) void prefix_kernel(const float* __restrict__ Ssum,
    float* __restrict__ Spre){
  int bh = blockIdx.x; int t = threadIdx.x;
  size_t base = (size_t)bh*NCc*4160;
  for (int e=t; e<4160; e+=256){
    float acc = 0.f;
    #pragma unroll
    for (int c=0;c<NCc;c++){
      Spre[base + (size_t)c*4160 + e] = acc;
      acc += Ssum[base + (size_t)c*4160 + e];
    }
  }
}

// ---------------- per-chunk causal attention; 2-pass LDS ----------------
__global__ __launch_bounds__(256) void attnout_kernel(const unsigned short* __restrict__ qkv,
    const float* __restrict__ Spre, unsigned short* __restrict__ attn){
  int c = blockIdx.x, bh = blockIdx.y;
  int b = bh >> 4, h = bh & 15;
  __shared__ __align__(16) unsigned short Ks[128][64];
  __shared__ __align__(16) unsigned short Vs[128][64];
  int t = threadIdx.x;
  int wave = t >> 6;
  float q[64];
  size_t qg = ((size_t)(b*Ll + c*CHk + t))*3072 + (size_t)h*64;
  #pragma unroll
  for (int g8=0; g8<8; g8++){
    bf16x8 v = *(const bf16x8*)(qkv + qg + g8*8);
    #pragma unroll
    for (int u=0;u<8;u++) q[g8*8+u] = bf2f((unsigned short)v[u]);
  }
  const float* Sp = Spre + ((size_t)bh*NCc + c)*4160;
  float num[64];
  #pragma unroll
  for (int d=0;d<64;d++) num[d]=0.f;
  for (int j=0;j<64;j++){
    float qj = q[j];
    const float* Sr = Sp + j*64;
    #pragma unroll
    for (int d4=0; d4<16; d4++){
      float4 sv = *(const float4*)(Sr + d4*4);
      num[d4*4+0] += qj*sv.x; num[d4*4+1] += qj*sv.y;
      num[d4*4+2] += qj*sv.z; num[d4*4+3] += qj*sv.w;
    }
  }
  float den = 0.f;
  #pragma unroll
  for (int j=0;j<64;j++) den += q[j]*Sp[4096+j];
  for (int p=0;p<2;p++){
    __syncthreads();
    #pragma unroll
    for (int it=0; it<4; it++){
      int flat = it*256 + t;
      int row = flat >> 3, colg = (flat & 7)*8;
      size_t g = ((size_t)(b*Ll + c*CHk + p*128 + row))*3072 + h*64 + colg;
      *(bf16x8*)&Ks[row][colg] = *(const bf16x8*)(qkv + g + 1024);
      *(bf16x8*)&Vs[row][colg] = *(const bf16x8*)(qkv + g + 2048);
    }
    __syncthreads();
    int wtop = wave*64 + 63;
    if (wtop >= p*128){
      int wlim = wtop - p*128; if (wlim > 127) wlim = 127;
      int lim = t - p*128;
      for (int m=0; m<=wlim; m++){
        float qk = 0.f;
        #pragma unroll
        for (int g8=0; g8<8; g8++){
          bf16x8 kv8 = *(const bf16x8*)&Ks[m][g8*8];
          #pragma unroll
          for (int u=0;u<8;u++) qk += q[g8*8+u]*bf2f((unsigned short)kv8[u]);
        }
        float qkm = (m <= lim) ? qk : 0.f;
        den += qkm;
        #pragma unroll
        for (int g8=0; g8<8; g8++){
          bf16x8 vv8 = *(const bf16x8*)&Vs[m][g8*8];
          #pragma unroll
          for (int u=0;u<8;u++) num[g8*8+u] += qkm*bf2f((unsigned short)vv8[u]);
        }
      }
    }
  }
  den = fmaxf(den, 1e-6f);
  float inv = 1.f/den;
  unsigned short* o = attn + ((size_t)(b*Ll + c*CHk + t))*Ee + (size_t)h*64;
  #pragma unroll
  for (int g8=0; g8<8; g8++){
    bf16x8 ov;
    #pragma unroll
    for (int u=0;u<8;u++) ov[u] = (short)f2bf(num[g8*8+u]*inv);
    *(bf16x8*)(o + g8*8) = ov;
  }
}

// ---------------- column mean over L, deterministic 2-stage ----------------
__global__ __launch_bounds__(256) void colmean1_kernel(const unsigned short* __restrict__ h2,
    float* __restrict__ partial){
  int e = blockIdx.x*256 + threadIdx.x;
  int ly = blockIdx.y;
  int b = blockIdx.z;
  int l0 = ly * 128;
  float s = 0.f;
  for (int l=l0; l<l0+128; l++) s += bf2f(h2[((size_t)(b*Ll + l))*Ee + e]);
  partial[((size_t)(b*32 + ly))*Ee + e] = s;
}
__global__ __launch_bounds__(256) void colmean2_kernel(const float* __restrict__ partial,
    float* __restrict__ xmean){
  int e = blockIdx.x*256 + threadIdx.x;
  int b = blockIdx.y;
  float s = 0.f;
  #pragma unroll
  for (int ly=0; ly<32; ly++) s += partial[((size_t)(b*32 + ly))*Ee + e];
  xmean[b*Ee + e] = s * (1.f/Ll);
}

// ---------------- dim predictor -> floored size ----------------
__global__ __launch_bounds__(256) void dimpred_kernel(const float* __restrict__ xmean,
    const float* __restrict__ w_dp1, const float* __restrict__ w_dp2,
    float* __restrict__ scalars){
  __shared__ float red[256];
  __shared__ float ratio_s[2];
  int t = threadIdx.x;
  for (int b=0;b<2;b++){
    float s = 0.f;
    for (int k=0;k<1024;k++) s += xmean[b*Ee + k] * w_dp1[k*256 + t];
    float sil = s * (1.f/(1.f+expf(-s)));
    red[t] = sil * w_dp2[t];
    __syncthreads();
    for (int off=128; off>0; off>>=1){
      if (t<off) red[t] += red[t+off];
      __syncthreads();
    }
    if (t==0){
      float dr = 1.f/(1.f+expf(-red[0]));
      float ratio = 1.f + (dr-0.5f)*1.0f;       // 2*ADAPT = 1
      ratio = fminf(fmaxf(ratio, 0.5f), 1.5f);
      ratio_s[b] = ratio;
    }
    __syncthreads();
  }
  if (t==0){
    float rm = 0.5f*(ratio_s[0]+ratio_s[1]);
    float size_f = floorf(3072.f * rm);
    if (size_f < 1.f) size_f = 1.f;
    scalars[0] = size_f;
  }
}

// ---------------- per-row sumsq of hidden -> inv_rms ----------------
__global__ __launch_bounds__(256) void rowrms_kernel(const unsigned short* __restrict__ Hid,
    const float* __restrict__ scal, float* __restrict__ invr){
  int row = blockIdx.x; int t = threadIdx.x;
  float ss = 0.f;
  for (int c8 = t; c8 < Ff/8; c8 += 256){
    bf16x8 v = *(const bf16x8*)(Hid + (size_t)row*Ff + c8*8);
    #pragma unroll
    for (int u=0;u<8;u++){ float f = bf2f((unsigned short)v[u]); ss += f*f; }
  }
  #pragma unroll
  for (int off=32; off>0; off>>=1) ss += __shfl_down(ss, off);
  __shared__ float red[4];
  if ((t&63)==0) red[t>>6] = ss;
  __syncthreads();
  if (t==0){
    float tot = red[0]+red[1]+red[2]+red[3];
    float rms = sqrtf(tot/scal[0] + 1e-6f);
    rms = fminf(fmaxf(rms, 1e-6f), 1e6f);
    invr[row] = 1.f/rms;
  }
}

extern "C" void kernel_launch(void* const* d_in, const int* in_sizes, int n_in,
                              void* d_out, int out_size, void* d_ws, size_t ws_size,
                              hipStream_t stream){
  const float* x      = (const float*)d_in[0];
  const float* w_qkv  = (const float*)d_in[1];
  const float* w_out  = (const float*)d_in[2];
  const float* g1     = (const float*)d_in[3];
  const float* g2     = (const float*)d_in[4];
  const float* w_dp1  = (const float*)d_in[5];
  const float* w_dp2  = (const float*)d_in[6];
  const float* w_gate = (const float*)d_in[7];
  const float* w_up   = (const float*)d_in[8];
  const float* w_down = (const float*)d_in[9];
  const float* g_hid  = (const float*)d_in[10];
  float* out = (float*)d_out;

  char* w = (char*)d_ws;
  size_t o = 0;
  auto alloc = [&](size_t bytes)->char*{ char* p = w + o; o += (bytes + 255) & ~255ull; return p; };
  unsigned short* R1   = (unsigned short*)alloc((size_t)8192*1024*2);   // h/attn/h2 bf16
  float*          x2   = (float*)alloc((size_t)8192*1024*4);            // post-attn residual fp32
  char*           R2   = alloc((size_t)8192*4608*2);                    // qkv bf16 (48MB) then hidden (75.5MB)
  unsigned short* qkvT = (unsigned short*)alloc((size_t)3072*1024*2);
  unsigned short* outT = (unsigned short*)alloc((size_t)1024*1024*2);
  char*           W2   = alloc((size_t)3*4608*1024*2);                  // Ssum/Spre then gateT/upT/downT
  float*       partial = (float*)alloc((size_t)64*1024*4);
  float*         xmean = (float*)alloc(2048*4);
  float*          scal = (float*)alloc(64);
  float*          invr = (float*)alloc(8192*4);

  unsigned short* qkv    = (unsigned short*)R2;
  unsigned short* hidden = (unsigned short*)R2;
  float* Ssum = (float*)W2;
  float* Spre = Ssum + (size_t)512*4160;
  unsigned short* gateT = (unsigned short*)W2;
  unsigned short* upT   = gateT + (size_t)4608*1024;
  unsigned short* downT = upT   + (size_t)4608*1024;

  // weights needed early
  wconv_kernel<<<dim3(3072/64, 1024/64),256,0,stream>>>(w_qkv, qkvT, 1024, 3072, nullptr);
  wconv_kernel<<<dim3(1024/64, 1024/64),256,0,stream>>>(w_out, outT, 1024, 1024, nullptr);

  rmsnorm_kernel<<<8192,256,0,stream>>>(x, g1, R1);
  gemm_kernel<0><<<dim3(3072/128, 8192/128),256,0,stream>>>(R1, qkvT, qkv,
      8192,3072,1024, nullptr,nullptr);
  rope_kernel<<<16384,256,0,stream>>>(qkv);
  chunksum_kernel<<<dim3(NCc,Bb*Hh),256,0,stream>>>(qkv, Ssum);
  prefix_kernel<<<Bb*Hh,256,0,stream>>>(Ssum, Spre);
  attnout_kernel<<<dim3(NCc,Bb*Hh),256,0,stream>>>(qkv, Spre, R1);

  // Ssum/Spre dead now: convert FFN weights into W2
  wconv_kernel<<<dim3(4608/64, 1024/64),256,0,stream>>>(w_gate, gateT, 1024, 4608, nullptr);
  wconv_kernel<<<dim3(4608/64, 1024/64),256,0,stream>>>(w_up,   upT,   1024, 4608, nullptr);
  wconv_kernel<<<dim3(1024/64, 4608/64),256,0,stream>>>(w_down, downT, 4608, 1024, g_hid);

  gemm_kernel<1><<<dim3(1024/128, 8192/128),256,0,stream>>>(R1, outT, x2,
      8192,1024,1024, x,nullptr);
  rmsnorm_kernel<<<8192,256,0,stream>>>(x2, g2, R1);
  colmean1_kernel<<<dim3(4,32,2),256,0,stream>>>(R1, partial);
  colmean2_kernel<<<dim3(4,2),256,0,stream>>>(partial, xmean);
  dimpred_kernel<<<1,256,0,stream>>>(xmean, w_dp1, w_dp2, scal);
  gateup_kernel<<<dim3(4608/128, 8192/128),256,0,stream>>>(R1, gateT, upT, hidden, scal);
  rowrms_kernel<<<8192,256,0,stream>>>(hidden, scal, invr);
  gemm_kernel<2><<<dim3(1024/128, 8192/128),256,0,stream>>>(hidden, downT, out,
      8192,1024,4608, x2, invr);
}

// Round 4
// 957.580 us; speedup vs baseline: 1.3735x; 1.1097x over previous
//
#include <hip/hip_runtime.h>
#include <hip/hip_bf16.h>

#define Ee 1024
#define Hh 16
#define Ff 4608
#define Ll 4096
#define Bb 2
#define NCc 16
#define CHk 256

typedef short bf16x8 __attribute__((ext_vector_type(8)));
typedef float f32x4 __attribute__((ext_vector_type(4)));

#define GLD16(g, l) __builtin_amdgcn_global_load_lds( \
    (const __attribute__((address_space(1))) unsigned int*)(g), \
    (__attribute__((address_space(3))) unsigned int*)(l), 16, 0, 0)

__device__ __forceinline__ unsigned short f2bf(float f){
  unsigned int u = __builtin_bit_cast(unsigned int, f);
  u += 0x7fffu + ((u >> 16) & 1u);
  return (unsigned short)(u >> 16);
}
__device__ __forceinline__ float bf2f(unsigned short h){
  unsigned int u = ((unsigned int)h) << 16;
  return __builtin_bit_cast(float, u);
}
__device__ __forceinline__ float fixv(float v){
  return (__builtin_isnan(v) || __builtin_isinf(v)) ? 0.f : v;
}

// ---------------- weight convert+transpose: W[K][N] fp32 -> WT[N][K] bf16 ----------------
__global__ __launch_bounds__(256) void wconv_kernel(const float* __restrict__ W,
    unsigned short* __restrict__ WT, int K, int N, const float* __restrict__ scale){
  __shared__ unsigned short T[64][72];
  int k0 = blockIdx.y*64, n0 = blockIdx.x*64;
  int t = threadIdx.x;
  int kr = t>>4, n4 = (t&15)*4;
  #pragma unroll
  for (int it=0; it<4; it++){
    int k = kr + it*16;
    float s = scale ? scale[k0+k] : 1.f;
    float4 v = *(const float4*)(W + (size_t)(k0+k)*N + n0 + n4);
    T[n4+0][k] = f2bf(v.x*s);
    T[n4+1][k] = f2bf(v.y*s);
    T[n4+2][k] = f2bf(v.z*s);
    T[n4+3][k] = f2bf(v.w*s);
  }
  __syncthreads();
  int u = t&7;
  #pragma unroll
  for (int it=0; it<2; it++){
    int n = (t>>3) + it*32;
    *(bf16x8*)(WT + (size_t)(n0+n)*K + k0 + u*8) = *(const bf16x8*)&T[n][u*8];
  }
}

// ---------------- RMSNorm fp32 in -> bf16 out ----------------
__global__ __launch_bounds__(256) void rmsnorm_kernel(const float* __restrict__ x,
    const float* __restrict__ g, unsigned short* __restrict__ out){
  int row = blockIdx.x; int t = threadIdx.x;
  float4 v = ((const float4*)(x + (size_t)row*Ee))[t];
  v.x=fixv(v.x); v.y=fixv(v.y); v.z=fixv(v.z); v.w=fixv(v.w);
  float ss = v.x*v.x + v.y*v.y + v.z*v.z + v.w*v.w;
  #pragma unroll
  for (int off=32; off>0; off>>=1) ss += __shfl_down(ss, off);
  __shared__ float red[4];
  if ((t&63)==0) red[t>>6] = ss;
  __syncthreads();
  float tot = red[0]+red[1]+red[2]+red[3];
  float rms = sqrtf(tot*(1.f/Ee) + 1e-6f);
  rms = fminf(fmaxf(rms, 1e-6f), 1e6f);
  float inv = 1.f/rms;
  float4 gv = ((const float4*)g)[t];
  uint2 o;
  o.x = (unsigned)f2bf(v.x*inv*gv.x) | ((unsigned)f2bf(v.y*inv*gv.y)<<16);
  o.y = (unsigned)f2bf(v.z*inv*gv.z) | ((unsigned)f2bf(v.w*inv*gv.w)<<16);
  ((uint2*)(out + (size_t)row*Ee))[t] = o;
}

// ---------------- bf16 GEMM: C[M,N] = A[M,K] @ Bt[N,K]^T ----------------
// global_load_lds staging, double-buffered 2-phase pipeline.
// MODE 0: C bf16. MODE 1: C fp32 = acc + res. MODE 2: C fp32 = acc*rowscale[m] + res.
template<int MODE>
__global__ __launch_bounds__(256) void gemm_kernel(
    const unsigned short* __restrict__ A, const unsigned short* __restrict__ Bt,
    void* __restrict__ Cv, int M, int N, int K,
    const float* __restrict__ res, const float* __restrict__ rowscale){
  __shared__ __align__(16) unsigned short As[2][4096];
  __shared__ __align__(16) unsigned short Bs[2][4096];
  int tid = threadIdx.x;
  int nbx = gridDim.x;
  int id = blockIdx.y * nbx + blockIdx.x;
  int chunk = (nbx * gridDim.y) >> 3;
  int wg = (id & 7) * chunk + (id >> 3);
  int m0 = (wg / nbx) * 128, n0 = (wg % nbx) * 128;
  int lane = tid & 63, wave = tid >> 6;
  int wm = (wave>>1)*64, wn = (wave&1)*64;
  int lrow = lane & 15, lk = (lane>>4)*8;
  // staging geometry: wave w fills segments 2w, 2w+1 of each 8KB tile
  int s0 = wave*2, s1 = s0+1;
  int r0 = s0*16 + (lane>>2), r1 = s1*16 + (lane>>2);
  int cg = (lane&3)*8;
  const unsigned short* a0 = A  + (size_t)(m0+r0)*K + cg;
  const unsigned short* a1 = A  + (size_t)(m0+r1)*K + cg;
  const unsigned short* b0 = Bt + (size_t)(n0+r0)*K + cg;
  const unsigned short* b1 = Bt + (size_t)(n0+r1)*K + cg;
  f32x4 acc[4][4] = {};
  int nk = K >> 5;
  GLD16(a0, &As[0][s0*512]); GLD16(a1, &As[0][s1*512]);
  GLD16(b0, &Bs[0][s0*512]); GLD16(b1, &Bs[0][s1*512]);
  __syncthreads();
  int cur = 0;
  for (int t=0; t<nk; ++t){
    if (t+1 < nk){
      int ko = (t+1) << 5;
      GLD16(a0+ko, &As[cur^1][s0*512]); GLD16(a1+ko, &As[cur^1][s1*512]);
      GLD16(b0+ko, &Bs[cur^1][s0*512]); GLD16(b1+ko, &Bs[cur^1][s1*512]);
    }
    bf16x8 af[4], bfr[4];
    #pragma unroll
    for (int i=0;i<4;i++){
      af[i]  = *(const bf16x8*)&As[cur][(wm + i*16 + lrow)*32 + lk];
      bfr[i] = *(const bf16x8*)&Bs[cur][(wn + i*16 + lrow)*32 + lk];
    }
    #pragma unroll
    for (int mi=0;mi<4;mi++)
      #pragma unroll
      for (int ni=0;ni<4;ni++)
        acc[mi][ni] = __builtin_amdgcn_mfma_f32_16x16x32_bf16(af[mi], bfr[ni], acc[mi][ni], 0,0,0);
    __syncthreads();
    cur ^= 1;
  }
  int rbase = m0 + wm + ((lane>>4)<<2);
  int cbase = n0 + wn + (lane&15);
  #pragma unroll
  for (int mi=0;mi<4;mi++){
    #pragma unroll
    for (int r=0;r<4;r++){
      int row = rbase + mi*16 + r;
      float rs = (MODE==2) ? rowscale[row] : 1.f;
      #pragma unroll
      for (int ni=0;ni<4;ni++){
        int col = cbase + ni*16;
        float v = acc[mi][ni][r];
        if (MODE==0){
          ((unsigned short*)Cv)[(size_t)row*N + col] = f2bf(v);
        } else if (MODE==1){
          ((float*)Cv)[(size_t)row*N + col] = v + res[(size_t)row*N + col];
        } else {
          ((float*)Cv)[(size_t)row*N + col] = v*rs + res[(size_t)row*N + col];
        }
      }
    }
  }
}

// ---------------- fused gate+up GEMM (128x128) -> hidden = silu(g)*u masked ----------------
__global__ __launch_bounds__(256) void gateup_kernel(
    const unsigned short* __restrict__ A, const unsigned short* __restrict__ Gt,
    const unsigned short* __restrict__ Ut, unsigned short* __restrict__ Hid,
    const float* __restrict__ scal){
  __shared__ __align__(16) unsigned short As[2][4096];
  __shared__ __align__(16) unsigned short Bg[2][4096];
  __shared__ __align__(16) unsigned short Bu[2][4096];
  int tid = threadIdx.x;
  int nbx = gridDim.x;
  int id = blockIdx.y * nbx + blockIdx.x;
  int chunk = (nbx * gridDim.y) >> 3;
  int wg = (id & 7) * chunk + (id >> 3);
  int m0 = (wg / nbx) * 128, n0 = (wg % nbx) * 128;
  int lane = tid & 63, wave = tid >> 6;
  int wm = (wave>>1)*64, wn = (wave&1)*64;
  int lrow = lane & 15, lk = (lane>>4)*8;
  int s0 = wave*2, s1 = s0+1;
  int r0 = s0*16 + (lane>>2), r1 = s1*16 + (lane>>2);
  int cg = (lane&3)*8;
  const unsigned short* a0 = A  + (size_t)(m0+r0)*Ee + cg;
  const unsigned short* a1 = A  + (size_t)(m0+r1)*Ee + cg;
  const unsigned short* g0 = Gt + (size_t)(n0+r0)*Ee + cg;
  const unsigned short* g1p= Gt + (size_t)(n0+r1)*Ee + cg;
  const unsigned short* u0 = Ut + (size_t)(n0+r0)*Ee + cg;
  const unsigned short* u1 = Ut + (size_t)(n0+r1)*Ee + cg;
  f32x4 ag[4][4] = {}, au[4][4] = {};
  GLD16(a0, &As[0][s0*512]); GLD16(a1, &As[0][s1*512]);
  GLD16(g0, &Bg[0][s0*512]); GLD16(g1p,&Bg[0][s1*512]);
  GLD16(u0, &Bu[0][s0*512]); GLD16(u1, &Bu[0][s1*512]);
  __syncthreads();
  int cur = 0;
  for (int t=0; t<32; ++t){
    if (t+1 < 32){
      int ko = (t+1) << 5;
      GLD16(a0+ko, &As[cur^1][s0*512]); GLD16(a1+ko, &As[cur^1][s1*512]);
      GLD16(g0+ko, &Bg[cur^1][s0*512]); GLD16(g1p+ko,&Bg[cur^1][s1*512]);
      GLD16(u0+ko, &Bu[cur^1][s0*512]); GLD16(u1+ko, &Bu[cur^1][s1*512]);
    }
    bf16x8 af[4], bg4[4], bu4[4];
    #pragma unroll
    for (int i=0;i<4;i++){
      af[i]  = *(const bf16x8*)&As[cur][(wm + i*16 + lrow)*32 + lk];
      bg4[i] = *(const bf16x8*)&Bg[cur][(wn + i*16 + lrow)*32 + lk];
      bu4[i] = *(const bf16x8*)&Bu[cur][(wn + i*16 + lrow)*32 + lk];
    }
    #pragma unroll
    for (int mi=0;mi<4;mi++)
      #pragma unroll
      for (int ni=0;ni<4;ni++){
        ag[mi][ni] = __builtin_amdgcn_mfma_f32_16x16x32_bf16(af[mi], bg4[ni], ag[mi][ni], 0,0,0);
        au[mi][ni] = __builtin_amdgcn_mfma_f32_16x16x32_bf16(af[mi], bu4[ni], au[mi][ni], 0,0,0);
      }
    __syncthreads();
    cur ^= 1;
  }
  int size = (int)scal[0];
  int rbase = m0 + wm + ((lane>>4)<<2);
  int cbase = n0 + wn + (lane&15);
  #pragma unroll
  for (int mi=0;mi<4;mi++){
    #pragma unroll
    for (int r=0;r<4;r++){
      int row = rbase + mi*16 + r;
      #pragma unroll
      for (int ni=0;ni<4;ni++){
        int col = cbase + ni*16;
        float g = ag[mi][ni][r], u = au[mi][ni][r];
        float hv = (g * (1.f/(1.f+expf(-g)))) * u;
        if (col >= size) hv = 0.f;
        if (__builtin_isnan(hv) || __builtin_isinf(hv)) hv = 0.f;
        Hid[(size_t)row*Ff + col] = f2bf(hv);
      }
    }
  }
}

// ---------------- RoPE + ELU+1 on q,k in bf16 qkv ----------------
__global__ __launch_bounds__(256) void rope_kernel(unsigned short* __restrict__ qkv){
  size_t idx = (size_t)blockIdx.x*256 + threadIdx.x;    // B*L*H*32
  int i = (int)(idx & 31);
  int h = (int)((idx>>5) & 15);
  size_t bl = idx >> 9;
  int pos = (int)(bl & (Ll-1));
  int d0 = 2*i, d1 = d0+1;
  size_t base = bl*3072 + (size_t)h*64 + d0;
  const float LOG1E4_D32 = 0.2878231366242557f;  // ln(10000)/32
  float e0 = (float)(d0 < 32 ? d0 : d0-32);
  float e1 = (float)(d1 < 32 ? d1 : d1-32);
  float f0 = pos * expf(-e0*LOG1E4_D32);
  float f1 = pos * expf(-e1*LOG1E4_D32);
  float s0,c0,s1,c1;
  sincosf(f0,&s0,&c0); sincosf(f1,&s1,&c1);
  unsigned int* qp = (unsigned int*)(qkv + base);
  unsigned int qv = *qp;
  float q0 = bf2f((unsigned short)(qv&0xffff)), q1 = bf2f((unsigned short)(qv>>16));
  float r0 = q0*c0 - q1*s0;
  float r1 = q1*c1 + q0*s1;
  r0 = r0>0.f ? r0+1.f : expf(r0);
  r1 = r1>0.f ? r1+1.f : expf(r1);
  *qp = (unsigned)f2bf(r0) | ((unsigned)f2bf(r1)<<16);
  unsigned int* kp = (unsigned int*)(qkv + base + 1024);
  unsigned int kv = *kp;
  float k0v = bf2f((unsigned short)(kv&0xffff)), k1v = bf2f((unsigned short)(kv>>16));
  float t0 = k0v*c0 - k1v*s0;
  float t1 = k1v*c1 + k0v*s1;
  t0 = t0>0.f ? t0+1.f : expf(t0);
  t1 = t1>0.f ? t1+1.f : expf(t1);
  *kp = (unsigned)f2bf(t0) | ((unsigned)f2bf(t1)<<16);
}

// ---------------- per-chunk K^T V (64x64) + K col sums; 2-pass LDS ----------------
__global__ __launch_bounds__(256) void chunksum_kernel(const unsigned short* __restrict__ qkv,
    float* __restrict__ Ssum){
  int c = blockIdx.x, bh = blockIdx.y;
  int b = bh >> 4, h = bh & 15;
  __shared__ __align__(16) unsigned short Ks[128][64];
  __shared__ __align__(16) unsigned short Vs[128][64];
  int t = threadIdx.x;
  int j = t >> 2, dg = (t&3)*16;
  float acc[16] = {}; float zacc = 0.f;
  for (int p=0;p<2;p++){
    __syncthreads();
    #pragma unroll
    for (int it=0; it<4; it++){
      int flat = it*256 + t;
      int row = flat >> 3, colg = (flat & 7)*8;
      size_t g = ((size_t)(b*Ll + c*CHk + p*128 + row))*3072 + h*64 + colg;
      *(bf16x8*)&Ks[row][colg] = *(const bf16x8*)(qkv + g + 1024);
      *(bf16x8*)&Vs[row][colg] = *(const bf16x8*)(qkv + g + 2048);
    }
    __syncthreads();
    for (int m=0;m<128;m++){
      float kv = bf2f(Ks[m][j]);
      zacc += kv;
      #pragma unroll
      for (int q8=0;q8<2;q8++){
        bf16x8 vv = *(const bf16x8*)&Vs[m][dg + q8*8];
        #pragma unroll
        for (int u=0;u<8;u++) acc[q8*8+u] += kv * bf2f((unsigned short)vv[u]);
      }
    }
  }
  float* S = Ssum + ((size_t)bh*NCc + c)*4160;
  #pragma unroll
  for (int d=0;d<16;d++) S[j*64 + dg + d] = acc[d];
  if ((t&3)==0) S[4096 + j] = zacc;
}

// ---------------- exclusive prefix over chunks ----------------
__global__ __launch_bounds__(256) void prefix_kernel(const float* __restrict__ Ssum,
    float* __restrict__ Spre){
  int bh = blockIdx.x; int t = threadIdx.x;
  size_t base = (size_t)bh*NCc*4160;
  for (int e=t; e<4160; e+=256){
    float acc = 0.f;
    #pragma unroll
    for (int c=0;c<NCc;c++){
      Spre[base + (size_t)c*4160 + e] = acc;
      acc += Ssum[base + (size_t)c*4160 + e];
    }
  }
}

// ---------------- per-chunk causal attention; 2-pass LDS ----------------
__global__ __launch_bounds__(256) void attnout_kernel(const unsigned short* __restrict__ qkv,
    const float* __restrict__ Spre, unsigned short* __restrict__ attn){
  int c = blockIdx.x, bh = blockIdx.y;
  int b = bh >> 4, h = bh & 15;
  __shared__ __align__(16) unsigned short Ks[128][64];
  __shared__ __align__(16) unsigned short Vs[128][64];
  int t = threadIdx.x;
  int wave = t >> 6;
  float q[64];
  size_t qg = ((size_t)(b*Ll + c*CHk + t))*3072 + (size_t)h*64;
  #pragma unroll
  for (int g8=0; g8<8; g8++){
    bf16x8 v = *(const bf16x8*)(qkv + qg + g8*8);
    #pragma unroll
    for (int u=0;u<8;u++) q[g8*8+u] = bf2f((unsigned short)v[u]);
  }
  const float* Sp = Spre + ((size_t)bh*NCc + c)*4160;
  float num[64];
  #pragma unroll
  for (int d=0;d<64;d++) num[d]=0.f;
  for (int j=0;j<64;j++){
    float qj = q[j];
    const float* Sr = Sp + j*64;
    #pragma unroll
    for (int d4=0; d4<16; d4++){
      float4 sv = *(const float4*)(Sr + d4*4);
      num[d4*4+0] += qj*sv.x; num[d4*4+1] += qj*sv.y;
      num[d4*4+2] += qj*sv.z; num[d4*4+3] += qj*sv.w;
    }
  }
  float den = 0.f;
  #pragma unroll
  for (int j=0;j<64;j++) den += q[j]*Sp[4096+j];
  for (int p=0;p<2;p++){
    __syncthreads();
    #pragma unroll
    for (int it=0; it<4; it++){
      int flat = it*256 + t;
      int row = flat >> 3, colg = (flat & 7)*8;
      size_t g = ((size_t)(b*Ll + c*CHk + p*128 + row))*3072 + h*64 + colg;
      *(bf16x8*)&Ks[row][colg] = *(const bf16x8*)(qkv + g + 1024);
      *(bf16x8*)&Vs[row][colg] = *(const bf16x8*)(qkv + g + 2048);
    }
    __syncthreads();
    int wtop = wave*64 + 63;
    if (wtop >= p*128){
      int wlim = wtop - p*128; if (wlim > 127) wlim = 127;
      int lim = t - p*128;
      for (int m=0; m<=wlim; m++){
        float qk = 0.f;
        #pragma unroll
        for (int g8=0; g8<8; g8++){
          bf16x8 kv8 = *(const bf16x8*)&Ks[m][g8*8];
          #pragma unroll
          for (int u=0;u<8;u++) qk += q[g8*8+u]*bf2f((unsigned short)kv8[u]);
        }
        float qkm = (m <= lim) ? qk : 0.f;
        den += qkm;
        #pragma unroll
        for (int g8=0; g8<8; g8++){
          bf16x8 vv8 = *(const bf16x8*)&Vs[m][g8*8];
          #pragma unroll
          for (int u=0;u<8;u++) num[g8*8+u] += qkm*bf2f((unsigned short)vv8[u]);
        }
      }
    }
  }
  den = fmaxf(den, 1e-6f);
  float inv = 1.f/den;
  unsigned short* o = attn + ((size_t)(b*Ll + c*CHk + t))*Ee + (size_t)h*64;
  #pragma unroll
  for (int g8=0; g8<8; g8++){
    bf16x8 ov;
    #pragma unroll
    for (int u=0;u<8;u++) ov[u] = (short)f2bf(num[g8*8+u]*inv);
    *(bf16x8*)(o + g8*8) = ov;
  }
}

// ---------------- column mean over L, deterministic 2-stage ----------------
__global__ __launch_bounds__(256) void colmean1_kernel(const unsigned short* __restrict__ h2,
    float* __restrict__ partial){
  int e = blockIdx.x*256 + threadIdx.x;
  int ly = blockIdx.y;
  int b = blockIdx.z;
  int l0 = ly * 128;
  float s = 0.f;
  for (int l=l0; l<l0+128; l++) s += bf2f(h2[((size_t)(b*Ll + l))*Ee + e]);
  partial[((size_t)(b*32 + ly))*Ee + e] = s;
}
__global__ __launch_bounds__(256) void colmean2_kernel(const float* __restrict__ partial,
    float* __restrict__ xmean){
  int e = blockIdx.x*256 + threadIdx.x;
  int b = blockIdx.y;
  float s = 0.f;
  #pragma unroll
  for (int ly=0; ly<32; ly++) s += partial[((size_t)(b*32 + ly))*Ee + e];
  xmean[b*Ee + e] = s * (1.f/Ll);
}

// ---------------- dim predictor -> floored size ----------------
__global__ __launch_bounds__(256) void dimpred_kernel(const float* __restrict__ xmean,
    const float* __restrict__ w_dp1, const float* __restrict__ w_dp2,
    float* __restrict__ scalars){
  __shared__ float red[256];
  __shared__ float ratio_s[2];
  int t = threadIdx.x;
  for (int b=0;b<2;b++){
    float s = 0.f;
    for (int k=0;k<1024;k++) s += xmean[b*Ee + k] * w_dp1[k*256 + t];
    float sil = s * (1.f/(1.f+expf(-s)));
    red[t] = sil * w_dp2[t];
    __syncthreads();
    for (int off=128; off>0; off>>=1){
      if (t<off) red[t] += red[t+off];
      __syncthreads();
    }
    if (t==0){
      float dr = 1.f/(1.f+expf(-red[0]));
      float ratio = 1.f + (dr-0.5f)*1.0f;       // 2*ADAPT = 1
      ratio = fminf(fmaxf(ratio, 0.5f), 1.5f);
      ratio_s[b] = ratio;
    }
    __syncthreads();
  }
  if (t==0){
    float rm = 0.5f*(ratio_s[0]+ratio_s[1]);
    float size_f = floorf(3072.f * rm);
    if (size_f < 1.f) size_f = 1.f;
    scalars[0] = size_f;
  }
}

// ---------------- per-row sumsq of hidden -> inv_rms ----------------
__global__ __launch_bounds__(256) void rowrms_kernel(const unsigned short* __restrict__ Hid,
    const float* __restrict__ scal, float* __restrict__ invr){
  int row = blockIdx.x; int t = threadIdx.x;
  float ss = 0.f;
  for (int c8 = t; c8 < Ff/8; c8 += 256){
    bf16x8 v = *(const bf16x8*)(Hid + (size_t)row*Ff + c8*8);
    #pragma unroll
    for (int u=0;u<8;u++){ float f = bf2f((unsigned short)v[u]); ss += f*f; }
  }
  #pragma unroll
  for (int off=32; off>0; off>>=1) ss += __shfl_down(ss, off);
  __shared__ float red[4];
  if ((t&63)==0) red[t>>6] = ss;
  __syncthreads();
  if (t==0){
    float tot = red[0]+red[1]+red[2]+red[3];
    float rms = sqrtf(tot/scal[0] + 1e-6f);
    rms = fminf(fmaxf(rms, 1e-6f), 1e6f);
    invr[row] = 1.f/rms;
  }
}

extern "C" void kernel_launch(void* const* d_in, const int* in_sizes, int n_in,
                              void* d_out, int out_size, void* d_ws, size_t ws_size,
                              hipStream_t stream){
  const float* x      = (const float*)d_in[0];
  const float* w_qkv  = (const float*)d_in[1];
  const float* w_out  = (const float*)d_in[2];
  const float* g1     = (const float*)d_in[3];
  const float* g2     = (const float*)d_in[4];
  const float* w_dp1  = (const float*)d_in[5];
  const float* w_dp2  = (const float*)d_in[6];
  const float* w_gate = (const float*)d_in[7];
  const float* w_up   = (const float*)d_in[8];
  const float* w_down = (const float*)d_in[9];
  const float* g_hid  = (const float*)d_in[10];
  float* out = (float*)d_out;

  char* w = (char*)d_ws;
  size_t o = 0;
  auto alloc = [&](size_t bytes)->char*{ char* p = w + o; o += (bytes + 255) & ~255ull; return p; };
  unsigned short* R1   = (unsigned short*)alloc((size_t)8192*1024*2);   // h/attn/h2 bf16
  float*          x2   = (float*)alloc((size_t)8192*1024*4);            // post-attn residual fp32
  char*           R2   = alloc((size_t)8192*4608*2);                    // qkv bf16 (48MB) then hidden (75.5MB)
  unsigned short* qkvT = (unsigned short*)alloc((size_t)3072*1024*2);
  unsigned short* outT = (unsigned short*)alloc((size_t)1024*1024*2);
  char*           W2   = alloc((size_t)3*4608*1024*2);                  // Ssum/Spre then gateT/upT/downT
  float*       partial = (float*)alloc((size_t)64*1024*4);
  float*         xmean = (float*)alloc(2048*4);
  float*          scal = (float*)alloc(64);
  float*          invr = (float*)alloc(8192*4);

  unsigned short* qkv    = (unsigned short*)R2;
  unsigned short* hidden = (unsigned short*)R2;
  float* Ssum = (float*)W2;
  float* Spre = Ssum + (size_t)512*4160;
  unsigned short* gateT = (unsigned short*)W2;
  unsigned short* upT   = gateT + (size_t)4608*1024;
  unsigned short* downT = upT   + (size_t)4608*1024;

  // weights needed early
  wconv_kernel<<<dim3(3072/64, 1024/64),256,0,stream>>>(w_qkv, qkvT, 1024, 3072, nullptr);
  wconv_kernel<<<dim3(1024/64, 1024/64),256,0,stream>>>(w_out, outT, 1024, 1024, nullptr);

  rmsnorm_kernel<<<8192,256,0,stream>>>(x, g1, R1);
  gemm_kernel<0><<<dim3(3072/128, 8192/128),256,0,stream>>>(R1, qkvT, qkv,
      8192,3072,1024, nullptr,nullptr);
  rope_kernel<<<16384,256,0,stream>>>(qkv);
  chunksum_kernel<<<dim3(NCc,Bb*Hh),256,0,stream>>>(qkv, Ssum);
  prefix_kernel<<<Bb*Hh,256,0,stream>>>(Ssum, Spre);
  attnout_kernel<<<dim3(NCc,Bb*Hh),256,0,stream>>>(qkv, Spre, R1);

  // Ssum/Spre dead now: convert FFN weights into W2
  wconv_kernel<<<dim3(4608/64, 1024/64),256,0,stream>>>(w_gate, gateT, 1024, 4608, nullptr);
  wconv_kernel<<<dim3(4608/64, 1024/64),256,0,stream>>>(w_up,   upT,   1024, 4608, nullptr);
  wconv_kernel<<<dim3(1024/64, 4608/64),256,0,stream>>>(w_down, downT, 4608, 1024, g_hid);

  gemm_kernel<1><<<dim3(1024/128, 8192/128),256,0,stream>>>(R1, outT, x2,
      8192,1024,1024, x,nullptr);
  rmsnorm_kernel<<<8192,256,0,stream>>>(x2, g2, R1);
  colmean1_kernel<<<dim3(4,32,2),256,0,stream>>>(R1, partial);
  colmean2_kernel<<<dim3(4,2),256,0,stream>>>(partial, xmean);
  dimpred_kernel<<<1,256,0,stream>>>(xmean, w_dp1, w_dp2, scal);
  gateup_kernel<<<dim3(4608/128, 8192/128),256,0,stream>>>(R1, gateT, upT, hidden, scal);
  rowrms_kernel<<<8192,256,0,stream>>>(hidden, scal, invr);
  gemm_kernel<2><<<dim3(1024/128, 8192/128),256,0,stream>>>(hidden, downT, out,
      8192,1024,4608, x2, invr);
}

// Round 5
// 825.338 us; speedup vs baseline: 1.5936x; 1.1602x over previous
//
#include <hip/hip_runtime.h>
#include <hip/hip_bf16.h>

#define Ee 1024
#define Hh 16
#define Ff 4608
#define Ll 4096
#define Bb 2
#define NCc 16
#define CHk 256

typedef short bf16x8 __attribute__((ext_vector_type(8)));
typedef float f32x4 __attribute__((ext_vector_type(4)));

#define GLD16(g, l) __builtin_amdgcn_global_load_lds( \
    (const __attribute__((address_space(1))) unsigned int*)(g), \
    (__attribute__((address_space(3))) unsigned int*)(l), 16, 0, 0)

__device__ __forceinline__ unsigned short f2bf(float f){
  unsigned int u = __builtin_bit_cast(unsigned int, f);
  u += 0x7fffu + ((u >> 16) & 1u);
  return (unsigned short)(u >> 16);
}
__device__ __forceinline__ float bf2f(unsigned short h){
  unsigned int u = ((unsigned int)h) << 16;
  return __builtin_bit_cast(float, u);
}
__device__ __forceinline__ float fixv(float v){
  return (__builtin_isnan(v) || __builtin_isinf(v)) ? 0.f : v;
}

// ---------------- weight convert+transpose: W[K][N] fp32 -> WT[N][K] bf16 ----------------
__global__ __launch_bounds__(256) void wconv_kernel(const float* __restrict__ W,
    unsigned short* __restrict__ WT, int K, int N, const float* __restrict__ scale){
  __shared__ unsigned short T[64][72];
  int k0 = blockIdx.y*64, n0 = blockIdx.x*64;
  int t = threadIdx.x;
  int kr = t>>4, n4 = (t&15)*4;
  #pragma unroll
  for (int it=0; it<4; it++){
    int k = kr + it*16;
    float s = scale ? scale[k0+k] : 1.f;
    float4 v = *(const float4*)(W + (size_t)(k0+k)*N + n0 + n4);
    T[n4+0][k] = f2bf(v.x*s);
    T[n4+1][k] = f2bf(v.y*s);
    T[n4+2][k] = f2bf(v.z*s);
    T[n4+3][k] = f2bf(v.w*s);
  }
  __syncthreads();
  int u = t&7;
  #pragma unroll
  for (int it=0; it<2; it++){
    int n = (t>>3) + it*32;
    *(bf16x8*)(WT + (size_t)(n0+n)*K + k0 + u*8) = *(const bf16x8*)&T[n][u*8];
  }
}

// ---------------- RMSNorm fp32 in -> bf16 out ----------------
__global__ __launch_bounds__(256) void rmsnorm_kernel(const float* __restrict__ x,
    const float* __restrict__ g, unsigned short* __restrict__ out){
  int row = blockIdx.x; int t = threadIdx.x;
  float4 v = ((const float4*)(x + (size_t)row*Ee))[t];
  v.x=fixv(v.x); v.y=fixv(v.y); v.z=fixv(v.z); v.w=fixv(v.w);
  float ss = v.x*v.x + v.y*v.y + v.z*v.z + v.w*v.w;
  #pragma unroll
  for (int off=32; off>0; off>>=1) ss += __shfl_down(ss, off);
  __shared__ float red[4];
  if ((t&63)==0) red[t>>6] = ss;
  __syncthreads();
  float tot = red[0]+red[1]+red[2]+red[3];
  float rms = sqrtf(tot*(1.f/Ee) + 1e-6f);
  rms = fminf(fmaxf(rms, 1e-6f), 1e6f);
  float inv = 1.f/rms;
  float4 gv = ((const float4*)g)[t];
  uint2 o;
  o.x = (unsigned)f2bf(v.x*inv*gv.x) | ((unsigned)f2bf(v.y*inv*gv.y)<<16);
  o.y = (unsigned)f2bf(v.z*inv*gv.z) | ((unsigned)f2bf(v.w*inv*gv.w)<<16);
  ((uint2*)(out + (size_t)row*Ee))[t] = o;
}

// ---------------- bf16 GEMM: C[M,N] = A[M,K] @ Bt[N,K]^T ----------------
// global_load_lds staging, double-buffered 2-phase pipeline.
// MODE 0: C bf16. MODE 1: C fp32 = acc + res. MODE 2: C fp32 = acc*rowscale[m] + res,
//         and K-loop truncated to round_up(klim[0], 32) (zero columns beyond).
template<int MODE>
__global__ __launch_bounds__(256) void gemm_kernel(
    const unsigned short* __restrict__ A, const unsigned short* __restrict__ Bt,
    void* __restrict__ Cv, int M, int N, int K,
    const float* __restrict__ res, const float* __restrict__ rowscale,
    const float* __restrict__ klim){
  __shared__ __align__(16) unsigned short As[2][4096];
  __shared__ __align__(16) unsigned short Bs[2][4096];
  int tid = threadIdx.x;
  int nbx = gridDim.x;
  int id = blockIdx.y * nbx + blockIdx.x;
  int chunk = (nbx * gridDim.y) >> 3;
  int wg = (id & 7) * chunk + (id >> 3);
  int m0 = (wg / nbx) * 128, n0 = (wg % nbx) * 128;
  int lane = tid & 63, wave = tid >> 6;
  int wm = (wave>>1)*64, wn = (wave&1)*64;
  int lrow = lane & 15, lk = (lane>>4)*8;
  int kend = K;
  if (MODE==2 && klim){
    int sz = (int)klim[0];
    int ke = ((sz + 31) >> 5) << 5;
    kend = ke < K ? ke : K;
  }
  int nk = kend >> 5;
  // staging geometry: wave w fills segments 2w, 2w+1 of each 8KB tile
  int s0 = wave*2, s1 = s0+1;
  int r0 = s0*16 + (lane>>2), r1 = s1*16 + (lane>>2);
  int cg = (lane&3)*8;
  const unsigned short* a0 = A  + (size_t)(m0+r0)*K + cg;
  const unsigned short* a1 = A  + (size_t)(m0+r1)*K + cg;
  const unsigned short* b0 = Bt + (size_t)(n0+r0)*K + cg;
  const unsigned short* b1 = Bt + (size_t)(n0+r1)*K + cg;
  f32x4 acc[4][4] = {};
  GLD16(a0, &As[0][s0*512]); GLD16(a1, &As[0][s1*512]);
  GLD16(b0, &Bs[0][s0*512]); GLD16(b1, &Bs[0][s1*512]);
  __syncthreads();
  int cur = 0;
  for (int t=0; t<nk; ++t){
    if (t+1 < nk){
      int ko = (t+1) << 5;
      GLD16(a0+ko, &As[cur^1][s0*512]); GLD16(a1+ko, &As[cur^1][s1*512]);
      GLD16(b0+ko, &Bs[cur^1][s0*512]); GLD16(b1+ko, &Bs[cur^1][s1*512]);
    }
    bf16x8 af[4], bfr[4];
    #pragma unroll
    for (int i=0;i<4;i++){
      af[i]  = *(const bf16x8*)&As[cur][(wm + i*16 + lrow)*32 + lk];
      bfr[i] = *(const bf16x8*)&Bs[cur][(wn + i*16 + lrow)*32 + lk];
    }
    #pragma unroll
    for (int mi=0;mi<4;mi++)
      #pragma unroll
      for (int ni=0;ni<4;ni++)
        acc[mi][ni] = __builtin_amdgcn_mfma_f32_16x16x32_bf16(af[mi], bfr[ni], acc[mi][ni], 0,0,0);
    __syncthreads();
    cur ^= 1;
  }
  int rbase = m0 + wm + ((lane>>4)<<2);
  int cbase = n0 + wn + (lane&15);
  #pragma unroll
  for (int mi=0;mi<4;mi++){
    #pragma unroll
    for (int r=0;r<4;r++){
      int row = rbase + mi*16 + r;
      float rs = (MODE==2) ? rowscale[row] : 1.f;
      #pragma unroll
      for (int ni=0;ni<4;ni++){
        int col = cbase + ni*16;
        float v = acc[mi][ni][r];
        if (MODE==0){
          ((unsigned short*)Cv)[(size_t)row*N + col] = f2bf(v);
        } else if (MODE==1){
          ((float*)Cv)[(size_t)row*N + col] = v + res[(size_t)row*N + col];
        } else {
          ((float*)Cv)[(size_t)row*N + col] = v*rs + res[(size_t)row*N + col];
        }
      }
    }
  }
}

// ---------------- fused gate+up GEMM (128x128) -> hidden = silu(g)*u masked ----------------
// Blocks entirely beyond size skip the K-loop and zero-fill.
__global__ __launch_bounds__(256) void gateup_kernel(
    const unsigned short* __restrict__ A, const unsigned short* __restrict__ Gt,
    const unsigned short* __restrict__ Ut, unsigned short* __restrict__ Hid,
    const float* __restrict__ scal){
  __shared__ __align__(16) unsigned short As[2][4096];
  __shared__ __align__(16) unsigned short Bg[2][4096];
  __shared__ __align__(16) unsigned short Bu[2][4096];
  int tid = threadIdx.x;
  int nbx = gridDim.x;
  int id = blockIdx.y * nbx + blockIdx.x;
  int chunk = (nbx * gridDim.y) >> 3;
  int wg = (id & 7) * chunk + (id >> 3);
  int m0 = (wg / nbx) * 128, n0 = (wg % nbx) * 128;
  int size = (int)scal[0];
  if (n0 >= size){
    // entire tile is masked out: write zeros (needed once per call for rowrms/down)
    int r = tid >> 1, cb = n0 + (tid&1)*64;
    unsigned short* hp = Hid + (size_t)(m0+r)*Ff + cb;
    bf16x8 z = {};
    #pragma unroll
    for (int i=0;i<8;i++) *(bf16x8*)(hp + i*8) = z;
    return;
  }
  int lane = tid & 63, wave = tid >> 6;
  int wm = (wave>>1)*64, wn = (wave&1)*64;
  int lrow = lane & 15, lk = (lane>>4)*8;
  int s0 = wave*2, s1 = s0+1;
  int r0 = s0*16 + (lane>>2), r1 = s1*16 + (lane>>2);
  int cg = (lane&3)*8;
  const unsigned short* a0 = A  + (size_t)(m0+r0)*Ee + cg;
  const unsigned short* a1 = A  + (size_t)(m0+r1)*Ee + cg;
  const unsigned short* g0 = Gt + (size_t)(n0+r0)*Ee + cg;
  const unsigned short* g1p= Gt + (size_t)(n0+r1)*Ee + cg;
  const unsigned short* u0 = Ut + (size_t)(n0+r0)*Ee + cg;
  const unsigned short* u1 = Ut + (size_t)(n0+r1)*Ee + cg;
  f32x4 ag[4][4] = {}, au[4][4] = {};
  GLD16(a0, &As[0][s0*512]); GLD16(a1, &As[0][s1*512]);
  GLD16(g0, &Bg[0][s0*512]); GLD16(g1p,&Bg[0][s1*512]);
  GLD16(u0, &Bu[0][s0*512]); GLD16(u1, &Bu[0][s1*512]);
  __syncthreads();
  int cur = 0;
  for (int t=0; t<32; ++t){
    if (t+1 < 32){
      int ko = (t+1) << 5;
      GLD16(a0+ko, &As[cur^1][s0*512]); GLD16(a1+ko, &As[cur^1][s1*512]);
      GLD16(g0+ko, &Bg[cur^1][s0*512]); GLD16(g1p+ko,&Bg[cur^1][s1*512]);
      GLD16(u0+ko, &Bu[cur^1][s0*512]); GLD16(u1+ko, &Bu[cur^1][s1*512]);
    }
    bf16x8 af[4], bg4[4], bu4[4];
    #pragma unroll
    for (int i=0;i<4;i++){
      af[i]  = *(const bf16x8*)&As[cur][(wm + i*16 + lrow)*32 + lk];
      bg4[i] = *(const bf16x8*)&Bg[cur][(wn + i*16 + lrow)*32 + lk];
      bu4[i] = *(const bf16x8*)&Bu[cur][(wn + i*16 + lrow)*32 + lk];
    }
    #pragma unroll
    for (int mi=0;mi<4;mi++)
      #pragma unroll
      for (int ni=0;ni<4;ni++){
        ag[mi][ni] = __builtin_amdgcn_mfma_f32_16x16x32_bf16(af[mi], bg4[ni], ag[mi][ni], 0,0,0);
        au[mi][ni] = __builtin_amdgcn_mfma_f32_16x16x32_bf16(af[mi], bu4[ni], au[mi][ni], 0,0,0);
      }
    __syncthreads();
    cur ^= 1;
  }
  int rbase = m0 + wm + ((lane>>4)<<2);
  int cbase = n0 + wn + (lane&15);
  #pragma unroll
  for (int mi=0;mi<4;mi++){
    #pragma unroll
    for (int r=0;r<4;r++){
      int row = rbase + mi*16 + r;
      #pragma unroll
      for (int ni=0;ni<4;ni++){
        int col = cbase + ni*16;
        float g = ag[mi][ni][r], u = au[mi][ni][r];
        float hv = (g * (1.f/(1.f+expf(-g)))) * u;
        if (col >= size) hv = 0.f;
        if (__builtin_isnan(hv) || __builtin_isinf(hv)) hv = 0.f;
        Hid[(size_t)row*Ff + col] = f2bf(hv);
      }
    }
  }
}

// ---------------- RoPE + ELU+1 on q,k in bf16 qkv ----------------
__global__ __launch_bounds__(256) void rope_kernel(unsigned short* __restrict__ qkv){
  size_t idx = (size_t)blockIdx.x*256 + threadIdx.x;    // B*L*H*32
  int i = (int)(idx & 31);
  int h = (int)((idx>>5) & 15);
  size_t bl = idx >> 9;
  int pos = (int)(bl & (Ll-1));
  int d0 = 2*i, d1 = d0+1;
  size_t base = bl*3072 + (size_t)h*64 + d0;
  const float LOG1E4_D32 = 0.2878231366242557f;  // ln(10000)/32
  float e0 = (float)(d0 < 32 ? d0 : d0-32);
  float e1 = (float)(d1 < 32 ? d1 : d1-32);
  float f0 = pos * expf(-e0*LOG1E4_D32);
  float f1 = pos * expf(-e1*LOG1E4_D32);
  float s0,c0,s1,c1;
  sincosf(f0,&s0,&c0); sincosf(f1,&s1,&c1);
  unsigned int* qp = (unsigned int*)(qkv + base);
  unsigned int qv = *qp;
  float q0 = bf2f((unsigned short)(qv&0xffff)), q1 = bf2f((unsigned short)(qv>>16));
  float r0 = q0*c0 - q1*s0;
  float r1 = q1*c1 + q0*s1;
  r0 = r0>0.f ? r0+1.f : expf(r0);
  r1 = r1>0.f ? r1+1.f : expf(r1);
  *qp = (unsigned)f2bf(r0) | ((unsigned)f2bf(r1)<<16);
  unsigned int* kp = (unsigned int*)(qkv + base + 1024);
  unsigned int kv = *kp;
  float k0v = bf2f((unsigned short)(kv&0xffff)), k1v = bf2f((unsigned short)(kv>>16));
  float t0 = k0v*c0 - k1v*s0;
  float t1 = k1v*c1 + k0v*s1;
  t0 = t0>0.f ? t0+1.f : expf(t0);
  t1 = t1>0.f ? t1+1.f : expf(t1);
  *kp = (unsigned)f2bf(t0) | ((unsigned)f2bf(t1)<<16);
}

// ---------------- per-chunk K^T V (64x64) + K col sums; 2-pass LDS ----------------
__global__ __launch_bounds__(256) void chunksum_kernel(const unsigned short* __restrict__ qkv,
    float* __restrict__ Ssum){
  int c = blockIdx.x, bh = blockIdx.y;
  int b = bh >> 4, h = bh & 15;
  __shared__ __align__(16) unsigned short Ks[128][64];
  __shared__ __align__(16) unsigned short Vs[128][64];
  int t = threadIdx.x;
  int j = t >> 2, dg = (t&3)*16;
  float acc[16] = {}; float zacc = 0.f;
  for (int p=0;p<2;p++){
    __syncthreads();
    #pragma unroll
    for (int it=0; it<4; it++){
      int flat = it*256 + t;
      int row = flat >> 3, colg = (flat & 7)*8;
      size_t g = ((size_t)(b*Ll + c*CHk + p*128 + row))*3072 + h*64 + colg;
      *(bf16x8*)&Ks[row][colg] = *(const bf16x8*)(qkv + g + 1024);
      *(bf16x8*)&Vs[row][colg] = *(const bf16x8*)(qkv + g + 2048);
    }
    __syncthreads();
    for (int m=0;m<128;m++){
      float kv = bf2f(Ks[m][j]);
      zacc += kv;
      #pragma unroll
      for (int q8=0;q8<2;q8++){
        bf16x8 vv = *(const bf16x8*)&Vs[m][dg + q8*8];
        #pragma unroll
        for (int u=0;u<8;u++) acc[q8*8+u] += kv * bf2f((unsigned short)vv[u]);
      }
    }
  }
  float* S = Ssum + ((size_t)bh*NCc + c)*4160;
  #pragma unroll
  for (int d=0;d<16;d++) S[j*64 + dg + d] = acc[d];
  if ((t&3)==0) S[4096 + j] = zacc;
}

// ---------------- exclusive prefix over chunks ----------------
__global__ __launch_bounds__(256) void prefix_kernel(const float* __restrict__ Ssum,
    float* __restrict__ Spre){
  int bh = blockIdx.x; int t = threadIdx.x;
  size_t base = (size_t)bh*NCc*4160;
  for (int e=t; e<4160; e+=256){
    float acc = 0.f;
    #pragma unroll
    for (int c=0;c<NCc;c++){
      Spre[base + (size_t)c*4160 + e] = acc;
      acc += Ssum[base + (size_t)c*4160 + e];
    }
  }
}

// ---------------- per-chunk causal attention; 2-pass LDS ----------------
__global__ __launch_bounds__(256) void attnout_kernel(const unsigned short* __restrict__ qkv,
    const float* __restrict__ Spre, unsigned short* __restrict__ attn){
  int c = blockIdx.x, bh = blockIdx.y;
  int b = bh >> 4, h = bh & 15;
  __shared__ __align__(16) unsigned short Ks[128][64];
  __shared__ __align__(16) unsigned short Vs[128][64];
  int t = threadIdx.x;
  int wave = t >> 6;
  float q[64];
  size_t qg = ((size_t)(b*Ll + c*CHk + t))*3072 + (size_t)h*64;
  #pragma unroll
  for (int g8=0; g8<8; g8++){
    bf16x8 v = *(const bf16x8*)(qkv + qg + g8*8);
    #pragma unroll
    for (int u=0;u<8;u++) q[g8*8+u] = bf2f((unsigned short)v[u]);
  }
  const float* Sp = Spre + ((size_t)bh*NCc + c)*4160;
  float num[64];
  #pragma unroll
  for (int d=0;d<64;d++) num[d]=0.f;
  for (int j=0;j<64;j++){
    float qj = q[j];
    const float* Sr = Sp + j*64;
    #pragma unroll
    for (int d4=0; d4<16; d4++){
      float4 sv = *(const float4*)(Sr + d4*4);
      num[d4*4+0] += qj*sv.x; num[d4*4+1] += qj*sv.y;
      num[d4*4+2] += qj*sv.z; num[d4*4+3] += qj*sv.w;
    }
  }
  float den = 0.f;
  #pragma unroll
  for (int j=0;j<64;j++) den += q[j]*Sp[4096+j];
  for (int p=0;p<2;p++){
    __syncthreads();
    #pragma unroll
    for (int it=0; it<4; it++){
      int flat = it*256 + t;
      int row = flat >> 3, colg = (flat & 7)*8;
      size_t g = ((size_t)(b*Ll + c*CHk + p*128 + row))*3072 + h*64 + colg;
      *(bf16x8*)&Ks[row][colg] = *(const bf16x8*)(qkv + g + 1024);
      *(bf16x8*)&Vs[row][colg] = *(const bf16x8*)(qkv + g + 2048);
    }
    __syncthreads();
    int wtop = wave*64 + 63;
    if (wtop >= p*128){
      int wlim = wtop - p*128; if (wlim > 127) wlim = 127;
      int lim = t - p*128;
      for (int m=0; m<=wlim; m++){
        float qk = 0.f;
        #pragma unroll
        for (int g8=0; g8<8; g8++){
          bf16x8 kv8 = *(const bf16x8*)&Ks[m][g8*8];
          #pragma unroll
          for (int u=0;u<8;u++) qk += q[g8*8+u]*bf2f((unsigned short)kv8[u]);
        }
        float qkm = (m <= lim) ? qk : 0.f;
        den += qkm;
        #pragma unroll
        for (int g8=0; g8<8; g8++){
          bf16x8 vv8 = *(const bf16x8*)&Vs[m][g8*8];
          #pragma unroll
          for (int u=0;u<8;u++) num[g8*8+u] += qkm*bf2f((unsigned short)vv8[u]);
        }
      }
    }
  }
  den = fmaxf(den, 1e-6f);
  float inv = 1.f/den;
  unsigned short* o = attn + ((size_t)(b*Ll + c*CHk + t))*Ee + (size_t)h*64;
  #pragma unroll
  for (int g8=0; g8<8; g8++){
    bf16x8 ov;
    #pragma unroll
    for (int u=0;u<8;u++) ov[u] = (short)f2bf(num[g8*8+u]*inv);
    *(bf16x8*)(o + g8*8) = ov;
  }
}

// ---------------- column mean over L, deterministic 2-stage ----------------
__global__ __launch_bounds__(256) void colmean1_kernel(const unsigned short* __restrict__ h2,
    float* __restrict__ partial){
  int e = blockIdx.x*256 + threadIdx.x;
  int ly = blockIdx.y;
  int b = blockIdx.z;
  int l0 = ly * 128;
  float s = 0.f;
  for (int l=l0; l<l0+128; l++) s += bf2f(h2[((size_t)(b*Ll + l))*Ee + e]);
  partial[((size_t)(b*32 + ly))*Ee + e] = s;
}
__global__ __launch_bounds__(256) void colmean2_kernel(const float* __restrict__ partial,
    float* __restrict__ xmean){
  int e = blockIdx.x*256 + threadIdx.x;
  int b = blockIdx.y;
  float s = 0.f;
  #pragma unroll
  for (int ly=0; ly<32; ly++) s += partial[((size_t)(b*32 + ly))*Ee + e];
  xmean[b*Ee + e] = s * (1.f/Ll);
}

// ---------------- dim predictor -> floored size ----------------
__global__ __launch_bounds__(256) void dimpred_kernel(const float* __restrict__ xmean,
    const float* __restrict__ w_dp1, const float* __restrict__ w_dp2,
    float* __restrict__ scalars){
  __shared__ float red[256];
  __shared__ float ratio_s[2];
  int t = threadIdx.x;
  for (int b=0;b<2;b++){
    float s = 0.f;
    for (int k=0;k<1024;k++) s += xmean[b*Ee + k] * w_dp1[k*256 + t];
    float sil = s * (1.f/(1.f+expf(-s)));
    red[t] = sil * w_dp2[t];
    __syncthreads();
    for (int off=128; off>0; off>>=1){
      if (t<off) red[t] += red[t+off];
      __syncthreads();
    }
    if (t==0){
      float dr = 1.f/(1.f+expf(-red[0]));
      float ratio = 1.f + (dr-0.5f)*1.0f;       // 2*ADAPT = 1
      ratio = fminf(fmaxf(ratio, 0.5f), 1.5f);
      ratio_s[b] = ratio;
    }
    __syncthreads();
  }
  if (t==0){
    float rm = 0.5f*(ratio_s[0]+ratio_s[1]);
    float size_f = floorf(3072.f * rm);
    if (size_f < 1.f) size_f = 1.f;
    scalars[0] = size_f;
  }
}

// ---------------- per-row sumsq of hidden -> inv_rms ----------------
__global__ __launch_bounds__(256) void rowrms_kernel(const unsigned short* __restrict__ Hid,
    const float* __restrict__ scal, float* __restrict__ invr){
  int row = blockIdx.x; int t = threadIdx.x;
  float size_f = scal[0];
  int c8max = ((int)size_f + 7) >> 3;
  float ss = 0.f;
  for (int c8 = t; c8 < c8max; c8 += 256){
    bf16x8 v = *(const bf16x8*)(Hid + (size_t)row*Ff + c8*8);
    #pragma unroll
    for (int u=0;u<8;u++){ float f = bf2f((unsigned short)v[u]); ss += f*f; }
  }
  #pragma unroll
  for (int off=32; off>0; off>>=1) ss += __shfl_down(ss, off);
  __shared__ float red[4];
  if ((t&63)==0) red[t>>6] = ss;
  __syncthreads();
  if (t==0){
    float tot = red[0]+red[1]+red[2]+red[3];
    float rms = sqrtf(tot/size_f + 1e-6f);
    rms = fminf(fmaxf(rms, 1e-6f), 1e6f);
    invr[row] = 1.f/rms;
  }
}

extern "C" void kernel_launch(void* const* d_in, const int* in_sizes, int n_in,
                              void* d_out, int out_size, void* d_ws, size_t ws_size,
                              hipStream_t stream){
  const float* x      = (const float*)d_in[0];
  const float* w_qkv  = (const float*)d_in[1];
  const float* w_out  = (const float*)d_in[2];
  const float* g1     = (const float*)d_in[3];
  const float* g2     = (const float*)d_in[4];
  const float* w_dp1  = (const float*)d_in[5];
  const float* w_dp2  = (const float*)d_in[6];
  const float* w_gate = (const float*)d_in[7];
  const float* w_up   = (const float*)d_in[8];
  const float* w_down = (const float*)d_in[9];
  const float* g_hid  = (const float*)d_in[10];
  float* out = (float*)d_out;

  char* w = (char*)d_ws;
  size_t o = 0;
  auto alloc = [&](size_t bytes)->char*{ char* p = w + o; o += (bytes + 255) & ~255ull; return p; };
  unsigned short* R1   = (unsigned short*)alloc((size_t)8192*1024*2);   // h/attn/h2 bf16
  float*          x2   = (float*)alloc((size_t)8192*1024*4);            // post-attn residual fp32
  char*           R2   = alloc((size_t)8192*4608*2);                    // qkv bf16 (48MB) then hidden (75.5MB)
  unsigned short* qkvT = (unsigned short*)alloc((size_t)3072*1024*2);
  unsigned short* outT = (unsigned short*)alloc((size_t)1024*1024*2);
  char*           W2   = alloc((size_t)3*4608*1024*2);                  // Ssum/Spre then gateT/upT/downT
  float*       partial = (float*)alloc((size_t)64*1024*4);
  float*         xmean = (float*)alloc(2048*4);
  float*          scal = (float*)alloc(64);
  float*          invr = (float*)alloc(8192*4);

  unsigned short* qkv    = (unsigned short*)R2;
  unsigned short* hidden = (unsigned short*)R2;
  float* Ssum = (float*)W2;
  float* Spre = Ssum + (size_t)512*4160;
  unsigned short* gateT = (unsigned short*)W2;
  unsigned short* upT   = gateT + (size_t)4608*1024;
  unsigned short* downT = upT   + (size_t)4608*1024;

  // weights needed early
  wconv_kernel<<<dim3(3072/64, 1024/64),256,0,stream>>>(w_qkv, qkvT, 1024, 3072, nullptr);
  wconv_kernel<<<dim3(1024/64, 1024/64),256,0,stream>>>(w_out, outT, 1024, 1024, nullptr);

  rmsnorm_kernel<<<8192,256,0,stream>>>(x, g1, R1);
  gemm_kernel<0><<<dim3(3072/128, 8192/128),256,0,stream>>>(R1, qkvT, qkv,
      8192,3072,1024, nullptr,nullptr,nullptr);
  rope_kernel<<<16384,256,0,stream>>>(qkv);
  chunksum_kernel<<<dim3(NCc,Bb*Hh),256,0,stream>>>(qkv, Ssum);
  prefix_kernel<<<Bb*Hh,256,0,stream>>>(Ssum, Spre);
  attnout_kernel<<<dim3(NCc,Bb*Hh),256,0,stream>>>(qkv, Spre, R1);

  // Ssum/Spre dead now: convert FFN weights into W2
  wconv_kernel<<<dim3(4608/64, 1024/64),256,0,stream>>>(w_gate, gateT, 1024, 4608, nullptr);
  wconv_kernel<<<dim3(4608/64, 1024/64),256,0,stream>>>(w_up,   upT,   1024, 4608, nullptr);
  wconv_kernel<<<dim3(1024/64, 4608/64),256,0,stream>>>(w_down, downT, 4608, 1024, g_hid);

  gemm_kernel<1><<<dim3(1024/128, 8192/128),256,0,stream>>>(R1, outT, x2,
      8192,1024,1024, x,nullptr,nullptr);
  rmsnorm_kernel<<<8192,256,0,stream>>>(x2, g2, R1);
  colmean1_kernel<<<dim3(4,32,2),256,0,stream>>>(R1, partial);
  colmean2_kernel<<<dim3(4,2),256,0,stream>>>(partial, xmean);
  dimpred_kernel<<<1,256,0,stream>>>(xmean, w_dp1, w_dp2, scal);
  gateup_kernel<<<dim3(4608/128, 8192/128),256,0,stream>>>(R1, gateT, upT, hidden, scal);
  rowrms_kernel<<<8192,256,0,stream>>>(hidden, scal, invr);
  gemm_kernel<2><<<dim3(1024/128, 8192/128),256,0,stream>>>(hidden, downT, out,
      8192,1024,4608, x2, invr, scal);
}

// Round 6
// 569.660 us; speedup vs baseline: 2.3088x; 1.4488x over previous
//
#include <hip/hip_runtime.h>
#include <hip/hip_bf16.h>

#define Ee 1024
#define Hh 16
#define Ff 4608
#define Ll 4096
#define Bb 2
#define NCc 16
#define CHk 256

typedef short bf16x8 __attribute__((ext_vector_type(8)));
typedef float f32x4 __attribute__((ext_vector_type(4)));

#define GLD16(g, l) __builtin_amdgcn_global_load_lds( \
    (const __attribute__((address_space(1))) unsigned int*)(g), \
    (__attribute__((address_space(3))) unsigned int*)(l), 16, 0, 0)

__device__ __forceinline__ unsigned short f2bf(float f){
  unsigned int u = __builtin_bit_cast(unsigned int, f);
  u += 0x7fffu + ((u >> 16) & 1u);
  return (unsigned short)(u >> 16);
}
__device__ __forceinline__ float bf2f(unsigned short h){
  unsigned int u = ((unsigned int)h) << 16;
  return __builtin_bit_cast(float, u);
}
__device__ __forceinline__ float fixv(float v){
  return (__builtin_isnan(v) || __builtin_isinf(v)) ? 0.f : v;
}

// ---------------- weight convert+transpose: W[K][N] fp32 -> WT[N][K] bf16 ----------------
__global__ __launch_bounds__(256) void wconv_kernel(const float* __restrict__ W,
    unsigned short* __restrict__ WT, int K, int N, const float* __restrict__ scale){
  __shared__ unsigned short T[64][72];
  int k0 = blockIdx.y*64, n0 = blockIdx.x*64;
  int t = threadIdx.x;
  int kr = t>>4, n4 = (t&15)*4;
  #pragma unroll
  for (int it=0; it<4; it++){
    int k = kr + it*16;
    float s = scale ? scale[k0+k] : 1.f;
    float4 v = *(const float4*)(W + (size_t)(k0+k)*N + n0 + n4);
    T[n4+0][k] = f2bf(v.x*s);
    T[n4+1][k] = f2bf(v.y*s);
    T[n4+2][k] = f2bf(v.z*s);
    T[n4+3][k] = f2bf(v.w*s);
  }
  __syncthreads();
  int u = t&7;
  #pragma unroll
  for (int it=0; it<2; it++){
    int n = (t>>3) + it*32;
    *(bf16x8*)(WT + (size_t)(n0+n)*K + k0 + u*8) = *(const bf16x8*)&T[n][u*8];
  }
}

// ---------------- RMSNorm fp32 in -> bf16 out ----------------
__global__ __launch_bounds__(256) void rmsnorm_kernel(const float* __restrict__ x,
    const float* __restrict__ g, unsigned short* __restrict__ out){
  int row = blockIdx.x; int t = threadIdx.x;
  float4 v = ((const float4*)(x + (size_t)row*Ee))[t];
  v.x=fixv(v.x); v.y=fixv(v.y); v.z=fixv(v.z); v.w=fixv(v.w);
  float ss = v.x*v.x + v.y*v.y + v.z*v.z + v.w*v.w;
  #pragma unroll
  for (int off=32; off>0; off>>=1) ss += __shfl_down(ss, off);
  __shared__ float red[4];
  if ((t&63)==0) red[t>>6] = ss;
  __syncthreads();
  float tot = red[0]+red[1]+red[2]+red[3];
  float rms = sqrtf(tot*(1.f/Ee) + 1e-6f);
  rms = fminf(fmaxf(rms, 1e-6f), 1e6f);
  float inv = 1.f/rms;
  float4 gv = ((const float4*)g)[t];
  uint2 o;
  o.x = (unsigned)f2bf(v.x*inv*gv.x) | ((unsigned)f2bf(v.y*inv*gv.y)<<16);
  o.y = (unsigned)f2bf(v.z*inv*gv.z) | ((unsigned)f2bf(v.w*inv*gv.w)<<16);
  ((uint2*)(out + (size_t)row*Ee))[t] = o;
}

// ---------------- bf16 GEMM: C[M,N] = A[M,K] @ Bt[N,K]^T ----------------
// MODE 0: C bf16. MODE 1: C fp32 = acc + res. MODE 2: C fp32 = acc*rowscale[m] + res,
//         K-loop truncated to round_up(klim[0], 32).
template<int MODE>
__global__ __launch_bounds__(256) void gemm_kernel(
    const unsigned short* __restrict__ A, const unsigned short* __restrict__ Bt,
    void* __restrict__ Cv, int M, int N, int K,
    const float* __restrict__ res, const float* __restrict__ rowscale,
    const float* __restrict__ klim){
  __shared__ __align__(16) unsigned short As[2][4096];
  __shared__ __align__(16) unsigned short Bs[2][4096];
  int tid = threadIdx.x;
  int nbx = gridDim.x;
  int id = blockIdx.y * nbx + blockIdx.x;
  int chunk = (nbx * gridDim.y) >> 3;
  int wg = (id & 7) * chunk + (id >> 3);
  int m0 = (wg / nbx) * 128, n0 = (wg % nbx) * 128;
  int lane = tid & 63, wave = tid >> 6;
  int wm = (wave>>1)*64, wn = (wave&1)*64;
  int lrow = lane & 15, lk = (lane>>4)*8;
  int kend = K;
  if (MODE==2 && klim){
    int sz = (int)klim[0];
    int ke = ((sz + 31) >> 5) << 5;
    kend = ke < K ? ke : K;
  }
  int nk = kend >> 5;
  int s0 = wave*2, s1 = s0+1;
  int r0 = s0*16 + (lane>>2), r1 = s1*16 + (lane>>2);
  int cg = (lane&3)*8;
  const unsigned short* a0 = A  + (size_t)(m0+r0)*K + cg;
  const unsigned short* a1 = A  + (size_t)(m0+r1)*K + cg;
  const unsigned short* b0 = Bt + (size_t)(n0+r0)*K + cg;
  const unsigned short* b1 = Bt + (size_t)(n0+r1)*K + cg;
  f32x4 acc[4][4] = {};
  GLD16(a0, &As[0][s0*512]); GLD16(a1, &As[0][s1*512]);
  GLD16(b0, &Bs[0][s0*512]); GLD16(b1, &Bs[0][s1*512]);
  __syncthreads();
  int cur = 0;
  for (int t=0; t<nk; ++t){
    if (t+1 < nk){
      int ko = (t+1) << 5;
      GLD16(a0+ko, &As[cur^1][s0*512]); GLD16(a1+ko, &As[cur^1][s1*512]);
      GLD16(b0+ko, &Bs[cur^1][s0*512]); GLD16(b1+ko, &Bs[cur^1][s1*512]);
    }
    bf16x8 af[4], bfr[4];
    #pragma unroll
    for (int i=0;i<4;i++){
      af[i]  = *(const bf16x8*)&As[cur][(wm + i*16 + lrow)*32 + lk];
      bfr[i] = *(const bf16x8*)&Bs[cur][(wn + i*16 + lrow)*32 + lk];
    }
    #pragma unroll
    for (int mi=0;mi<4;mi++)
      #pragma unroll
      for (int ni=0;ni<4;ni++)
        acc[mi][ni] = __builtin_amdgcn_mfma_f32_16x16x32_bf16(af[mi], bfr[ni], acc[mi][ni], 0,0,0);
    __syncthreads();
    cur ^= 1;
  }
  int rbase = m0 + wm + ((lane>>4)<<2);
  int cbase = n0 + wn + (lane&15);
  #pragma unroll
  for (int mi=0;mi<4;mi++){
    #pragma unroll
    for (int r=0;r<4;r++){
      int row = rbase + mi*16 + r;
      float rs = (MODE==2) ? rowscale[row] : 1.f;
      #pragma unroll
      for (int ni=0;ni<4;ni++){
        int col = cbase + ni*16;
        float v = acc[mi][ni][r];
        if (MODE==0){
          ((unsigned short*)Cv)[(size_t)row*N + col] = f2bf(v);
        } else if (MODE==1){
          ((float*)Cv)[(size_t)row*N + col] = v + res[(size_t)row*N + col];
        } else {
          ((float*)Cv)[(size_t)row*N + col] = v*rs + res[(size_t)row*N + col];
        }
      }
    }
  }
}

// ---------------- fused gate+up GEMM (128x128) -> hidden = silu(g)*u masked ----------------
__global__ __launch_bounds__(256) void gateup_kernel(
    const unsigned short* __restrict__ A, const unsigned short* __restrict__ Gt,
    const unsigned short* __restrict__ Ut, unsigned short* __restrict__ Hid,
    const float* __restrict__ scal){
  __shared__ __align__(16) unsigned short As[2][4096];
  __shared__ __align__(16) unsigned short Bg[2][4096];
  __shared__ __align__(16) unsigned short Bu[2][4096];
  int tid = threadIdx.x;
  int nbx = gridDim.x;
  int id = blockIdx.y * nbx + blockIdx.x;
  int chunk = (nbx * gridDim.y) >> 3;
  int wg = (id & 7) * chunk + (id >> 3);
  int m0 = (wg / nbx) * 128, n0 = (wg % nbx) * 128;
  int size = (int)scal[0];
  if (n0 >= size){
    int r = tid >> 1, cb = n0 + (tid&1)*64;
    unsigned short* hp = Hid + (size_t)(m0+r)*Ff + cb;
    bf16x8 z = {};
    #pragma unroll
    for (int i=0;i<8;i++) *(bf16x8*)(hp + i*8) = z;
    return;
  }
  int lane = tid & 63, wave = tid >> 6;
  int wm = (wave>>1)*64, wn = (wave&1)*64;
  int lrow = lane & 15, lk = (lane>>4)*8;
  int s0 = wave*2, s1 = s0+1;
  int r0 = s0*16 + (lane>>2), r1 = s1*16 + (lane>>2);
  int cg = (lane&3)*8;
  const unsigned short* a0 = A  + (size_t)(m0+r0)*Ee + cg;
  const unsigned short* a1 = A  + (size_t)(m0+r1)*Ee + cg;
  const unsigned short* g0 = Gt + (size_t)(n0+r0)*Ee + cg;
  const unsigned short* g1p= Gt + (size_t)(n0+r1)*Ee + cg;
  const unsigned short* u0 = Ut + (size_t)(n0+r0)*Ee + cg;
  const unsigned short* u1 = Ut + (size_t)(n0+r1)*Ee + cg;
  f32x4 ag[4][4] = {}, au[4][4] = {};
  GLD16(a0, &As[0][s0*512]); GLD16(a1, &As[0][s1*512]);
  GLD16(g0, &Bg[0][s0*512]); GLD16(g1p,&Bg[0][s1*512]);
  GLD16(u0, &Bu[0][s0*512]); GLD16(u1, &Bu[0][s1*512]);
  __syncthreads();
  int cur = 0;
  for (int t=0; t<32; ++t){
    if (t+1 < 32){
      int ko = (t+1) << 5;
      GLD16(a0+ko, &As[cur^1][s0*512]); GLD16(a1+ko, &As[cur^1][s1*512]);
      GLD16(g0+ko, &Bg[cur^1][s0*512]); GLD16(g1p+ko,&Bg[cur^1][s1*512]);
      GLD16(u0+ko, &Bu[cur^1][s0*512]); GLD16(u1+ko, &Bu[cur^1][s1*512]);
    }
    bf16x8 af[4], bg4[4], bu4[4];
    #pragma unroll
    for (int i=0;i<4;i++){
      af[i]  = *(const bf16x8*)&As[cur][(wm + i*16 + lrow)*32 + lk];
      bg4[i] = *(const bf16x8*)&Bg[cur][(wn + i*16 + lrow)*32 + lk];
      bu4[i] = *(const bf16x8*)&Bu[cur][(wn + i*16 + lrow)*32 + lk];
    }
    #pragma unroll
    for (int mi=0;mi<4;mi++)
      #pragma unroll
      for (int ni=0;ni<4;ni++){
        ag[mi][ni] = __builtin_amdgcn_mfma_f32_16x16x32_bf16(af[mi], bg4[ni], ag[mi][ni], 0,0,0);
        au[mi][ni] = __builtin_amdgcn_mfma_f32_16x16x32_bf16(af[mi], bu4[ni], au[mi][ni], 0,0,0);
      }
    __syncthreads();
    cur ^= 1;
  }
  int rbase = m0 + wm + ((lane>>4)<<2);
  int cbase = n0 + wn + (lane&15);
  #pragma unroll
  for (int mi=0;mi<4;mi++){
    #pragma unroll
    for (int r=0;r<4;r++){
      int row = rbase + mi*16 + r;
      #pragma unroll
      for (int ni=0;ni<4;ni++){
        int col = cbase + ni*16;
        float g = ag[mi][ni][r], u = au[mi][ni][r];
        float hv = (g * (1.f/(1.f+expf(-g)))) * u;
        if (col >= size) hv = 0.f;
        if (__builtin_isnan(hv) || __builtin_isinf(hv)) hv = 0.f;
        Hid[(size_t)row*Ff + col] = f2bf(hv);
      }
    }
  }
}

// ---------------- RoPE + ELU+1 on q,k in bf16 qkv ----------------
__global__ __launch_bounds__(256) void rope_kernel(unsigned short* __restrict__ qkv){
  size_t idx = (size_t)blockIdx.x*256 + threadIdx.x;    // B*L*H*32
  int i = (int)(idx & 31);
  int h = (int)((idx>>5) & 15);
  size_t bl = idx >> 9;
  int pos = (int)(bl & (Ll-1));
  int d0 = 2*i, d1 = d0+1;
  size_t base = bl*3072 + (size_t)h*64 + d0;
  const float LOG1E4_D32 = 0.2878231366242557f;  // ln(10000)/32
  float e0 = (float)(d0 < 32 ? d0 : d0-32);
  float e1 = (float)(d1 < 32 ? d1 : d1-32);
  float f0 = pos * expf(-e0*LOG1E4_D32);
  float f1 = pos * expf(-e1*LOG1E4_D32);
  float s0,c0,s1,c1;
  sincosf(f0,&s0,&c0); sincosf(f1,&s1,&c1);
  unsigned int* qp = (unsigned int*)(qkv + base);
  unsigned int qv = *qp;
  float q0 = bf2f((unsigned short)(qv&0xffff)), q1 = bf2f((unsigned short)(qv>>16));
  float r0 = q0*c0 - q1*s0;
  float r1 = q1*c1 + q0*s1;
  r0 = r0>0.f ? r0+1.f : expf(r0);
  r1 = r1>0.f ? r1+1.f : expf(r1);
  *qp = (unsigned)f2bf(r0) | ((unsigned)f2bf(r1)<<16);
  unsigned int* kp = (unsigned int*)(qkv + base + 1024);
  unsigned int kv = *kp;
  float k0v = bf2f((unsigned short)(kv&0xffff)), k1v = bf2f((unsigned short)(kv>>16));
  float t0 = k0v*c0 - k1v*s0;
  float t1 = k1v*c1 + k0v*s1;
  t0 = t0>0.f ? t0+1.f : expf(t0);
  t1 = t1>0.f ? t1+1.f : expf(t1);
  *kp = (unsigned)f2bf(t0) | ((unsigned)f2bf(t1)<<16);
}

// ---------------- per-chunk K^T V + K col sums via MFMA (ones-column trick) ----------------
__global__ __launch_bounds__(256) void chunksum_kernel(const unsigned short* __restrict__ qkv,
    float* __restrict__ Ssum){
  __shared__ __align__(16) unsigned short Kt[64][72];   // K^T[j][m]
  __shared__ __align__(16) unsigned short Vt[80][72];   // V^T[e][m]; row64=1.0, 65..79=0
  int c = blockIdx.x, bh = blockIdx.y;
  int b = bh >> 4, h = bh & 15;
  int tid = threadIdx.x, lane = tid & 63, wave = tid >> 6;
  int lr = lane & 15, lg = lane >> 4;
  f32x4 acc[5] = {};
  {
    int r16 = tid >> 4, m4 = (tid & 15) * 4;
    unsigned short val = (r16 == 0) ? (unsigned short)0x3F80 : (unsigned short)0;
    #pragma unroll
    for (int u=0; u<4; u++) Vt[64 + r16][m4 + u] = val;
  }
  for (int t=0; t<4; ++t){
    __syncthreads();
    #pragma unroll
    for (int i=0; i<2; i++){
      int tau = tid + i*256;
      int m = tau & 63, dg = (tau >> 6) * 8;
      size_t g = ((size_t)(b*Ll + c*CHk + t*64 + m))*3072 + h*64 + dg;
      bf16x8 kv = *(const bf16x8*)(qkv + g + 1024);
      bf16x8 vv = *(const bf16x8*)(qkv + g + 2048);
      #pragma unroll
      for (int u=0; u<8; u++){
        Kt[dg+u][m] = (unsigned short)kv[u];
        Vt[dg+u][m] = (unsigned short)vv[u];
      }
    }
    __syncthreads();
    #pragma unroll
    for (int kk=0; kk<2; kk++){
      bf16x8 af = *(const bf16x8*)&Kt[wave*16 + lr][kk*32 + lg*8];
      #pragma unroll
      for (int ni=0; ni<5; ni++){
        bf16x8 vf = *(const bf16x8*)&Vt[ni*16 + lr][kk*32 + lg*8];
        acc[ni] = __builtin_amdgcn_mfma_f32_16x16x32_bf16(af, vf, acc[ni], 0,0,0);
      }
    }
  }
  float* S = Ssum + ((size_t)bh*NCc + c)*4160;
  int j = wave*16 + lg*4;
  #pragma unroll
  for (int ni=0; ni<4; ni++)
    #pragma unroll
    for (int r=0; r<4; r++)
      S[(size_t)(j+r)*64 + ni*16 + lr] = acc[ni][r];
  if (lr == 0){
    #pragma unroll
    for (int r=0; r<4; r++) S[4096 + j + r] = acc[4][r];
  }
}

// ---------------- exclusive prefix over chunks ----------------
__global__ __launch_bounds__(256) void prefix_kernel(const float* __restrict__ Ssum,
    float* __restrict__ Spre){
  int bh = blockIdx.x; int t = threadIdx.x;
  size_t base = (size_t)bh*NCc*4160;
  for (int e=t; e<4160; e+=256){
    float acc = 0.f;
    #pragma unroll
    for (int c=0;c<NCc;c++){
      Spre[base + (size_t)c*4160 + e] = acc;
      acc += Ssum[base + (size_t)c*4160 + e];
    }
  }
}

// ---------------- per-chunk causal attention via MFMA ----------------
// wave w owns q rows [64w, 64w+64) of the 256-chunk; 4 kv tiles of 64.
__global__ __launch_bounds__(256, 2) void attnout_kernel(const unsigned short* __restrict__ qkv,
    const float* __restrict__ Spre, unsigned short* __restrict__ attn){
  __shared__ __align__(16) unsigned short SpT[64][72];     // Spre^T[e][j] bf16
  __shared__ __align__(16) unsigned short Ks[64][72];      // K[m][d]
  __shared__ __align__(16) unsigned short Vt[64][72];      // V^T[d][m]
  __shared__ __align__(16) unsigned short P[4][64][72];    // per-wave masked S bf16
  __shared__ float qZd[256];
  int c = blockIdx.x, bh = blockIdx.y;
  int b = bh >> 4, h = bh & 15;
  int tid = threadIdx.x, lane = tid & 63, wave = tid >> 6;
  int lr = lane & 15, lg = lane >> 4;
  const float* Sp = Spre + ((size_t)bh*NCc + c)*4160;

  // qZ: thread t handles chunk-row t:  qZ = sum_j Q[t][j] * Z[j]
  {
    float zacc = 0.f;
    const unsigned short* qp = qkv + ((size_t)(b*Ll + c*CHk + tid))*3072 + (size_t)h*64;
    #pragma unroll
    for (int g8=0; g8<8; g8++){
      bf16x8 qv = *(const bf16x8*)(qp + g8*8);
      #pragma unroll
      for (int u=0; u<8; u++) zacc += bf2f((unsigned short)qv[u]) * Sp[4096 + g8*8 + u];
    }
    qZd[tid] = zacc;
  }
  // stage SpT (transpose + bf16)
  #pragma unroll
  for (int i=0; i<2; i++){
    int tau = tid + i*256;
    int j = tau & 63, dg = (tau >> 6) * 8;
    const float* sp = Sp + j*64 + dg;
    #pragma unroll
    for (int u=0; u<8; u++) SpT[dg+u][j] = f2bf(sp[u]);
  }
  // Q fragments (A-layout), kept in registers
  bf16x8 af[4][2];
  #pragma unroll
  for (int mi=0; mi<4; mi++){
    size_t qrow = ((size_t)(b*Ll + c*CHk + wave*64 + mi*16 + lr))*3072 + (size_t)h*64;
    #pragma unroll
    for (int kk=0; kk<2; kk++)
      af[mi][kk] = *(const bf16x8*)(qkv + qrow + kk*32 + lg*8);
  }
  __syncthreads();
  // prefix: O = Q @ Spre
  f32x4 accO[4][4] = {};
  #pragma unroll
  for (int kk=0; kk<2; kk++){
    #pragma unroll
    for (int ni=0; ni<4; ni++){
      bf16x8 bsp = *(const bf16x8*)&SpT[ni*16 + lr][kk*32 + lg*8];
      #pragma unroll
      for (int mi=0; mi<4; mi++)
        accO[mi][ni] = __builtin_amdgcn_mfma_f32_16x16x32_bf16(af[mi][kk], bsp, accO[mi][ni], 0,0,0);
    }
  }
  f32x4 den4[4] = {};
  // kv tiles
  for (int t=0; t<4; ++t){
    __syncthreads();
    #pragma unroll
    for (int i=0; i<2; i++){
      int tau = tid + i*256;
      int m = tau & 63, dg = (tau >> 6) * 8;
      size_t g = ((size_t)(b*Ll + c*CHk + t*64 + m))*3072 + h*64 + dg;
      *(bf16x8*)&Ks[m][dg] = *(const bf16x8*)(qkv + g + 1024);
      bf16x8 vv = *(const bf16x8*)(qkv + g + 2048);
      #pragma unroll
      for (int u=0; u<8; u++) Vt[dg+u][m] = (unsigned short)vv[u];
    }
    __syncthreads();
    if (wave < t) continue;
    // S = Q K^T
    f32x4 sacc[4][4] = {};
    #pragma unroll
    for (int kk=0; kk<2; kk++){
      #pragma unroll
      for (int ni=0; ni<4; ni++){
        bf16x8 kf = *(const bf16x8*)&Ks[ni*16 + lr][kk*32 + lg*8];
        #pragma unroll
        for (int mi=0; mi<4; mi++)
          sacc[mi][ni] = __builtin_amdgcn_mfma_f32_16x16x32_bf16(af[mi][kk], kf, sacc[mi][ni], 0,0,0);
      }
    }
    // mask + P write + den rowsum
    unsigned short (*Pw)[72] = P[wave];
    bool diag = (t == wave);
    #pragma unroll
    for (int mi=0; mi<4; mi++){
      #pragma unroll
      for (int r=0; r<4; r++){
        int q_l = mi*16 + lg*4 + r;
        float rs = 0.f;
        #pragma unroll
        for (int ni=0; ni<4; ni++){
          int m_l = ni*16 + lr;
          float v = sacc[mi][ni][r];
          if (diag && m_l > q_l) v = 0.f;
          rs += v;
          Pw[q_l][m_l] = f2bf(v);
        }
        rs += __shfl_xor(rs, 1);
        rs += __shfl_xor(rs, 2);
        rs += __shfl_xor(rs, 4);
        rs += __shfl_xor(rs, 8);
        den4[mi][r] += rs;
      }
    }
    // PV
    #pragma unroll
    for (int kk=0; kk<2; kk++){
      bf16x8 pa[4], vf[4];
      #pragma unroll
      for (int mi=0; mi<4; mi++) pa[mi] = *(const bf16x8*)&Pw[mi*16 + lr][kk*32 + lg*8];
      #pragma unroll
      for (int ni=0; ni<4; ni++) vf[ni] = *(const bf16x8*)&Vt[ni*16 + lr][kk*32 + lg*8];
      #pragma unroll
      for (int mi=0; mi<4; mi++)
        #pragma unroll
        for (int ni=0; ni<4; ni++)
          accO[mi][ni] = __builtin_amdgcn_mfma_f32_16x16x32_bf16(pa[mi], vf[ni], accO[mi][ni], 0,0,0);
    }
  }
  // finalize: O / den -> attn
  #pragma unroll
  for (int mi=0; mi<4; mi++){
    #pragma unroll
    for (int r=0; r<4; r++){
      int q_l = mi*16 + lg*4 + r;
      float dtot = den4[mi][r] + qZd[wave*64 + q_l];
      float inv = 1.f / fmaxf(dtot, 1e-6f);
      size_t l = (size_t)(b*Ll + c*CHk + wave*64 + q_l);
      unsigned short* op = attn + l*Ee + h*64 + lr;
      #pragma unroll
      for (int ni=0; ni<4; ni++)
        op[ni*16] = f2bf(accO[mi][ni][r] * inv);
    }
  }
}

// ---------------- column mean over L, deterministic 2-stage ----------------
__global__ __launch_bounds__(256) void colmean1_kernel(const unsigned short* __restrict__ h2,
    float* __restrict__ partial){
  int e = blockIdx.x*256 + threadIdx.x;
  int ly = blockIdx.y;
  int b = blockIdx.z;
  int l0 = ly * 128;
  float s = 0.f;
  for (int l=l0; l<l0+128; l++) s += bf2f(h2[((size_t)(b*Ll + l))*Ee + e]);
  partial[((size_t)(b*32 + ly))*Ee + e] = s;
}
__global__ __launch_bounds__(256) void colmean2_kernel(const float* __restrict__ partial,
    float* __restrict__ xmean){
  int e = blockIdx.x*256 + threadIdx.x;
  int b = blockIdx.y;
  float s = 0.f;
  #pragma unroll
  for (int ly=0; ly<32; ly++) s += partial[((size_t)(b*32 + ly))*Ee + e];
  xmean[b*Ee + e] = s * (1.f/Ll);
}

// ---------------- dim predictor -> floored size ----------------
__global__ __launch_bounds__(256) void dimpred_kernel(const float* __restrict__ xmean,
    const float* __restrict__ w_dp1, const float* __restrict__ w_dp2,
    float* __restrict__ scalars){
  __shared__ float red[256];
  __shared__ float ratio_s[2];
  int t = threadIdx.x;
  for (int b=0;b<2;b++){
    float s = 0.f;
    for (int k=0;k<1024;k++) s += xmean[b*Ee + k] * w_dp1[k*256 + t];
    float sil = s * (1.f/(1.f+expf(-s)));
    red[t] = sil * w_dp2[t];
    __syncthreads();
    for (int off=128; off>0; off>>=1){
      if (t<off) red[t] += red[t+off];
      __syncthreads();
    }
    if (t==0){
      float dr = 1.f/(1.f+expf(-red[0]));
      float ratio = 1.f + (dr-0.5f)*1.0f;       // 2*ADAPT = 1
      ratio = fminf(fmaxf(ratio, 0.5f), 1.5f);
      ratio_s[b] = ratio;
    }
    __syncthreads();
  }
  if (t==0){
    float rm = 0.5f*(ratio_s[0]+ratio_s[1]);
    float size_f = floorf(3072.f * rm);
    if (size_f < 1.f) size_f = 1.f;
    scalars[0] = size_f;
  }
}

// ---------------- per-row sumsq of hidden -> inv_rms ----------------
__global__ __launch_bounds__(256) void rowrms_kernel(const unsigned short* __restrict__ Hid,
    const float* __restrict__ scal, float* __restrict__ invr){
  int row = blockIdx.x; int t = threadIdx.x;
  float size_f = scal[0];
  int c8max = ((int)size_f + 7) >> 3;
  float ss = 0.f;
  for (int c8 = t; c8 < c8max; c8 += 256){
    bf16x8 v = *(const bf16x8*)(Hid + (size_t)row*Ff + c8*8);
    #pragma unroll
    for (int u=0;u<8;u++){ float f = bf2f((unsigned short)v[u]); ss += f*f; }
  }
  #pragma unroll
  for (int off=32; off>0; off>>=1) ss += __shfl_down(ss, off);
  __shared__ float red[4];
  if ((t&63)==0) red[t>>6] = ss;
  __syncthreads();
  if (t==0){
    float tot = red[0]+red[1]+red[2]+red[3];
    float rms = sqrtf(tot/size_f + 1e-6f);
    rms = fminf(fmaxf(rms, 1e-6f), 1e6f);
    invr[row] = 1.f/rms;
  }
}

extern "C" void kernel_launch(void* const* d_in, const int* in_sizes, int n_in,
                              void* d_out, int out_size, void* d_ws, size_t ws_size,
                              hipStream_t stream){
  const float* x      = (const float*)d_in[0];
  const float* w_qkv  = (const float*)d_in[1];
  const float* w_out  = (const float*)d_in[2];
  const float* g1     = (const float*)d_in[3];
  const float* g2     = (const float*)d_in[4];
  const float* w_dp1  = (const float*)d_in[5];
  const float* w_dp2  = (const float*)d_in[6];
  const float* w_gate = (const float*)d_in[7];
  const float* w_up   = (const float*)d_in[8];
  const float* w_down = (const float*)d_in[9];
  const float* g_hid  = (const float*)d_in[10];
  float* out = (float*)d_out;

  char* w = (char*)d_ws;
  size_t o = 0;
  auto alloc = [&](size_t bytes)->char*{ char* p = w + o; o += (bytes + 255) & ~255ull; return p; };
  unsigned short* R1   = (unsigned short*)alloc((size_t)8192*1024*2);   // h/attn/h2 bf16
  float*          x2   = (float*)alloc((size_t)8192*1024*4);            // post-attn residual fp32
  char*           R2   = alloc((size_t)8192*4608*2);                    // qkv bf16 then hidden
  unsigned short* qkvT = (unsigned short*)alloc((size_t)3072*1024*2);
  unsigned short* outT = (unsigned short*)alloc((size_t)1024*1024*2);
  char*           W2   = alloc((size_t)3*4608*1024*2);                  // Ssum/Spre then gateT/upT/downT
  float*       partial = (float*)alloc((size_t)64*1024*4);
  float*         xmean = (float*)alloc(2048*4);
  float*          scal = (float*)alloc(64);
  float*          invr = (float*)alloc(8192*4);

  unsigned short* qkv    = (unsigned short*)R2;
  unsigned short* hidden = (unsigned short*)R2;
  float* Ssum = (float*)W2;
  float* Spre = Ssum + (size_t)512*4160;
  unsigned short* gateT = (unsigned short*)W2;
  unsigned short* upT   = gateT + (size_t)4608*1024;
  unsigned short* downT = upT   + (size_t)4608*1024;

  wconv_kernel<<<dim3(3072/64, 1024/64),256,0,stream>>>(w_qkv, qkvT, 1024, 3072, nullptr);
  wconv_kernel<<<dim3(1024/64, 1024/64),256,0,stream>>>(w_out, outT, 1024, 1024, nullptr);

  rmsnorm_kernel<<<8192,256,0,stream>>>(x, g1, R1);
  gemm_kernel<0><<<dim3(3072/128, 8192/128),256,0,stream>>>(R1, qkvT, qkv,
      8192,3072,1024, nullptr,nullptr,nullptr);
  rope_kernel<<<16384,256,0,stream>>>(qkv);
  chunksum_kernel<<<dim3(NCc,Bb*Hh),256,0,stream>>>(qkv, Ssum);
  prefix_kernel<<<Bb*Hh,256,0,stream>>>(Ssum, Spre);
  attnout_kernel<<<dim3(NCc,Bb*Hh),256,0,stream>>>(qkv, Spre, R1);

  wconv_kernel<<<dim3(4608/64, 1024/64),256,0,stream>>>(w_gate, gateT, 1024, 4608, nullptr);
  wconv_kernel<<<dim3(4608/64, 1024/64),256,0,stream>>>(w_up,   upT,   1024, 4608, nullptr);
  wconv_kernel<<<dim3(1024/64, 4608/64),256,0,stream>>>(w_down, downT, 4608, 1024, g_hid);

  gemm_kernel<1><<<dim3(1024/128, 8192/128),256,0,stream>>>(R1, outT, x2,
      8192,1024,1024, x,nullptr,nullptr);
  rmsnorm_kernel<<<8192,256,0,stream>>>(x2, g2, R1);
  colmean1_kernel<<<dim3(4,32,2),256,0,stream>>>(R1, partial);
  colmean2_kernel<<<dim3(4,2),256,0,stream>>>(partial, xmean);
  dimpred_kernel<<<1,256,0,stream>>>(xmean, w_dp1, w_dp2, scal);
  gateup_kernel<<<dim3(4608/128, 8192/128),256,0,stream>>>(R1, gateT, upT, hidden, scal);
  rowrms_kernel<<<8192,256,0,stream>>>(hidden, scal, invr);
  gemm_kernel<2><<<dim3(1024/128, 8192/128),256,0,stream>>>(hidden, downT, out,
      8192,1024,4608, x2, invr, scal);
}

// Round 7
// 563.079 us; speedup vs baseline: 2.3358x; 1.0117x over previous
//
#include <hip/hip_runtime.h>
#include <hip/hip_bf16.h>

#define Ee 1024
#define Hh 16
#define Ff 4608
#define Ll 4096
#define Bb 2
#define NCc 16
#define CHk 256

typedef short bf16x8 __attribute__((ext_vector_type(8)));
typedef float f32x4 __attribute__((ext_vector_type(4)));

#define GLD16(g, l) __builtin_amdgcn_global_load_lds( \
    (const __attribute__((address_space(1))) unsigned int*)(g), \
    (__attribute__((address_space(3))) unsigned int*)(l), 16, 0, 0)

__device__ __forceinline__ unsigned short f2bf(float f){
  unsigned int u = __builtin_bit_cast(unsigned int, f);
  u += 0x7fffu + ((u >> 16) & 1u);
  return (unsigned short)(u >> 16);
}
__device__ __forceinline__ float bf2f(unsigned short h){
  unsigned int u = ((unsigned int)h) << 16;
  return __builtin_bit_cast(float, u);
}
__device__ __forceinline__ float fixv(float v){
  return (__builtin_isnan(v) || __builtin_isinf(v)) ? 0.f : v;
}

// ---------------- weight convert+transpose: W[K][N] fp32 -> WT[N][K] bf16 ----------------
__global__ __launch_bounds__(256) void wconv_kernel(const float* __restrict__ W,
    unsigned short* __restrict__ WT, int K, int N, const float* __restrict__ scale){
  __shared__ unsigned short T[64][72];
  int k0 = blockIdx.y*64, n0 = blockIdx.x*64;
  int t = threadIdx.x;
  int kr = t>>4, n4 = (t&15)*4;
  #pragma unroll
  for (int it=0; it<4; it++){
    int k = kr + it*16;
    float s = scale ? scale[k0+k] : 1.f;
    float4 v = *(const float4*)(W + (size_t)(k0+k)*N + n0 + n4);
    T[n4+0][k] = f2bf(v.x*s);
    T[n4+1][k] = f2bf(v.y*s);
    T[n4+2][k] = f2bf(v.z*s);
    T[n4+3][k] = f2bf(v.w*s);
  }
  __syncthreads();
  int u = t&7;
  #pragma unroll
  for (int it=0; it<2; it++){
    int n = (t>>3) + it*32;
    *(bf16x8*)(WT + (size_t)(n0+n)*K + k0 + u*8) = *(const bf16x8*)&T[n][u*8];
  }
}

// ---------------- RMSNorm fp32 in -> bf16 out ----------------
__global__ __launch_bounds__(256) void rmsnorm_kernel(const float* __restrict__ x,
    const float* __restrict__ g, unsigned short* __restrict__ out){
  int row = blockIdx.x; int t = threadIdx.x;
  float4 v = ((const float4*)(x + (size_t)row*Ee))[t];
  v.x=fixv(v.x); v.y=fixv(v.y); v.z=fixv(v.z); v.w=fixv(v.w);
  float ss = v.x*v.x + v.y*v.y + v.z*v.z + v.w*v.w;
  #pragma unroll
  for (int off=32; off>0; off>>=1) ss += __shfl_down(ss, off);
  __shared__ float red[4];
  if ((t&63)==0) red[t>>6] = ss;
  __syncthreads();
  float tot = red[0]+red[1]+red[2]+red[3];
  float rms = sqrtf(tot*(1.f/Ee) + 1e-6f);
  rms = fminf(fmaxf(rms, 1e-6f), 1e6f);
  float inv = 1.f/rms;
  float4 gv = ((const float4*)g)[t];
  uint2 o;
  o.x = (unsigned)f2bf(v.x*inv*gv.x) | ((unsigned)f2bf(v.y*inv*gv.y)<<16);
  o.y = (unsigned)f2bf(v.z*inv*gv.z) | ((unsigned)f2bf(v.w*inv*gv.w)<<16);
  ((uint2*)(out + (size_t)row*Ee))[t] = o;
}

// ---------------- bf16 GEMM: C[M,N] = A[M,K] @ Bt[N,K]^T ----------------
// LDS tiles stored with 16B-chunk XOR swizzle: chunk_slot = chunk ^ ((row>>1)&3).
// Staged via global_load_lds with pre-swizzled per-lane source (rule 21).
// MODE 0: C bf16. MODE 1: C fp32 = acc + res. MODE 2: C fp32 = acc*rowscale[m] + res,
//         K-loop truncated to round_up(klim[0], 32).
template<int MODE>
__global__ __launch_bounds__(256) void gemm_kernel(
    const unsigned short* __restrict__ A, const unsigned short* __restrict__ Bt,
    void* __restrict__ Cv, int M, int N, int K,
    const float* __restrict__ res, const float* __restrict__ rowscale,
    const float* __restrict__ klim){
  __shared__ __align__(16) unsigned short As[2][4096];
  __shared__ __align__(16) unsigned short Bs[2][4096];
  int tid = threadIdx.x;
  int nbx = gridDim.x;
  int id = blockIdx.y * nbx + blockIdx.x;
  int chunk = (nbx * gridDim.y) >> 3;
  int wg = (id & 7) * chunk + (id >> 3);
  int m0 = (wg / nbx) * 128, n0 = (wg % nbx) * 128;
  int lane = tid & 63, wave = tid >> 6;
  int wm = (wave>>1)*64, wn = (wave&1)*64;
  int lrow = lane & 15;
  int lksw = (((lane>>4) ^ ((lrow>>1)&3)))*8;    // swizzled read chunk
  int kend = K;
  if (MODE==2 && klim){
    int sz = (int)klim[0];
    int ke = ((sz + 31) >> 5) << 5;
    kend = ke < K ? ke : K;
  }
  int nk = kend >> 5;
  int s0 = wave*2, s1 = s0+1;
  int r0 = s0*16 + (lane>>2), r1 = s1*16 + (lane>>2);
  int cg = (((lane&3) ^ ((lane>>3)&3))) * 8;     // swizzled source chunk
  const unsigned short* a0 = A  + (size_t)(m0+r0)*K + cg;
  const unsigned short* a1 = A  + (size_t)(m0+r1)*K + cg;
  const unsigned short* b0 = Bt + (size_t)(n0+r0)*K + cg;
  const unsigned short* b1 = Bt + (size_t)(n0+r1)*K + cg;
  f32x4 acc[4][4] = {};
  GLD16(a0, &As[0][s0*512]); GLD16(a1, &As[0][s1*512]);
  GLD16(b0, &Bs[0][s0*512]); GLD16(b1, &Bs[0][s1*512]);
  __syncthreads();
  int cur = 0;
  for (int t=0; t<nk; ++t){
    if (t+1 < nk){
      int ko = (t+1) << 5;
      GLD16(a0+ko, &As[cur^1][s0*512]); GLD16(a1+ko, &As[cur^1][s1*512]);
      GLD16(b0+ko, &Bs[cur^1][s0*512]); GLD16(b1+ko, &Bs[cur^1][s1*512]);
    }
    bf16x8 af[4], bfr[4];
    #pragma unroll
    for (int i=0;i<4;i++){
      af[i]  = *(const bf16x8*)&As[cur][(wm + i*16 + lrow)*32 + lksw];
      bfr[i] = *(const bf16x8*)&Bs[cur][(wn + i*16 + lrow)*32 + lksw];
    }
    #pragma unroll
    for (int mi=0;mi<4;mi++)
      #pragma unroll
      for (int ni=0;ni<4;ni++)
        acc[mi][ni] = __builtin_amdgcn_mfma_f32_16x16x32_bf16(af[mi], bfr[ni], acc[mi][ni], 0,0,0);
    __syncthreads();
    cur ^= 1;
  }
  int lg = lane >> 4;
  int rbase = m0 + wm + (lg<<2);
  int cbase = n0 + wn + lrow;
  #pragma unroll
  for (int mi=0;mi<4;mi++){
    #pragma unroll
    for (int r=0;r<4;r++){
      int row = rbase + mi*16 + r;
      float rs = (MODE==2) ? rowscale[row] : 1.f;
      #pragma unroll
      for (int ni=0;ni<4;ni++){
        int col = cbase + ni*16;
        float v = acc[mi][ni][r];
        if (MODE==0){
          ((unsigned short*)Cv)[(size_t)row*N + col] = f2bf(v);
        } else if (MODE==1){
          ((float*)Cv)[(size_t)row*N + col] = v + res[(size_t)row*N + col];
        } else {
          ((float*)Cv)[(size_t)row*N + col] = v*rs + res[(size_t)row*N + col];
        }
      }
    }
  }
}

// ---------------- fused gate+up GEMM (128x128) -> hidden = silu(g)*u masked ----------------
__global__ __launch_bounds__(256) void gateup_kernel(
    const unsigned short* __restrict__ A, const unsigned short* __restrict__ Gt,
    const unsigned short* __restrict__ Ut, unsigned short* __restrict__ Hid,
    const float* __restrict__ scal){
  __shared__ __align__(16) unsigned short As[2][4096];
  __shared__ __align__(16) unsigned short Bg[2][4096];
  __shared__ __align__(16) unsigned short Bu[2][4096];
  int tid = threadIdx.x;
  int nbx = gridDim.x;
  int id = blockIdx.y * nbx + blockIdx.x;
  int chunk = (nbx * gridDim.y) >> 3;
  int wg = (id & 7) * chunk + (id >> 3);
  int m0 = (wg / nbx) * 128, n0 = (wg % nbx) * 128;
  int size = (int)scal[0];
  if (n0 >= size){
    int r = tid >> 1, cb = n0 + (tid&1)*64;
    unsigned short* hp = Hid + (size_t)(m0+r)*Ff + cb;
    bf16x8 z = {};
    #pragma unroll
    for (int i=0;i<8;i++) *(bf16x8*)(hp + i*8) = z;
    return;
  }
  int lane = tid & 63, wave = tid >> 6;
  int wm = (wave>>1)*64, wn = (wave&1)*64;
  int lrow = lane & 15;
  int lksw = (((lane>>4) ^ ((lrow>>1)&3)))*8;
  int s0 = wave*2, s1 = s0+1;
  int r0 = s0*16 + (lane>>2), r1 = s1*16 + (lane>>2);
  int cg = (((lane&3) ^ ((lane>>3)&3))) * 8;
  const unsigned short* a0 = A  + (size_t)(m0+r0)*Ee + cg;
  const unsigned short* a1 = A  + (size_t)(m0+r1)*Ee + cg;
  const unsigned short* g0 = Gt + (size_t)(n0+r0)*Ee + cg;
  const unsigned short* g1p= Gt + (size_t)(n0+r1)*Ee + cg;
  const unsigned short* u0 = Ut + (size_t)(n0+r0)*Ee + cg;
  const unsigned short* u1 = Ut + (size_t)(n0+r1)*Ee + cg;
  f32x4 ag[4][4] = {}, au[4][4] = {};
  GLD16(a0, &As[0][s0*512]); GLD16(a1, &As[0][s1*512]);
  GLD16(g0, &Bg[0][s0*512]); GLD16(g1p,&Bg[0][s1*512]);
  GLD16(u0, &Bu[0][s0*512]); GLD16(u1, &Bu[0][s1*512]);
  __syncthreads();
  int cur = 0;
  for (int t=0; t<32; ++t){
    if (t+1 < 32){
      int ko = (t+1) << 5;
      GLD16(a0+ko, &As[cur^1][s0*512]); GLD16(a1+ko, &As[cur^1][s1*512]);
      GLD16(g0+ko, &Bg[cur^1][s0*512]); GLD16(g1p+ko,&Bg[cur^1][s1*512]);
      GLD16(u0+ko, &Bu[cur^1][s0*512]); GLD16(u1+ko, &Bu[cur^1][s1*512]);
    }
    bf16x8 af[4], bg4[4], bu4[4];
    #pragma unroll
    for (int i=0;i<4;i++){
      af[i]  = *(const bf16x8*)&As[cur][(wm + i*16 + lrow)*32 + lksw];
      bg4[i] = *(const bf16x8*)&Bg[cur][(wn + i*16 + lrow)*32 + lksw];
      bu4[i] = *(const bf16x8*)&Bu[cur][(wn + i*16 + lrow)*32 + lksw];
    }
    #pragma unroll
    for (int mi=0;mi<4;mi++)
      #pragma unroll
      for (int ni=0;ni<4;ni++){
        ag[mi][ni] = __builtin_amdgcn_mfma_f32_16x16x32_bf16(af[mi], bg4[ni], ag[mi][ni], 0,0,0);
        au[mi][ni] = __builtin_amdgcn_mfma_f32_16x16x32_bf16(af[mi], bu4[ni], au[mi][ni], 0,0,0);
      }
    __syncthreads();
    cur ^= 1;
  }
  int lg = lane >> 4;
  int rbase = m0 + wm + (lg<<2);
  int cbase = n0 + wn + lrow;
  #pragma unroll
  for (int mi=0;mi<4;mi++){
    #pragma unroll
    for (int r=0;r<4;r++){
      int row = rbase + mi*16 + r;
      #pragma unroll
      for (int ni=0;ni<4;ni++){
        int col = cbase + ni*16;
        float g = ag[mi][ni][r], u = au[mi][ni][r];
        float hv = (g * (1.f/(1.f+expf(-g)))) * u;
        if (col >= size) hv = 0.f;
        if (__builtin_isnan(hv) || __builtin_isinf(hv)) hv = 0.f;
        Hid[(size_t)row*Ff + col] = f2bf(hv);
      }
    }
  }
}

// ---------------- RoPE + ELU+1 on q,k in bf16 qkv ----------------
__global__ __launch_bounds__(256) void rope_kernel(unsigned short* __restrict__ qkv){
  size_t idx = (size_t)blockIdx.x*256 + threadIdx.x;    // B*L*H*32
  int i = (int)(idx & 31);
  int h = (int)((idx>>5) & 15);
  size_t bl = idx >> 9;
  int pos = (int)(bl & (Ll-1));
  int d0 = 2*i, d1 = d0+1;
  size_t base = bl*3072 + (size_t)h*64 + d0;
  const float LOG1E4_D32 = 0.2878231366242557f;  // ln(10000)/32
  float e0 = (float)(d0 < 32 ? d0 : d0-32);
  float e1 = (float)(d1 < 32 ? d1 : d1-32);
  float f0 = pos * expf(-e0*LOG1E4_D32);
  float f1 = pos * expf(-e1*LOG1E4_D32);
  float s0,c0,s1,c1;
  sincosf(f0,&s0,&c0); sincosf(f1,&s1,&c1);
  unsigned int* qp = (unsigned int*)(qkv + base);
  unsigned int qv = *qp;
  float q0 = bf2f((unsigned short)(qv&0xffff)), q1 = bf2f((unsigned short)(qv>>16));
  float r0 = q0*c0 - q1*s0;
  float r1 = q1*c1 + q0*s1;
  r0 = r0>0.f ? r0+1.f : expf(r0);
  r1 = r1>0.f ? r1+1.f : expf(r1);
  *qp = (unsigned)f2bf(r0) | ((unsigned)f2bf(r1)<<16);
  unsigned int* kp = (unsigned int*)(qkv + base + 1024);
  unsigned int kv = *kp;
  float k0v = bf2f((unsigned short)(kv&0xffff)), k1v = bf2f((unsigned short)(kv>>16));
  float t0 = k0v*c0 - k1v*s0;
  float t1 = k1v*c1 + k0v*s1;
  t0 = t0>0.f ? t0+1.f : expf(t0);
  t1 = t1>0.f ? t1+1.f : expf(t1);
  *kp = (unsigned)f2bf(t0) | ((unsigned)f2bf(t1)<<16);
}

// ---------------- per-chunk K^T V + K col sums via MFMA (ones-column trick) ----------------
__global__ __launch_bounds__(256) void chunksum_kernel(const unsigned short* __restrict__ qkv,
    float* __restrict__ Ssum){
  __shared__ __align__(16) unsigned short Kt[64][72];   // K^T[j][m]
  __shared__ __align__(16) unsigned short Vt[80][72];   // V^T[e][m]; row64=1.0, 65..79=0
  int c = blockIdx.x, bh = blockIdx.y;
  int b = bh >> 4, h = bh & 15;
  int tid = threadIdx.x, lane = tid & 63, wave = tid >> 6;
  int lr = lane & 15, lg = lane >> 4;
  f32x4 acc[5] = {};
  {
    int r16 = tid >> 4, m4 = (tid & 15) * 4;
    unsigned short val = (r16 == 0) ? (unsigned short)0x3F80 : (unsigned short)0;
    #pragma unroll
    for (int u=0; u<4; u++) Vt[64 + r16][m4 + u] = val;
  }
  for (int t=0; t<4; ++t){
    __syncthreads();
    #pragma unroll
    for (int i=0; i<2; i++){
      int tau = tid + i*256;
      int m = tau & 63, dg = (tau >> 6) * 8;
      size_t g = ((size_t)(b*Ll + c*CHk + t*64 + m))*3072 + h*64 + dg;
      bf16x8 kv = *(const bf16x8*)(qkv + g + 1024);
      bf16x8 vv = *(const bf16x8*)(qkv + g + 2048);
      #pragma unroll
      for (int u=0; u<8; u++){
        Kt[dg+u][m] = (unsigned short)kv[u];
        Vt[dg+u][m] = (unsigned short)vv[u];
      }
    }
    __syncthreads();
    #pragma unroll
    for (int kk=0; kk<2; kk++){
      bf16x8 af = *(const bf16x8*)&Kt[wave*16 + lr][kk*32 + lg*8];
      #pragma unroll
      for (int ni=0; ni<5; ni++){
        bf16x8 vf = *(const bf16x8*)&Vt[ni*16 + lr][kk*32 + lg*8];
        acc[ni] = __builtin_amdgcn_mfma_f32_16x16x32_bf16(af, vf, acc[ni], 0,0,0);
      }
    }
  }
  float* S = Ssum + ((size_t)bh*NCc + c)*4160;
  int j = wave*16 + lg*4;
  #pragma unroll
  for (int ni=0; ni<4; ni++)
    #pragma unroll
    for (int r=0; r<4; r++)
      S[(size_t)(j+r)*64 + ni*16 + lr] = acc[ni][r];
  if (lr == 0){
    #pragma unroll
    for (int r=0; r<4; r++) S[4096 + j + r] = acc[4][r];
  }
}

// ---------------- exclusive prefix over chunks ----------------
__global__ __launch_bounds__(256) void prefix_kernel(const float* __restrict__ Ssum,
    float* __restrict__ Spre){
  int bh = blockIdx.x; int t = threadIdx.x;
  size_t base = (size_t)bh*NCc*4160;
  for (int e=t; e<4160; e+=256){
    float acc = 0.f;
    #pragma unroll
    for (int c=0;c<NCc;c++){
      Spre[base + (size_t)c*4160 + e] = acc;
      acc += Ssum[base + (size_t)c*4160 + e];
    }
  }
}

// ---------------- per-chunk causal attention via MFMA ----------------
__global__ __launch_bounds__(256, 2) void attnout_kernel(const unsigned short* __restrict__ qkv,
    const float* __restrict__ Spre, unsigned short* __restrict__ attn){
  __shared__ __align__(16) unsigned short SpT[64][72];     // Spre^T[e][j] bf16
  __shared__ __align__(16) unsigned short Ks[64][72];      // K[m][d]
  __shared__ __align__(16) unsigned short Vt[64][72];      // V^T[d][m]
  __shared__ __align__(16) unsigned short P[4][64][72];    // per-wave masked S bf16
  __shared__ float qZd[256];
  int c = blockIdx.x, bh = blockIdx.y;
  int b = bh >> 4, h = bh & 15;
  int tid = threadIdx.x, lane = tid & 63, wave = tid >> 6;
  int lr = lane & 15, lg = lane >> 4;
  const float* Sp = Spre + ((size_t)bh*NCc + c)*4160;

  {
    float zacc = 0.f;
    const unsigned short* qp = qkv + ((size_t)(b*Ll + c*CHk + tid))*3072 + (size_t)h*64;
    #pragma unroll
    for (int g8=0; g8<8; g8++){
      bf16x8 qv = *(const bf16x8*)(qp + g8*8);
      #pragma unroll
      for (int u=0; u<8; u++) zacc += bf2f((unsigned short)qv[u]) * Sp[4096 + g8*8 + u];
    }
    qZd[tid] = zacc;
  }
  #pragma unroll
  for (int i=0; i<2; i++){
    int tau = tid + i*256;
    int j = tau & 63, dg = (tau >> 6) * 8;
    const float* sp = Sp + j*64 + dg;
    #pragma unroll
    for (int u=0; u<8; u++) SpT[dg+u][j] = f2bf(sp[u]);
  }
  bf16x8 af[4][2];
  #pragma unroll
  for (int mi=0; mi<4; mi++){
    size_t qrow = ((size_t)(b*Ll + c*CHk + wave*64 + mi*16 + lr))*3072 + (size_t)h*64;
    #pragma unroll
    for (int kk=0; kk<2; kk++)
      af[mi][kk] = *(const bf16x8*)(qkv + qrow + kk*32 + lg*8);
  }
  __syncthreads();
  f32x4 accO[4][4] = {};
  #pragma unroll
  for (int kk=0; kk<2; kk++){
    #pragma unroll
    for (int ni=0; ni<4; ni++){
      bf16x8 bsp = *(const bf16x8*)&SpT[ni*16 + lr][kk*32 + lg*8];
      #pragma unroll
      for (int mi=0; mi<4; mi++)
        accO[mi][ni] = __builtin_amdgcn_mfma_f32_16x16x32_bf16(af[mi][kk], bsp, accO[mi][ni], 0,0,0);
    }
  }
  f32x4 den4[4] = {};
  for (int t=0; t<4; ++t){
    __syncthreads();
    #pragma unroll
    for (int i=0; i<2; i++){
      int tau = tid + i*256;
      int m = tau & 63, dg = (tau >> 6) * 8;
      size_t g = ((size_t)(b*Ll + c*CHk + t*64 + m))*3072 + h*64 + dg;
      *(bf16x8*)&Ks[m][dg] = *(const bf16x8*)(qkv + g + 1024);
      bf16x8 vv = *(const bf16x8*)(qkv + g + 2048);
      #pragma unroll
      for (int u=0; u<8; u++) Vt[dg+u][m] = (unsigned short)vv[u];
    }
    __syncthreads();
    if (wave < t) continue;
    f32x4 sacc[4][4] = {};
    #pragma unroll
    for (int kk=0; kk<2; kk++){
      #pragma unroll
      for (int ni=0; ni<4; ni++){
        bf16x8 kf = *(const bf16x8*)&Ks[ni*16 + lr][kk*32 + lg*8];
        #pragma unroll
        for (int mi=0; mi<4; mi++)
          sacc[mi][ni] = __builtin_amdgcn_mfma_f32_16x16x32_bf16(af[mi][kk], kf, sacc[mi][ni], 0,0,0);
      }
    }
    unsigned short (*Pw)[72] = P[wave];
    bool diag = (t == wave);
    #pragma unroll
    for (int mi=0; mi<4; mi++){
      #pragma unroll
      for (int r=0; r<4; r++){
        int q_l = mi*16 + lg*4 + r;
        float rs = 0.f;
        #pragma unroll
        for (int ni=0; ni<4; ni++){
          int m_l = ni*16 + lr;
          float v = sacc[mi][ni][r];
          if (diag && m_l > q_l) v = 0.f;
          rs += v;
          Pw[q_l][m_l] = f2bf(v);
        }
        rs += __shfl_xor(rs, 1);
        rs += __shfl_xor(rs, 2);
        rs += __shfl_xor(rs, 4);
        rs += __shfl_xor(rs, 8);
        den4[mi][r] += rs;
      }
    }
    #pragma unroll
    for (int kk=0; kk<2; kk++){
      bf16x8 pa[4], vf[4];
      #pragma unroll
      for (int mi=0; mi<4; mi++) pa[mi] = *(const bf16x8*)&Pw[mi*16 + lr][kk*32 + lg*8];
      #pragma unroll
      for (int ni=0; ni<4; ni++) vf[ni] = *(const bf16x8*)&Vt[ni*16 + lr][kk*32 + lg*8];
      #pragma unroll
      for (int mi=0; mi<4; mi++)
        #pragma unroll
        for (int ni=0; ni<4; ni++)
          accO[mi][ni] = __builtin_amdgcn_mfma_f32_16x16x32_bf16(pa[mi], vf[ni], accO[mi][ni], 0,0,0);
    }
  }
  #pragma unroll
  for (int mi=0; mi<4; mi++){
    #pragma unroll
    for (int r=0; r<4; r++){
      int q_l = mi*16 + lg*4 + r;
      float dtot = den4[mi][r] + qZd[wave*64 + q_l];
      float inv = 1.f / fmaxf(dtot, 1e-6f);
      size_t l = (size_t)(b*Ll + c*CHk + wave*64 + q_l);
      unsigned short* op = attn + l*Ee + h*64 + lr;
      #pragma unroll
      for (int ni=0; ni<4; ni++)
        op[ni*16] = f2bf(accO[mi][ni][r] * inv);
    }
  }
}

// ---------------- column mean over L, deterministic 2-stage ----------------
__global__ __launch_bounds__(256) void colmean1_kernel(const unsigned short* __restrict__ h2,
    float* __restrict__ partial){
  int e = blockIdx.x*256 + threadIdx.x;
  int ly = blockIdx.y;
  int b = blockIdx.z;
  int l0 = ly * 128;
  float s = 0.f;
  for (int l=l0; l<l0+128; l++) s += bf2f(h2[((size_t)(b*Ll + l))*Ee + e]);
  partial[((size_t)(b*32 + ly))*Ee + e] = s;
}
__global__ __launch_bounds__(256) void colmean2_kernel(const float* __restrict__ partial,
    float* __restrict__ xmean){
  int e = blockIdx.x*256 + threadIdx.x;
  int b = blockIdx.y;
  float s = 0.f;
  #pragma unroll
  for (int ly=0; ly<32; ly++) s += partial[((size_t)(b*32 + ly))*Ee + e];
  xmean[b*Ee + e] = s * (1.f/Ll);
}

// ---------------- dim predictor -> floored size ----------------
__global__ __launch_bounds__(256) void dimpred_kernel(const float* __restrict__ xmean,
    const float* __restrict__ w_dp1, const float* __restrict__ w_dp2,
    float* __restrict__ scalars){
  __shared__ float red[256];
  __shared__ float ratio_s[2];
  int t = threadIdx.x;
  for (int b=0;b<2;b++){
    float s = 0.f;
    for (int k=0;k<1024;k++) s += xmean[b*Ee + k] * w_dp1[k*256 + t];
    float sil = s * (1.f/(1.f+expf(-s)));
    red[t] = sil * w_dp2[t];
    __syncthreads();
    for (int off=128; off>0; off>>=1){
      if (t<off) red[t] += red[t+off];
      __syncthreads();
    }
    if (t==0){
      float dr = 1.f/(1.f+expf(-red[0]));
      float ratio = 1.f + (dr-0.5f)*1.0f;       // 2*ADAPT = 1
      ratio = fminf(fmaxf(ratio, 0.5f), 1.5f);
      ratio_s[b] = ratio;
    }
    __syncthreads();
  }
  if (t==0){
    float rm = 0.5f*(ratio_s[0]+ratio_s[1]);
    float size_f = floorf(3072.f * rm);
    if (size_f < 1.f) size_f = 1.f;
    scalars[0] = size_f;
  }
}

// ---------------- per-row sumsq of hidden -> inv_rms ----------------
__global__ __launch_bounds__(256) void rowrms_kernel(const unsigned short* __restrict__ Hid,
    const float* __restrict__ scal, float* __restrict__ invr){
  int row = blockIdx.x; int t = threadIdx.x;
  float size_f = scal[0];
  int c8max = ((int)size_f + 7) >> 3;
  float ss = 0.f;
  for (int c8 = t; c8 < c8max; c8 += 256){
    bf16x8 v = *(const bf16x8*)(Hid + (size_t)row*Ff + c8*8);
    #pragma unroll
    for (int u=0;u<8;u++){ float f = bf2f((unsigned short)v[u]); ss += f*f; }
  }
  #pragma unroll
  for (int off=32; off>0; off>>=1) ss += __shfl_down(ss, off);
  __shared__ float red[4];
  if ((t&63)==0) red[t>>6] = ss;
  __syncthreads();
  if (t==0){
    float tot = red[0]+red[1]+red[2]+red[3];
    float rms = sqrtf(tot/size_f + 1e-6f);
    rms = fminf(fmaxf(rms, 1e-6f), 1e6f);
    invr[row] = 1.f/rms;
  }
}

extern "C" void kernel_launch(void* const* d_in, const int* in_sizes, int n_in,
                              void* d_out, int out_size, void* d_ws, size_t ws_size,
                              hipStream_t stream){
  const float* x      = (const float*)d_in[0];
  const float* w_qkv  = (const float*)d_in[1];
  const float* w_out  = (const float*)d_in[2];
  const float* g1     = (const float*)d_in[3];
  const float* g2     = (const float*)d_in[4];
  const float* w_dp1  = (const float*)d_in[5];
  const float* w_dp2  = (const float*)d_in[6];
  const float* w_gate = (const float*)d_in[7];
  const float* w_up   = (const float*)d_in[8];
  const float* w_down = (const float*)d_in[9];
  const float* g_hid  = (const float*)d_in[10];
  float* out = (float*)d_out;

  char* w = (char*)d_ws;
  size_t o = 0;
  auto alloc = [&](size_t bytes)->char*{ char* p = w + o; o += (bytes + 255) & ~255ull; return p; };
  unsigned short* R1   = (unsigned short*)alloc((size_t)8192*1024*2);   // h/attn/h2 bf16
  float*          x2   = (float*)alloc((size_t)8192*1024*4);            // post-attn residual fp32
  char*           R2   = alloc((size_t)8192*4608*2);                    // qkv bf16 then hidden
  unsigned short* qkvT = (unsigned short*)alloc((size_t)3072*1024*2);
  unsigned short* outT = (unsigned short*)alloc((size_t)1024*1024*2);
  char*           W2   = alloc((size_t)3*4608*1024*2);                  // Ssum/Spre then gateT/upT/downT
  float*       partial = (float*)alloc((size_t)64*1024*4);
  float*         xmean = (float*)alloc(2048*4);
  float*          scal = (float*)alloc(64);
  float*          invr = (float*)alloc(8192*4);

  unsigned short* qkv    = (unsigned short*)R2;
  unsigned short* hidden = (unsigned short*)R2;
  float* Ssum = (float*)W2;
  float* Spre = Ssum + (size_t)512*4160;
  unsigned short* gateT = (unsigned short*)W2;
  unsigned short* upT   = gateT + (size_t)4608*1024;
  unsigned short* downT = upT   + (size_t)4608*1024;

  wconv_kernel<<<dim3(3072/64, 1024/64),256,0,stream>>>(w_qkv, qkvT, 1024, 3072, nullptr);
  wconv_kernel<<<dim3(1024/64, 1024/64),256,0,stream>>>(w_out, outT, 1024, 1024, nullptr);

  rmsnorm_kernel<<<8192,256,0,stream>>>(x, g1, R1);
  gemm_kernel<0><<<dim3(3072/128, 8192/128),256,0,stream>>>(R1, qkvT, qkv,
      8192,3072,1024, nullptr,nullptr,nullptr);
  rope_kernel<<<16384,256,0,stream>>>(qkv);
  chunksum_kernel<<<dim3(NCc,Bb*Hh),256,0,stream>>>(qkv, Ssum);
  prefix_kernel<<<Bb*Hh,256,0,stream>>>(Ssum, Spre);
  attnout_kernel<<<dim3(NCc,Bb*Hh),256,0,stream>>>(qkv, Spre, R1);

  wconv_kernel<<<dim3(4608/64, 1024/64),256,0,stream>>>(w_gate, gateT, 1024, 4608, nullptr);
  wconv_kernel<<<dim3(4608/64, 1024/64),256,0,stream>>>(w_up,   upT,   1024, 4608, nullptr);
  wconv_kernel<<<dim3(1024/64, 4608/64),256,0,stream>>>(w_down, downT, 4608, 1024, g_hid);

  gemm_kernel<1><<<dim3(1024/128, 8192/128),256,0,stream>>>(R1, outT, x2,
      8192,1024,1024, x,nullptr,nullptr);
  rmsnorm_kernel<<<8192,256,0,stream>>>(x2, g2, R1);
  colmean1_kernel<<<dim3(4,32,2),256,0,stream>>>(R1, partial);
  colmean2_kernel<<<dim3(4,2),256,0,stream>>>(partial, xmean);
  dimpred_kernel<<<1,256,0,stream>>>(xmean, w_dp1, w_dp2, scal);
  gateup_kernel<<<dim3(4608/128, 8192/128),256,0,stream>>>(R1, gateT, upT, hidden, scal);
  rowrms_kernel<<<8192,256,0,stream>>>(hidden, scal, invr);
  gemm_kernel<2><<<dim3(1024/128, 8192/128),256,0,stream>>>(hidden, downT, out,
      8192,1024,4608, x2, invr, scal);
}

// Round 8
// 514.889 us; speedup vs baseline: 2.5544x; 1.0936x over previous
//
#include <hip/hip_runtime.h>
#include <hip/hip_bf16.h>

#define Ee 1024
#define Hh 16
#define Ff 4608
#define Ll 4096
#define Bb 2
#define NCc 16
#define CHk 256

typedef short bf16x8 __attribute__((ext_vector_type(8)));
typedef float f32x4 __attribute__((ext_vector_type(4)));

#define GLD16(g, l) __builtin_amdgcn_global_load_lds( \
    (const __attribute__((address_space(1))) unsigned int*)(g), \
    (__attribute__((address_space(3))) unsigned int*)(l), 16, 0, 0)

__device__ __forceinline__ unsigned short f2bf(float f){
  unsigned int u = __builtin_bit_cast(unsigned int, f);
  u += 0x7fffu + ((u >> 16) & 1u);
  return (unsigned short)(u >> 16);
}
__device__ __forceinline__ float bf2f(unsigned short h){
  unsigned int u = ((unsigned int)h) << 16;
  return __builtin_bit_cast(float, u);
}
__device__ __forceinline__ float fixv(float v){
  return (__builtin_isnan(v) || __builtin_isinf(v)) ? 0.f : v;
}

// ---------------- weight convert+transpose: W[K][N] fp32 -> WT[N][K] bf16 ----------------
__global__ __launch_bounds__(256) void wconv_kernel(const float* __restrict__ W,
    unsigned short* __restrict__ WT, int K, int N, const float* __restrict__ scale){
  __shared__ unsigned short T[64][72];
  int k0 = blockIdx.y*64, n0 = blockIdx.x*64;
  int t = threadIdx.x;
  int kr = t>>4, n4 = (t&15)*4;
  #pragma unroll
  for (int it=0; it<4; it++){
    int k = kr + it*16;
    float s = scale ? scale[k0+k] : 1.f;
    float4 v = *(const float4*)(W + (size_t)(k0+k)*N + n0 + n4);
    T[n4+0][k] = f2bf(v.x*s);
    T[n4+1][k] = f2bf(v.y*s);
    T[n4+2][k] = f2bf(v.z*s);
    T[n4+3][k] = f2bf(v.w*s);
  }
  __syncthreads();
  int u = t&7;
  #pragma unroll
  for (int it=0; it<2; it++){
    int n = (t>>3) + it*32;
    *(bf16x8*)(WT + (size_t)(n0+n)*K + k0 + u*8) = *(const bf16x8*)&T[n][u*8];
  }
}

// ---------------- RMSNorm fp32 in -> bf16 out ----------------
__global__ __launch_bounds__(256) void rmsnorm_kernel(const float* __restrict__ x,
    const float* __restrict__ g, unsigned short* __restrict__ out){
  int row = blockIdx.x; int t = threadIdx.x;
  float4 v = ((const float4*)(x + (size_t)row*Ee))[t];
  v.x=fixv(v.x); v.y=fixv(v.y); v.z=fixv(v.z); v.w=fixv(v.w);
  float ss = v.x*v.x + v.y*v.y + v.z*v.z + v.w*v.w;
  #pragma unroll
  for (int off=32; off>0; off>>=1) ss += __shfl_down(ss, off);
  __shared__ float red[4];
  if ((t&63)==0) red[t>>6] = ss;
  __syncthreads();
  float tot = red[0]+red[1]+red[2]+red[3];
  float rms = sqrtf(tot*(1.f/Ee) + 1e-6f);
  rms = fminf(fmaxf(rms, 1e-6f), 1e6f);
  float inv = 1.f/rms;
  float4 gv = ((const float4*)g)[t];
  uint2 o;
  o.x = (unsigned)f2bf(v.x*inv*gv.x) | ((unsigned)f2bf(v.y*inv*gv.y)<<16);
  o.y = (unsigned)f2bf(v.z*inv*gv.z) | ((unsigned)f2bf(v.w*inv*gv.w)<<16);
  ((uint2*)(out + (size_t)row*Ee))[t] = o;
}

// ---------------- bf16 GEMM: C[M,N] = A[M,K] @ Bt[N,K]^T ----------------
// 256(M)x128(N) tile, 512 threads (8 waves, 4Mx2N wave grid, 64x64 per wave).
// LDS: A 256x32 (16KB) + B 128x32 (8KB), double-buffered = 48KB.
// 24 staging segments/K-step (16 A + 8 B) -> 3 GLD16 per wave.
// 16B-chunk XOR swizzle on source + read (both-sides involution).
// MODE 0: C bf16. MODE 1: C fp32 = acc + res. MODE 2: C fp32 = acc*rowscale[m] + res,
//         K-loop truncated to round_up(klim[0], 32).
template<int MODE>
__global__ __launch_bounds__(512) void gemm_kernel(
    const unsigned short* __restrict__ A, const unsigned short* __restrict__ Bt,
    void* __restrict__ Cv, int M, int N, int K,
    const float* __restrict__ res, const float* __restrict__ rowscale,
    const float* __restrict__ klim){
  __shared__ __align__(16) unsigned short S[2][12288];   // [0,8192): A, [8192,12288): B
  int tid = threadIdx.x;
  int nbx = gridDim.x;
  int id = blockIdx.y * nbx + blockIdx.x;
  int chunk = (nbx * gridDim.y) >> 3;
  int wg = (id & 7) * chunk + (id >> 3);
  int m0 = (wg / nbx) * 256, n0 = (wg % nbx) * 128;
  int lane = tid & 63, wave = tid >> 6;
  int wm = (wave>>1)*64, wn = (wave&1)*64;
  int lrow = lane & 15;
  int lksw = (((lane>>4) ^ ((lrow>>1)&3)))*8;
  int kend = K;
  if (MODE==2 && klim){
    int sz = (int)klim[0];
    int ke = ((sz + 31) >> 5) << 5;
    kend = ke < K ? ke : K;
  }
  int nk = kend >> 5;
  // staging: wave w handles global segments 3w..3w+2
  int segr = lane >> 2;
  int cg = (((lane&3) ^ ((lane>>3)&3))) * 8;
  const unsigned short* gp[3];
  int loff[3];
  #pragma unroll
  for (int i=0;i<3;i++){
    int g = wave*3 + i;
    if (g < 16){ gp[i] = A  + (size_t)(m0 + g*16 + segr)*K + cg;       loff[i] = g*512 + lane*8; }
    else       { gp[i] = Bt + (size_t)(n0 + (g-16)*16 + segr)*K + cg;  loff[i] = 8192 + (g-16)*512 + lane*8; }
  }
  f32x4 acc[4][4] = {};
  #pragma unroll
  for (int i=0;i<3;i++) GLD16(gp[i], &S[0][loff[i] - lane*8]);
  __syncthreads();
  int cur = 0;
  for (int t=0; t<nk; ++t){
    if (t+1 < nk){
      int ko = (t+1) << 5;
      #pragma unroll
      for (int i=0;i<3;i++) GLD16(gp[i]+ko, &S[cur^1][loff[i] - lane*8]);
    }
    bf16x8 af[4], bfr[4];
    #pragma unroll
    for (int i=0;i<4;i++){
      af[i]  = *(const bf16x8*)&S[cur][(wm + i*16 + lrow)*32 + lksw];
      bfr[i] = *(const bf16x8*)&S[cur][8192 + (wn + i*16 + lrow)*32 + lksw];
    }
    #pragma unroll
    for (int mi=0;mi<4;mi++)
      #pragma unroll
      for (int ni=0;ni<4;ni++)
        acc[mi][ni] = __builtin_amdgcn_mfma_f32_16x16x32_bf16(af[mi], bfr[ni], acc[mi][ni], 0,0,0);
    __syncthreads();
    cur ^= 1;
  }
  int lg = lane >> 4;
  int rbase = m0 + wm + (lg<<2);
  int cbase = n0 + wn + lrow;
  #pragma unroll
  for (int mi=0;mi<4;mi++){
    #pragma unroll
    for (int r=0;r<4;r++){
      int row = rbase + mi*16 + r;
      float rs = (MODE==2) ? rowscale[row] : 1.f;
      #pragma unroll
      for (int ni=0;ni<4;ni++){
        int col = cbase + ni*16;
        float v = acc[mi][ni][r];
        if (MODE==0){
          ((unsigned short*)Cv)[(size_t)row*N + col] = f2bf(v);
        } else if (MODE==1){
          ((float*)Cv)[(size_t)row*N + col] = v + res[(size_t)row*N + col];
        } else {
          ((float*)Cv)[(size_t)row*N + col] = v*rs + res[(size_t)row*N + col];
        }
      }
    }
  }
}

// ---------------- fused gate+up GEMM (256x128, 512 thr) -> hidden = silu(g)*u masked ----------------
__global__ __launch_bounds__(512) void gateup_kernel(
    const unsigned short* __restrict__ A, const unsigned short* __restrict__ Gt,
    const unsigned short* __restrict__ Ut, unsigned short* __restrict__ Hid,
    const float* __restrict__ scal){
  __shared__ __align__(16) unsigned short S[2][16384];  // A[0,8192) G[8192,12288) U[12288,16384)
  int tid = threadIdx.x;
  int nbx = gridDim.x;
  int id = blockIdx.y * nbx + blockIdx.x;
  int chunk = (nbx * gridDim.y) >> 3;
  int wg = (id & 7) * chunk + (id >> 3);
  int m0 = (wg / nbx) * 256, n0 = (wg % nbx) * 128;
  int size = (int)scal[0];
  if (n0 >= size){
    int r = tid >> 1, cb = n0 + (tid&1)*64;
    unsigned short* hp = Hid + (size_t)(m0+r)*Ff + cb;
    bf16x8 z = {};
    #pragma unroll
    for (int i=0;i<8;i++) *(bf16x8*)(hp + i*8) = z;
    return;
  }
  int lane = tid & 63, wave = tid >> 6;
  int wm = (wave>>1)*64, wn = (wave&1)*64;
  int lrow = lane & 15;
  int lksw = (((lane>>4) ^ ((lrow>>1)&3)))*8;
  int segr = lane >> 2;
  int cg = (((lane&3) ^ ((lane>>3)&3))) * 8;
  const unsigned short* gp[4];
  int loff[4];
  #pragma unroll
  for (int i=0;i<4;i++){
    int g = wave*4 + i;
    if (g < 16)      { gp[i] = A  + (size_t)(m0 + g*16 + segr)*Ee + cg;       loff[i] = g*512; }
    else if (g < 24) { gp[i] = Gt + (size_t)(n0 + (g-16)*16 + segr)*Ee + cg;  loff[i] = 8192 + (g-16)*512; }
    else             { gp[i] = Ut + (size_t)(n0 + (g-24)*16 + segr)*Ee + cg;  loff[i] = 12288 + (g-24)*512; }
  }
  f32x4 ag[4][4] = {}, au[4][4] = {};
  #pragma unroll
  for (int i=0;i<4;i++) GLD16(gp[i], &S[0][loff[i]]);
  __syncthreads();
  int cur = 0;
  for (int t=0; t<32; ++t){
    if (t+1 < 32){
      int ko = (t+1) << 5;
      #pragma unroll
      for (int i=0;i<4;i++) GLD16(gp[i]+ko, &S[cur^1][loff[i]]);
    }
    bf16x8 af[4], bg4[4], bu4[4];
    #pragma unroll
    for (int i=0;i<4;i++){
      af[i]  = *(const bf16x8*)&S[cur][(wm + i*16 + lrow)*32 + lksw];
      bg4[i] = *(const bf16x8*)&S[cur][8192  + (wn + i*16 + lrow)*32 + lksw];
      bu4[i] = *(const bf16x8*)&S[cur][12288 + (wn + i*16 + lrow)*32 + lksw];
    }
    #pragma unroll
    for (int mi=0;mi<4;mi++)
      #pragma unroll
      for (int ni=0;ni<4;ni++){
        ag[mi][ni] = __builtin_amdgcn_mfma_f32_16x16x32_bf16(af[mi], bg4[ni], ag[mi][ni], 0,0,0);
        au[mi][ni] = __builtin_amdgcn_mfma_f32_16x16x32_bf16(af[mi], bu4[ni], au[mi][ni], 0,0,0);
      }
    __syncthreads();
    cur ^= 1;
  }
  int lg = lane >> 4;
  int rbase = m0 + wm + (lg<<2);
  int cbase = n0 + wn + lrow;
  #pragma unroll
  for (int mi=0;mi<4;mi++){
    #pragma unroll
    for (int r=0;r<4;r++){
      int row = rbase + mi*16 + r;
      #pragma unroll
      for (int ni=0;ni<4;ni++){
        int col = cbase + ni*16;
        float g = ag[mi][ni][r], u = au[mi][ni][r];
        float hv = (g * (1.f/(1.f+expf(-g)))) * u;
        if (col >= size) hv = 0.f;
        if (__builtin_isnan(hv) || __builtin_isinf(hv)) hv = 0.f;
        Hid[(size_t)row*Ff + col] = f2bf(hv);
      }
    }
  }
}

// ---------------- RoPE + ELU+1 on q,k in bf16 qkv ----------------
__global__ __launch_bounds__(256) void rope_kernel(unsigned short* __restrict__ qkv){
  size_t idx = (size_t)blockIdx.x*256 + threadIdx.x;    // B*L*H*32
  int i = (int)(idx & 31);
  int h = (int)((idx>>5) & 15);
  size_t bl = idx >> 9;
  int pos = (int)(bl & (Ll-1));
  int d0 = 2*i, d1 = d0+1;
  size_t base = bl*3072 + (size_t)h*64 + d0;
  const float LOG1E4_D32 = 0.2878231366242557f;  // ln(10000)/32
  float e0 = (float)(d0 < 32 ? d0 : d0-32);
  float e1 = (float)(d1 < 32 ? d1 : d1-32);
  float f0 = pos * expf(-e0*LOG1E4_D32);
  float f1 = pos * expf(-e1*LOG1E4_D32);
  float s0,c0,s1,c1;
  sincosf(f0,&s0,&c0); sincosf(f1,&s1,&c1);
  unsigned int* qp = (unsigned int*)(qkv + base);
  unsigned int qv = *qp;
  float q0 = bf2f((unsigned short)(qv&0xffff)), q1 = bf2f((unsigned short)(qv>>16));
  float r0 = q0*c0 - q1*s0;
  float r1 = q1*c1 + q0*s1;
  r0 = r0>0.f ? r0+1.f : expf(r0);
  r1 = r1>0.f ? r1+1.f : expf(r1);
  *qp = (unsigned)f2bf(r0) | ((unsigned)f2bf(r1)<<16);
  unsigned int* kp = (unsigned int*)(qkv + base + 1024);
  unsigned int kv = *kp;
  float k0v = bf2f((unsigned short)(kv&0xffff)), k1v = bf2f((unsigned short)(kv>>16));
  float t0 = k0v*c0 - k1v*s0;
  float t1 = k1v*c1 + k0v*s1;
  t0 = t0>0.f ? t0+1.f : expf(t0);
  t1 = t1>0.f ? t1+1.f : expf(t1);
  *kp = (unsigned)f2bf(t0) | ((unsigned)f2bf(t1)<<16);
}

// ---------------- per-chunk K^T V + K col sums via MFMA (ones-column trick) ----------------
__global__ __launch_bounds__(256) void chunksum_kernel(const unsigned short* __restrict__ qkv,
    float* __restrict__ Ssum){
  __shared__ __align__(16) unsigned short Kt[64][72];   // K^T[j][m]
  __shared__ __align__(16) unsigned short Vt[80][72];   // V^T[e][m]; row64=1.0, 65..79=0
  int c = blockIdx.x, bh = blockIdx.y;
  int b = bh >> 4, h = bh & 15;
  int tid = threadIdx.x, lane = tid & 63, wave = tid >> 6;
  int lr = lane & 15, lg = lane >> 4;
  f32x4 acc[5] = {};
  {
    int r16 = tid >> 4, m4 = (tid & 15) * 4;
    unsigned short val = (r16 == 0) ? (unsigned short)0x3F80 : (unsigned short)0;
    #pragma unroll
    for (int u=0; u<4; u++) Vt[64 + r16][m4 + u] = val;
  }
  for (int t=0; t<4; ++t){
    __syncthreads();
    #pragma unroll
    for (int i=0; i<2; i++){
      int tau = tid + i*256;
      int m = tau & 63, dg = (tau >> 6) * 8;
      size_t g = ((size_t)(b*Ll + c*CHk + t*64 + m))*3072 + h*64 + dg;
      bf16x8 kv = *(const bf16x8*)(qkv + g + 1024);
      bf16x8 vv = *(const bf16x8*)(qkv + g + 2048);
      #pragma unroll
      for (int u=0; u<8; u++){
        Kt[dg+u][m] = (unsigned short)kv[u];
        Vt[dg+u][m] = (unsigned short)vv[u];
      }
    }
    __syncthreads();
    #pragma unroll
    for (int kk=0; kk<2; kk++){
      bf16x8 af = *(const bf16x8*)&Kt[wave*16 + lr][kk*32 + lg*8];
      #pragma unroll
      for (int ni=0; ni<5; ni++){
        bf16x8 vf = *(const bf16x8*)&Vt[ni*16 + lr][kk*32 + lg*8];
        acc[ni] = __builtin_amdgcn_mfma_f32_16x16x32_bf16(af, vf, acc[ni], 0,0,0);
      }
    }
  }
  float* S = Ssum + ((size_t)bh*NCc + c)*4160;
  int j = wave*16 + lg*4;
  #pragma unroll
  for (int ni=0; ni<4; ni++)
    #pragma unroll
    for (int r=0; r<4; r++)
      S[(size_t)(j+r)*64 + ni*16 + lr] = acc[ni][r];
  if (lr == 0){
    #pragma unroll
    for (int r=0; r<4; r++) S[4096 + j + r] = acc[4][r];
  }
}

// ---------------- exclusive prefix over chunks ----------------
__global__ __launch_bounds__(256) void prefix_kernel(const float* __restrict__ Ssum,
    float* __restrict__ Spre){
  int bh = blockIdx.x; int t = threadIdx.x;
  size_t base = (size_t)bh*NCc*4160;
  for (int e=t; e<4160; e+=256){
    float acc = 0.f;
    #pragma unroll
    for (int c=0;c<NCc;c++){
      Spre[base + (size_t)c*4160 + e] = acc;
      acc += Ssum[base + (size_t)c*4160 + e];
    }
  }
}

// ---------------- per-chunk causal attention via MFMA ----------------
__global__ __launch_bounds__(256, 2) void attnout_kernel(const unsigned short* __restrict__ qkv,
    const float* __restrict__ Spre, unsigned short* __restrict__ attn){
  __shared__ __align__(16) unsigned short SpT[64][72];     // Spre^T[e][j] bf16
  __shared__ __align__(16) unsigned short Ks[64][72];      // K[m][d]
  __shared__ __align__(16) unsigned short Vt[64][72];      // V^T[d][m]
  __shared__ __align__(16) unsigned short P[4][64][72];    // per-wave masked S bf16
  __shared__ float qZd[256];
  int c = blockIdx.x, bh = blockIdx.y;
  int b = bh >> 4, h = bh & 15;
  int tid = threadIdx.x, lane = tid & 63, wave = tid >> 6;
  int lr = lane & 15, lg = lane >> 4;
  const float* Sp = Spre + ((size_t)bh*NCc + c)*4160;

  {
    float zacc = 0.f;
    const unsigned short* qp = qkv + ((size_t)(b*Ll + c*CHk + tid))*3072 + (size_t)h*64;
    #pragma unroll
    for (int g8=0; g8<8; g8++){
      bf16x8 qv = *(const bf16x8*)(qp + g8*8);
      #pragma unroll
      for (int u=0; u<8; u++) zacc += bf2f((unsigned short)qv[u]) * Sp[4096 + g8*8 + u];
    }
    qZd[tid] = zacc;
  }
  #pragma unroll
  for (int i=0; i<2; i++){
    int tau = tid + i*256;
    int j = tau & 63, dg = (tau >> 6) * 8;
    const float* sp = Sp + j*64 + dg;
    #pragma unroll
    for (int u=0; u<8; u++) SpT[dg+u][j] = f2bf(sp[u]);
  }
  bf16x8 af[4][2];
  #pragma unroll
  for (int mi=0; mi<4; mi++){
    size_t qrow = ((size_t)(b*Ll + c*CHk + wave*64 + mi*16 + lr))*3072 + (size_t)h*64;
    #pragma unroll
    for (int kk=0; kk<2; kk++)
      af[mi][kk] = *(const bf16x8*)(qkv + qrow + kk*32 + lg*8);
  }
  __syncthreads();
  f32x4 accO[4][4] = {};
  #pragma unroll
  for (int kk=0; kk<2; kk++){
    #pragma unroll
    for (int ni=0; ni<4; ni++){
      bf16x8 bsp = *(const bf16x8*)&SpT[ni*16 + lr][kk*32 + lg*8];
      #pragma unroll
      for (int mi=0; mi<4; mi++)
        accO[mi][ni] = __builtin_amdgcn_mfma_f32_16x16x32_bf16(af[mi][kk], bsp, accO[mi][ni], 0,0,0);
    }
  }
  f32x4 den4[4] = {};
  for (int t=0; t<4; ++t){
    __syncthreads();
    #pragma unroll
    for (int i=0; i<2; i++){
      int tau = tid + i*256;
      int m = tau & 63, dg = (tau >> 6) * 8;
      size_t g = ((size_t)(b*Ll + c*CHk + t*64 + m))*3072 + h*64 + dg;
      *(bf16x8*)&Ks[m][dg] = *(const bf16x8*)(qkv + g + 1024);
      bf16x8 vv = *(const bf16x8*)(qkv + g + 2048);
      #pragma unroll
      for (int u=0; u<8; u++) Vt[dg+u][m] = (unsigned short)vv[u];
    }
    __syncthreads();
    if (wave < t) continue;
    f32x4 sacc[4][4] = {};
    #pragma unroll
    for (int kk=0; kk<2; kk++){
      #pragma unroll
      for (int ni=0; ni<4; ni++){
        bf16x8 kf = *(const bf16x8*)&Ks[ni*16 + lr][kk*32 + lg*8];
        #pragma unroll
        for (int mi=0; mi<4; mi++)
          sacc[mi][ni] = __builtin_amdgcn_mfma_f32_16x16x32_bf16(af[mi][kk], kf, sacc[mi][ni], 0,0,0);
      }
    }
    unsigned short (*Pw)[72] = P[wave];
    bool diag = (t == wave);
    #pragma unroll
    for (int mi=0; mi<4; mi++){
      #pragma unroll
      for (int r=0; r<4; r++){
        int q_l = mi*16 + lg*4 + r;
        float rs = 0.f;
        #pragma unroll
        for (int ni=0; ni<4; ni++){
          int m_l = ni*16 + lr;
          float v = sacc[mi][ni][r];
          if (diag && m_l > q_l) v = 0.f;
          rs += v;
          Pw[q_l][m_l] = f2bf(v);
        }
        rs += __shfl_xor(rs, 1);
        rs += __shfl_xor(rs, 2);
        rs += __shfl_xor(rs, 4);
        rs += __shfl_xor(rs, 8);
        den4[mi][r] += rs;
      }
    }
    #pragma unroll
    for (int kk=0; kk<2; kk++){
      bf16x8 pa[4], vf[4];
      #pragma unroll
      for (int mi=0; mi<4; mi++) pa[mi] = *(const bf16x8*)&Pw[mi*16 + lr][kk*32 + lg*8];
      #pragma unroll
      for (int ni=0; ni<4; ni++) vf[ni] = *(const bf16x8*)&Vt[ni*16 + lr][kk*32 + lg*8];
      #pragma unroll
      for (int mi=0; mi<4; mi++)
        #pragma unroll
        for (int ni=0; ni<4; ni++)
          accO[mi][ni] = __builtin_amdgcn_mfma_f32_16x16x32_bf16(pa[mi], vf[ni], accO[mi][ni], 0,0,0);
    }
  }
  #pragma unroll
  for (int mi=0; mi<4; mi++){
    #pragma unroll
    for (int r=0; r<4; r++){
      int q_l = mi*16 + lg*4 + r;
      float dtot = den4[mi][r] + qZd[wave*64 + q_l];
      float inv = 1.f / fmaxf(dtot, 1e-6f);
      size_t l = (size_t)(b*Ll + c*CHk + wave*64 + q_l);
      unsigned short* op = attn + l*Ee + h*64 + lr;
      #pragma unroll
      for (int ni=0; ni<4; ni++)
        op[ni*16] = f2bf(accO[mi][ni][r] * inv);
    }
  }
}

// ---------------- column mean over L, deterministic 2-stage ----------------
__global__ __launch_bounds__(256) void colmean1_kernel(const unsigned short* __restrict__ h2,
    float* __restrict__ partial){
  int e = blockIdx.x*256 + threadIdx.x;
  int ly = blockIdx.y;
  int b = blockIdx.z;
  int l0 = ly * 128;
  float s = 0.f;
  for (int l=l0; l<l0+128; l++) s += bf2f(h2[((size_t)(b*Ll + l))*Ee + e]);
  partial[((size_t)(b*32 + ly))*Ee + e] = s;
}
__global__ __launch_bounds__(256) void colmean2_kernel(const float* __restrict__ partial,
    float* __restrict__ xmean){
  int e = blockIdx.x*256 + threadIdx.x;
  int b = blockIdx.y;
  float s = 0.f;
  #pragma unroll
  for (int ly=0; ly<32; ly++) s += partial[((size_t)(b*32 + ly))*Ee + e];
  xmean[b*Ee + e] = s * (1.f/Ll);
}

// ---------------- dim predictor -> floored size ----------------
__global__ __launch_bounds__(256) void dimpred_kernel(const float* __restrict__ xmean,
    const float* __restrict__ w_dp1, const float* __restrict__ w_dp2,
    float* __restrict__ scalars){
  __shared__ float red[256];
  __shared__ float ratio_s[2];
  int t = threadIdx.x;
  for (int b=0;b<2;b++){
    float s = 0.f;
    for (int k=0;k<1024;k++) s += xmean[b*Ee + k] * w_dp1[k*256 + t];
    float sil = s * (1.f/(1.f+expf(-s)));
    red[t] = sil * w_dp2[t];
    __syncthreads();
    for (int off=128; off>0; off>>=1){
      if (t<off) red[t] += red[t+off];
      __syncthreads();
    }
    if (t==0){
      float dr = 1.f/(1.f+expf(-red[0]));
      float ratio = 1.f + (dr-0.5f)*1.0f;       // 2*ADAPT = 1
      ratio = fminf(fmaxf(ratio, 0.5f), 1.5f);
      ratio_s[b] = ratio;
    }
    __syncthreads();
  }
  if (t==0){
    float rm = 0.5f*(ratio_s[0]+ratio_s[1]);
    float size_f = floorf(3072.f * rm);
    if (size_f < 1.f) size_f = 1.f;
    scalars[0] = size_f;
  }
}

// ---------------- per-row sumsq of hidden -> inv_rms ----------------
__global__ __launch_bounds__(256) void rowrms_kernel(const unsigned short* __restrict__ Hid,
    const float* __restrict__ scal, float* __restrict__ invr){
  int row = blockIdx.x; int t = threadIdx.x;
  float size_f = scal[0];
  int c8max = ((int)size_f + 7) >> 3;
  float ss = 0.f;
  for (int c8 = t; c8 < c8max; c8 += 256){
    bf16x8 v = *(const bf16x8*)(Hid + (size_t)row*Ff + c8*8);
    #pragma unroll
    for (int u=0;u<8;u++){ float f = bf2f((unsigned short)v[u]); ss += f*f; }
  }
  #pragma unroll
  for (int off=32; off>0; off>>=1) ss += __shfl_down(ss, off);
  __shared__ float red[4];
  if ((t&63)==0) red[t>>6] = ss;
  __syncthreads();
  if (t==0){
    float tot = red[0]+red[1]+red[2]+red[3];
    float rms = sqrtf(tot/size_f + 1e-6f);
    rms = fminf(fmaxf(rms, 1e-6f), 1e6f);
    invr[row] = 1.f/rms;
  }
}

extern "C" void kernel_launch(void* const* d_in, const int* in_sizes, int n_in,
                              void* d_out, int out_size, void* d_ws, size_t ws_size,
                              hipStream_t stream){
  const float* x      = (const float*)d_in[0];
  const float* w_qkv  = (const float*)d_in[1];
  const float* w_out  = (const float*)d_in[2];
  const float* g1     = (const float*)d_in[3];
  const float* g2     = (const float*)d_in[4];
  const float* w_dp1  = (const float*)d_in[5];
  const float* w_dp2  = (const float*)d_in[6];
  const float* w_gate = (const float*)d_in[7];
  const float* w_up   = (const float*)d_in[8];
  const float* w_down = (const float*)d_in[9];
  const float* g_hid  = (const float*)d_in[10];
  float* out = (float*)d_out;

  char* w = (char*)d_ws;
  size_t o = 0;
  auto alloc = [&](size_t bytes)->char*{ char* p = w + o; o += (bytes + 255) & ~255ull; return p; };
  unsigned short* R1   = (unsigned short*)alloc((size_t)8192*1024*2);   // h/attn/h2 bf16
  float*          x2   = (float*)alloc((size_t)8192*1024*4);            // post-attn residual fp32
  char*           R2   = alloc((size_t)8192*4608*2);                    // qkv bf16 then hidden
  unsigned short* qkvT = (unsigned short*)alloc((size_t)3072*1024*2);
  unsigned short* outT = (unsigned short*)alloc((size_t)1024*1024*2);
  char*           W2   = alloc((size_t)3*4608*1024*2);                  // Ssum/Spre then gateT/upT/downT
  float*       partial = (float*)alloc((size_t)64*1024*4);
  float*         xmean = (float*)alloc(2048*4);
  float*          scal = (float*)alloc(64);
  float*          invr = (float*)alloc(8192*4);

  unsigned short* qkv    = (unsigned short*)R2;
  unsigned short* hidden = (unsigned short*)R2;
  float* Ssum = (float*)W2;
  float* Spre = Ssum + (size_t)512*4160;
  unsigned short* gateT = (unsigned short*)W2;
  unsigned short* upT   = gateT + (size_t)4608*1024;
  unsigned short* downT = upT   + (size_t)4608*1024;

  wconv_kernel<<<dim3(3072/64, 1024/64),256,0,stream>>>(w_qkv, qkvT, 1024, 3072, nullptr);
  wconv_kernel<<<dim3(1024/64, 1024/64),256,0,stream>>>(w_out, outT, 1024, 1024, nullptr);

  rmsnorm_kernel<<<8192,256,0,stream>>>(x, g1, R1);
  gemm_kernel<0><<<dim3(3072/128, 8192/256),512,0,stream>>>(R1, qkvT, qkv,
      8192,3072,1024, nullptr,nullptr,nullptr);
  rope_kernel<<<16384,256,0,stream>>>(qkv);
  chunksum_kernel<<<dim3(NCc,Bb*Hh),256,0,stream>>>(qkv, Ssum);
  prefix_kernel<<<Bb*Hh,256,0,stream>>>(Ssum, Spre);
  attnout_kernel<<<dim3(NCc,Bb*Hh),256,0,stream>>>(qkv, Spre, R1);

  wconv_kernel<<<dim3(4608/64, 1024/64),256,0,stream>>>(w_gate, gateT, 1024, 4608, nullptr);
  wconv_kernel<<<dim3(4608/64, 1024/64),256,0,stream>>>(w_up,   upT,   1024, 4608, nullptr);
  wconv_kernel<<<dim3(1024/64, 4608/64),256,0,stream>>>(w_down, downT, 4608, 1024, g_hid);

  gemm_kernel<1><<<dim3(1024/128, 8192/256),512,0,stream>>>(R1, outT, x2,
      8192,1024,1024, x,nullptr,nullptr);
  rmsnorm_kernel<<<8192,256,0,stream>>>(x2, g2, R1);
  colmean1_kernel<<<dim3(4,32,2),256,0,stream>>>(R1, partial);
  colmean2_kernel<<<dim3(4,2),256,0,stream>>>(partial, xmean);
  dimpred_kernel<<<1,256,0,stream>>>(xmean, w_dp1, w_dp2, scal);
  gateup_kernel<<<dim3(4608/128, 8192/256),512,0,stream>>>(R1, gateT, upT, hidden, scal);
  rowrms_kernel<<<8192,256,0,stream>>>(hidden, scal, invr);
  gemm_kernel<2><<<dim3(1024/128, 8192/256),512,0,stream>>>(hidden, downT, out,
      8192,1024,4608, x2, invr, scal);
}

// Round 9
// 489.268 us; speedup vs baseline: 2.6882x; 1.0524x over previous
//
#include <hip/hip_runtime.h>
#include <hip/hip_bf16.h>

#define Ee 1024
#define Hh 16
#define Ff 4608
#define Ll 4096
#define Bb 2
#define NCc 16
#define CHk 256

typedef short bf16x8 __attribute__((ext_vector_type(8)));
typedef float f32x4 __attribute__((ext_vector_type(4)));

#define GLD16(g, l) __builtin_amdgcn_global_load_lds( \
    (const __attribute__((address_space(1))) unsigned int*)(g), \
    (__attribute__((address_space(3))) unsigned int*)(l), 16, 0, 0)

__device__ __forceinline__ unsigned short f2bf(float f){
  unsigned int u = __builtin_bit_cast(unsigned int, f);
  u += 0x7fffu + ((u >> 16) & 1u);
  return (unsigned short)(u >> 16);
}
__device__ __forceinline__ float bf2f(unsigned short h){
  unsigned int u = ((unsigned int)h) << 16;
  return __builtin_bit_cast(float, u);
}
__device__ __forceinline__ float fixv(float v){
  return (__builtin_isnan(v) || __builtin_isinf(v)) ? 0.f : v;
}

// ---------------- weight convert+transpose: W[K][N] fp32 -> WT[N][K] bf16 ----------------
__global__ __launch_bounds__(256) void wconv_kernel(const float* __restrict__ W,
    unsigned short* __restrict__ WT, int K, int N, const float* __restrict__ scale){
  __shared__ unsigned short T[64][72];
  int k0 = blockIdx.y*64, n0 = blockIdx.x*64;
  int t = threadIdx.x;
  int kr = t>>4, n4 = (t&15)*4;
  #pragma unroll
  for (int it=0; it<4; it++){
    int k = kr + it*16;
    float s = scale ? scale[k0+k] : 1.f;
    float4 v = *(const float4*)(W + (size_t)(k0+k)*N + n0 + n4);
    T[n4+0][k] = f2bf(v.x*s);
    T[n4+1][k] = f2bf(v.y*s);
    T[n4+2][k] = f2bf(v.z*s);
    T[n4+3][k] = f2bf(v.w*s);
  }
  __syncthreads();
  int u = t&7;
  #pragma unroll
  for (int it=0; it<2; it++){
    int n = (t>>3) + it*32;
    *(bf16x8*)(WT + (size_t)(n0+n)*K + k0 + u*8) = *(const bf16x8*)&T[n][u*8];
  }
}

// ---------------- RMSNorm fp32 in -> bf16 out ----------------
__global__ __launch_bounds__(256) void rmsnorm_kernel(const float* __restrict__ x,
    const float* __restrict__ g, unsigned short* __restrict__ out){
  int row = blockIdx.x; int t = threadIdx.x;
  float4 v = ((const float4*)(x + (size_t)row*Ee))[t];
  v.x=fixv(v.x); v.y=fixv(v.y); v.z=fixv(v.z); v.w=fixv(v.w);
  float ss = v.x*v.x + v.y*v.y + v.z*v.z + v.w*v.w;
  #pragma unroll
  for (int off=32; off>0; off>>=1) ss += __shfl_down(ss, off);
  __shared__ float red[4];
  if ((t&63)==0) red[t>>6] = ss;
  __syncthreads();
  float tot = red[0]+red[1]+red[2]+red[3];
  float rms = sqrtf(tot*(1.f/Ee) + 1e-6f);
  rms = fminf(fmaxf(rms, 1e-6f), 1e6f);
  float inv = 1.f/rms;
  float4 gv = ((const float4*)g)[t];
  uint2 o;
  o.x = (unsigned)f2bf(v.x*inv*gv.x) | ((unsigned)f2bf(v.y*inv*gv.y)<<16);
  o.y = (unsigned)f2bf(v.z*inv*gv.z) | ((unsigned)f2bf(v.w*inv*gv.w)<<16);
  ((uint2*)(out + (size_t)row*Ee))[t] = o;
}

// ---------------- bf16 GEMM: C[M,N] = A[M,K] @ Bt[N,K]^T ----------------
// 256x128 tile, 512 thr, BK=64 (two 32-sub-tiles), 2-deep LDS dbuf (96KB),
// global_load_lds staging with both-sides 16B-chunk XOR swizzle.
// One __syncthreads per K-tile (correctness); per-phase s_barrier + setprio (pacing).
// MODE 0: C bf16. MODE 1: C fp32 = acc + res.
// MODE 2: C fp32 = acc*inv_rms(sumsq[row], klim[0]) + res; K truncated to round64(klim[0]).
template<int MODE>
__global__ __launch_bounds__(512) void gemm_kernel(
    const unsigned short* __restrict__ A, const unsigned short* __restrict__ Bt,
    void* __restrict__ Cv, int M, int N, int K,
    const float* __restrict__ res, const float* __restrict__ rowscale,
    const float* __restrict__ klim){
  __shared__ __align__(16) unsigned short S[2][24576];   // per buf: 2 sub-tiles of [A 8192 | B 4096]
  int tid = threadIdx.x;
  int nbx = gridDim.x;
  int id = blockIdx.y * nbx + blockIdx.x;
  int chunk = (nbx * gridDim.y) >> 3;
  int wg = (id & 7) * chunk + (id >> 3);
  int m0 = (wg / nbx) * 256, n0 = (wg % nbx) * 128;
  int lane = tid & 63, wave = tid >> 6;
  int wm = (wave>>1)*64, wn = (wave&1)*64;
  int lrow = lane & 15;
  int lksw = (((lane>>4) ^ ((lrow>>1)&3)))*8;
  float klim0 = (MODE==2 && klim) ? klim[0] : 0.f;
  int kend = K;
  if (MODE==2 && klim){
    int sz = (int)klim0;
    int ke = ((sz + 63) >> 6) << 6;
    kend = ke < K ? ke : K;
  }
  int nk2 = kend >> 6;
  int segr = lane >> 2;
  int cg = (((lane&3) ^ ((lane>>3)&3))) * 8;
  const unsigned short* gp[3];
  int loff[3];
  #pragma unroll
  for (int i=0;i<3;i++){
    int g = wave*3 + i;
    if (g < 16){ gp[i] = A  + (size_t)(m0 + g*16 + segr)*K + cg;       loff[i] = g*512; }
    else       { gp[i] = Bt + (size_t)(n0 + (g-16)*16 + segr)*K + cg;  loff[i] = 8192 + (g-16)*512; }
  }
  f32x4 acc[4][4] = {};
  #pragma unroll
  for (int i=0;i<3;i++){
    GLD16(gp[i],    &S[0][loff[i]]);
    GLD16(gp[i]+32, &S[0][12288 + loff[i]]);
  }
  __syncthreads();
  int cur = 0;
  for (int t=0; t<nk2; ++t){
    if (t+1 < nk2){
      int ko = (t+1) << 6;
      #pragma unroll
      for (int i=0;i<3;i++){
        GLD16(gp[i]+ko,    &S[cur^1][loff[i]]);
        GLD16(gp[i]+ko+32, &S[cur^1][12288 + loff[i]]);
      }
    }
    #pragma unroll
    for (int kk=0; kk<2; kk++){
      int base = kk*12288;
      bf16x8 af[4], bfr[4];
      #pragma unroll
      for (int i=0;i<4;i++){
        af[i]  = *(const bf16x8*)&S[cur][base + (wm + i*16 + lrow)*32 + lksw];
        bfr[i] = *(const bf16x8*)&S[cur][base + 8192 + (wn + i*16 + lrow)*32 + lksw];
      }
      __builtin_amdgcn_s_setprio(1);
      #pragma unroll
      for (int mi=0;mi<4;mi++)
        #pragma unroll
        for (int ni=0;ni<4;ni++)
          acc[mi][ni] = __builtin_amdgcn_mfma_f32_16x16x32_bf16(af[mi], bfr[ni], acc[mi][ni], 0,0,0);
      __builtin_amdgcn_s_setprio(0);
      if (kk==0) __builtin_amdgcn_s_barrier();   // pacing only; data stable all iteration
    }
    __syncthreads();
    cur ^= 1;
  }
  int lg = lane >> 4;
  int rbase = m0 + wm + (lg<<2);
  int cbase = n0 + wn + lrow;
  #pragma unroll
  for (int mi=0;mi<4;mi++){
    #pragma unroll
    for (int r=0;r<4;r++){
      int row = rbase + mi*16 + r;
      float rs = 1.f;
      if (MODE==2){
        float rms = sqrtf(rowscale[row]/klim0 + 1e-6f);
        rms = fminf(fmaxf(rms, 1e-6f), 1e6f);
        rs = 1.f/rms;
      }
      #pragma unroll
      for (int ni=0;ni<4;ni++){
        int col = cbase + ni*16;
        float v = acc[mi][ni][r];
        if (MODE==0){
          ((unsigned short*)Cv)[(size_t)row*N + col] = f2bf(v);
        } else if (MODE==1){
          ((float*)Cv)[(size_t)row*N + col] = v + res[(size_t)row*N + col];
        } else {
          ((float*)Cv)[(size_t)row*N + col] = v*rs + res[(size_t)row*N + col];
        }
      }
    }
  }
}

// ---------------- fused gate+up GEMM (256x128, BK=64, 128KB LDS) ----------------
// hidden = silu(g)*u masked; also accumulates per-row sumsq (fp32 atomics).
__global__ __launch_bounds__(512) void gateup_kernel(
    const unsigned short* __restrict__ A, const unsigned short* __restrict__ Gt,
    const unsigned short* __restrict__ Ut, unsigned short* __restrict__ Hid,
    const float* __restrict__ scal, float* __restrict__ sumsq){
  __shared__ __align__(16) unsigned short S[2][32768];  // per buf: 2 subtiles of [A 8192|G 4096|U 4096]
  int tid = threadIdx.x;
  int nbx = gridDim.x;
  int id = blockIdx.y * nbx + blockIdx.x;
  int chunk = (nbx * gridDim.y) >> 3;
  int wg = (id & 7) * chunk + (id >> 3);
  int m0 = (wg / nbx) * 256, n0 = (wg % nbx) * 128;
  int size = (int)scal[0];
  if (n0 >= size){
    int r = tid >> 1, cb = n0 + (tid&1)*64;
    unsigned short* hp = Hid + (size_t)(m0+r)*Ff + cb;
    bf16x8 z = {};
    #pragma unroll
    for (int i=0;i<8;i++) *(bf16x8*)(hp + i*8) = z;
    return;
  }
  int lane = tid & 63, wave = tid >> 6;
  int wm = (wave>>1)*64, wn = (wave&1)*64;
  int lrow = lane & 15;
  int lksw = (((lane>>4) ^ ((lrow>>1)&3)))*8;
  int segr = lane >> 2;
  int cg = (((lane&3) ^ ((lane>>3)&3))) * 8;
  const unsigned short* gp[4];
  int loff[4];
  #pragma unroll
  for (int i=0;i<4;i++){
    int g = wave*4 + i;
    if (g < 16)      { gp[i] = A  + (size_t)(m0 + g*16 + segr)*Ee + cg;       loff[i] = g*512; }
    else if (g < 24) { gp[i] = Gt + (size_t)(n0 + (g-16)*16 + segr)*Ee + cg;  loff[i] = 8192 + (g-16)*512; }
    else             { gp[i] = Ut + (size_t)(n0 + (g-24)*16 + segr)*Ee + cg;  loff[i] = 12288 + (g-24)*512; }
  }
  f32x4 ag[4][4] = {}, au[4][4] = {};
  #pragma unroll
  for (int i=0;i<4;i++){
    GLD16(gp[i],    &S[0][loff[i]]);
    GLD16(gp[i]+32, &S[0][16384 + loff[i]]);
  }
  __syncthreads();
  int cur = 0;
  for (int t=0; t<16; ++t){
    if (t+1 < 16){
      int ko = (t+1) << 6;
      #pragma unroll
      for (int i=0;i<4;i++){
        GLD16(gp[i]+ko,    &S[cur^1][loff[i]]);
        GLD16(gp[i]+ko+32, &S[cur^1][16384 + loff[i]]);
      }
    }
    #pragma unroll
    for (int kk=0; kk<2; kk++){
      int base = kk*16384;
      bf16x8 af[4], bg4[4], bu4[4];
      #pragma unroll
      for (int i=0;i<4;i++){
        af[i]  = *(const bf16x8*)&S[cur][base + (wm + i*16 + lrow)*32 + lksw];
        bg4[i] = *(const bf16x8*)&S[cur][base + 8192  + (wn + i*16 + lrow)*32 + lksw];
        bu4[i] = *(const bf16x8*)&S[cur][base + 12288 + (wn + i*16 + lrow)*32 + lksw];
      }
      __builtin_amdgcn_s_setprio(1);
      #pragma unroll
      for (int mi=0;mi<4;mi++)
        #pragma unroll
        for (int ni=0;ni<4;ni++){
          ag[mi][ni] = __builtin_amdgcn_mfma_f32_16x16x32_bf16(af[mi], bg4[ni], ag[mi][ni], 0,0,0);
          au[mi][ni] = __builtin_amdgcn_mfma_f32_16x16x32_bf16(af[mi], bu4[ni], au[mi][ni], 0,0,0);
        }
      __builtin_amdgcn_s_setprio(0);
      if (kk==0) __builtin_amdgcn_s_barrier();
    }
    __syncthreads();
    cur ^= 1;
  }
  int lg = lane >> 4;
  int lr = lrow;
  int rbase = m0 + wm + (lg<<2);
  int cbase = n0 + wn + lr;
  #pragma unroll
  for (int mi=0;mi<4;mi++){
    #pragma unroll
    for (int r=0;r<4;r++){
      int row = rbase + mi*16 + r;
      float s4 = 0.f;
      #pragma unroll
      for (int ni=0;ni<4;ni++){
        int col = cbase + ni*16;
        float g = ag[mi][ni][r], u = au[mi][ni][r];
        float hv = (g * (1.f/(1.f+expf(-g)))) * u;
        if (col >= size) hv = 0.f;
        if (__builtin_isnan(hv) || __builtin_isinf(hv)) hv = 0.f;
        Hid[(size_t)row*Ff + col] = f2bf(hv);
        s4 += hv*hv;
      }
      s4 += __shfl_xor(s4, 1);
      s4 += __shfl_xor(s4, 2);
      s4 += __shfl_xor(s4, 4);
      s4 += __shfl_xor(s4, 8);
      if (lr == 0) atomicAdd(&sumsq[row], s4);
    }
  }
}

// ---------------- RoPE + ELU+1 on q,k in bf16 qkv ----------------
__global__ __launch_bounds__(256) void rope_kernel(unsigned short* __restrict__ qkv){
  size_t idx = (size_t)blockIdx.x*256 + threadIdx.x;    // B*L*H*32
  int i = (int)(idx & 31);
  int h = (int)((idx>>5) & 15);
  size_t bl = idx >> 9;
  int pos = (int)(bl & (Ll-1));
  int d0 = 2*i, d1 = d0+1;
  size_t base = bl*3072 + (size_t)h*64 + d0;
  const float LOG1E4_D32 = 0.2878231366242557f;  // ln(10000)/32
  float e0 = (float)(d0 < 32 ? d0 : d0-32);
  float e1 = (float)(d1 < 32 ? d1 : d1-32);
  float f0 = pos * expf(-e0*LOG1E4_D32);
  float f1 = pos * expf(-e1*LOG1E4_D32);
  float s0,c0,s1,c1;
  sincosf(f0,&s0,&c0); sincosf(f1,&s1,&c1);
  unsigned int* qp = (unsigned int*)(qkv + base);
  unsigned int qv = *qp;
  float q0 = bf2f((unsigned short)(qv&0xffff)), q1 = bf2f((unsigned short)(qv>>16));
  float r0 = q0*c0 - q1*s0;
  float r1 = q1*c1 + q0*s1;
  r0 = r0>0.f ? r0+1.f : expf(r0);
  r1 = r1>0.f ? r1+1.f : expf(r1);
  *qp = (unsigned)f2bf(r0) | ((unsigned)f2bf(r1)<<16);
  unsigned int* kp = (unsigned int*)(qkv + base + 1024);
  unsigned int kv = *kp;
  float k0v = bf2f((unsigned short)(kv&0xffff)), k1v = bf2f((unsigned short)(kv>>16));
  float t0 = k0v*c0 - k1v*s0;
  float t1 = k1v*c1 + k0v*s1;
  t0 = t0>0.f ? t0+1.f : expf(t0);
  t1 = t1>0.f ? t1+1.f : expf(t1);
  *kp = (unsigned)f2bf(t0) | ((unsigned)f2bf(t1)<<16);
}

// ---------------- per-chunk K^T V + K col sums via MFMA (ones-column trick) ----------------
__global__ __launch_bounds__(256) void chunksum_kernel(const unsigned short* __restrict__ qkv,
    float* __restrict__ Ssum){
  __shared__ __align__(16) unsigned short Kt[64][72];   // K^T[j][m]
  __shared__ __align__(16) unsigned short Vt[80][72];   // V^T[e][m]; row64=1.0, 65..79=0
  int c = blockIdx.x, bh = blockIdx.y;
  int b = bh >> 4, h = bh & 15;
  int tid = threadIdx.x, lane = tid & 63, wave = tid >> 6;
  int lr = lane & 15, lg = lane >> 4;
  f32x4 acc[5] = {};
  {
    int r16 = tid >> 4, m4 = (tid & 15) * 4;
    unsigned short val = (r16 == 0) ? (unsigned short)0x3F80 : (unsigned short)0;
    #pragma unroll
    for (int u=0; u<4; u++) Vt[64 + r16][m4 + u] = val;
  }
  for (int t=0; t<4; ++t){
    __syncthreads();
    #pragma unroll
    for (int i=0; i<2; i++){
      int tau = tid + i*256;
      int m = tau & 63, dg = (tau >> 6) * 8;
      size_t g = ((size_t)(b*Ll + c*CHk + t*64 + m))*3072 + h*64 + dg;
      bf16x8 kv = *(const bf16x8*)(qkv + g + 1024);
      bf16x8 vv = *(const bf16x8*)(qkv + g + 2048);
      #pragma unroll
      for (int u=0; u<8; u++){
        Kt[dg+u][m] = (unsigned short)kv[u];
        Vt[dg+u][m] = (unsigned short)vv[u];
      }
    }
    __syncthreads();
    #pragma unroll
    for (int kk=0; kk<2; kk++){
      bf16x8 af = *(const bf16x8*)&Kt[wave*16 + lr][kk*32 + lg*8];
      #pragma unroll
      for (int ni=0; ni<5; ni++){
        bf16x8 vf = *(const bf16x8*)&Vt[ni*16 + lr][kk*32 + lg*8];
        acc[ni] = __builtin_amdgcn_mfma_f32_16x16x32_bf16(af, vf, acc[ni], 0,0,0);
      }
    }
  }
  float* S = Ssum + ((size_t)bh*NCc + c)*4160;
  int j = wave*16 + lg*4;
  #pragma unroll
  for (int ni=0; ni<4; ni++)
    #pragma unroll
    for (int r=0; r<4; r++)
      S[(size_t)(j+r)*64 + ni*16 + lr] = acc[ni][r];
  if (lr == 0){
    #pragma unroll
    for (int r=0; r<4; r++) S[4096 + j + r] = acc[4][r];
  }
}

// ---------------- exclusive prefix over chunks ----------------
__global__ __launch_bounds__(256) void prefix_kernel(const float* __restrict__ Ssum,
    float* __restrict__ Spre){
  int bh = blockIdx.x; int t = threadIdx.x;
  size_t base = (size_t)bh*NCc*4160;
  for (int e=t; e<4160; e+=256){
    float acc = 0.f;
    #pragma unroll
    for (int c=0;c<NCc;c++){
      Spre[base + (size_t)c*4160 + e] = acc;
      acc += Ssum[base + (size_t)c*4160 + e];
    }
  }
}

// ---------------- per-chunk causal attention via MFMA ----------------
__global__ __launch_bounds__(256, 2) void attnout_kernel(const unsigned short* __restrict__ qkv,
    const float* __restrict__ Spre, unsigned short* __restrict__ attn){
  __shared__ __align__(16) unsigned short SpT[64][72];     // Spre^T[e][j] bf16
  __shared__ __align__(16) unsigned short Ks[64][72];      // K[m][d]
  __shared__ __align__(16) unsigned short Vt[64][72];      // V^T[d][m]
  __shared__ __align__(16) unsigned short P[4][64][72];    // per-wave masked S bf16
  __shared__ float qZd[256];
  int c = blockIdx.x, bh = blockIdx.y;
  int b = bh >> 4, h = bh & 15;
  int tid = threadIdx.x, lane = tid & 63, wave = tid >> 6;
  int lr = lane & 15, lg = lane >> 4;
  const float* Sp = Spre + ((size_t)bh*NCc + c)*4160;

  {
    float zacc = 0.f;
    const unsigned short* qp = qkv + ((size_t)(b*Ll + c*CHk + tid))*3072 + (size_t)h*64;
    #pragma unroll
    for (int g8=0; g8<8; g8++){
      bf16x8 qv = *(const bf16x8*)(qp + g8*8);
      #pragma unroll
      for (int u=0; u<8; u++) zacc += bf2f((unsigned short)qv[u]) * Sp[4096 + g8*8 + u];
    }
    qZd[tid] = zacc;
  }
  #pragma unroll
  for (int i=0; i<2; i++){
    int tau = tid + i*256;
    int j = tau & 63, dg = (tau >> 6) * 8;
    const float* sp = Sp + j*64 + dg;
    #pragma unroll
    for (int u=0; u<8; u++) SpT[dg+u][j] = f2bf(sp[u]);
  }
  bf16x8 af[4][2];
  #pragma unroll
  for (int mi=0; mi<4; mi++){
    size_t qrow = ((size_t)(b*Ll + c*CHk + wave*64 + mi*16 + lr))*3072 + (size_t)h*64;
    #pragma unroll
    for (int kk=0; kk<2; kk++)
      af[mi][kk] = *(const bf16x8*)(qkv + qrow + kk*32 + lg*8);
  }
  __syncthreads();
  f32x4 accO[4][4] = {};
  #pragma unroll
  for (int kk=0; kk<2; kk++){
    #pragma unroll
    for (int ni=0; ni<4; ni++){
      bf16x8 bsp = *(const bf16x8*)&SpT[ni*16 + lr][kk*32 + lg*8];
      #pragma unroll
      for (int mi=0; mi<4; mi++)
        accO[mi][ni] = __builtin_amdgcn_mfma_f32_16x16x32_bf16(af[mi][kk], bsp, accO[mi][ni], 0,0,0);
    }
  }
  f32x4 den4[4] = {};
  for (int t=0; t<4; ++t){
    __syncthreads();
    #pragma unroll
    for (int i=0; i<2; i++){
      int tau = tid + i*256;
      int m = tau & 63, dg = (tau >> 6) * 8;
      size_t g = ((size_t)(b*Ll + c*CHk + t*64 + m))*3072 + h*64 + dg;
      *(bf16x8*)&Ks[m][dg] = *(const bf16x8*)(qkv + g + 1024);
      bf16x8 vv = *(const bf16x8*)(qkv + g + 2048);
      #pragma unroll
      for (int u=0; u<8; u++) Vt[dg+u][m] = (unsigned short)vv[u];
    }
    __syncthreads();
    if (wave < t) continue;
    f32x4 sacc[4][4] = {};
    #pragma unroll
    for (int kk=0; kk<2; kk++){
      #pragma unroll
      for (int ni=0; ni<4; ni++){
        bf16x8 kf = *(const bf16x8*)&Ks[ni*16 + lr][kk*32 + lg*8];
        #pragma unroll
        for (int mi=0; mi<4; mi++)
          sacc[mi][ni] = __builtin_amdgcn_mfma_f32_16x16x32_bf16(af[mi][kk], kf, sacc[mi][ni], 0,0,0);
      }
    }
    unsigned short (*Pw)[72] = P[wave];
    bool diag = (t == wave);
    #pragma unroll
    for (int mi=0; mi<4; mi++){
      #pragma unroll
      for (int r=0; r<4; r++){
        int q_l = mi*16 + lg*4 + r;
        float rs = 0.f;
        #pragma unroll
        for (int ni=0; ni<4; ni++){
          int m_l = ni*16 + lr;
          float v = sacc[mi][ni][r];
          if (diag && m_l > q_l) v = 0.f;
          rs += v;
          Pw[q_l][m_l] = f2bf(v);
        }
        rs += __shfl_xor(rs, 1);
        rs += __shfl_xor(rs, 2);
        rs += __shfl_xor(rs, 4);
        rs += __shfl_xor(rs, 8);
        den4[mi][r] += rs;
      }
    }
    #pragma unroll
    for (int kk=0; kk<2; kk++){
      bf16x8 pa[4], vf[4];
      #pragma unroll
      for (int mi=0; mi<4; mi++) pa[mi] = *(const bf16x8*)&Pw[mi*16 + lr][kk*32 + lg*8];
      #pragma unroll
      for (int ni=0; ni<4; ni++) vf[ni] = *(const bf16x8*)&Vt[ni*16 + lr][kk*32 + lg*8];
      #pragma unroll
      for (int mi=0; mi<4; mi++)
        #pragma unroll
        for (int ni=0; ni<4; ni++)
          accO[mi][ni] = __builtin_amdgcn_mfma_f32_16x16x32_bf16(pa[mi], vf[ni], accO[mi][ni], 0,0,0);
    }
  }
  #pragma unroll
  for (int mi=0; mi<4; mi++){
    #pragma unroll
    for (int r=0; r<4; r++){
      int q_l = mi*16 + lg*4 + r;
      float dtot = den4[mi][r] + qZd[wave*64 + q_l];
      float inv = 1.f / fmaxf(dtot, 1e-6f);
      size_t l = (size_t)(b*Ll + c*CHk + wave*64 + q_l);
      unsigned short* op = attn + l*Ee + h*64 + lr;
      #pragma unroll
      for (int ni=0; ni<4; ni++)
        op[ni*16] = f2bf(accO[mi][ni][r] * inv);
    }
  }
}

// ---------------- column mean over L, deterministic 2-stage ----------------
__global__ __launch_bounds__(256) void colmean1_kernel(const unsigned short* __restrict__ h2,
    float* __restrict__ partial){
  int e = blockIdx.x*256 + threadIdx.x;
  int ly = blockIdx.y;
  int b = blockIdx.z;
  int l0 = ly * 128;
  float s = 0.f;
  for (int l=l0; l<l0+128; l++) s += bf2f(h2[((size_t)(b*Ll + l))*Ee + e]);
  partial[((size_t)(b*32 + ly))*Ee + e] = s;
}
__global__ __launch_bounds__(256) void colmean2_kernel(const float* __restrict__ partial,
    float* __restrict__ xmean){
  int e = blockIdx.x*256 + threadIdx.x;
  int b = blockIdx.y;
  float s = 0.f;
  #pragma unroll
  for (int ly=0; ly<32; ly++) s += partial[((size_t)(b*32 + ly))*Ee + e];
  xmean[b*Ee + e] = s * (1.f/Ll);
}

// ---------------- dim predictor -> floored size ----------------
__global__ __launch_bounds__(256) void dimpred_kernel(const float* __restrict__ xmean,
    const float* __restrict__ w_dp1, const float* __restrict__ w_dp2,
    float* __restrict__ scalars){
  __shared__ float red[256];
  __shared__ float ratio_s[2];
  int t = threadIdx.x;
  for (int b=0;b<2;b++){
    float s = 0.f;
    for (int k=0;k<1024;k++) s += xmean[b*Ee + k] * w_dp1[k*256 + t];
    float sil = s * (1.f/(1.f+expf(-s)));
    red[t] = sil * w_dp2[t];
    __syncthreads();
    for (int off=128; off>0; off>>=1){
      if (t<off) red[t] += red[t+off];
      __syncthreads();
    }
    if (t==0){
      float dr = 1.f/(1.f+expf(-red[0]));
      float ratio = 1.f + (dr-0.5f)*1.0f;       // 2*ADAPT = 1
      ratio = fminf(fmaxf(ratio, 0.5f), 1.5f);
      ratio_s[b] = ratio;
    }
    __syncthreads();
  }
  if (t==0){
    float rm = 0.5f*(ratio_s[0]+ratio_s[1]);
    float size_f = floorf(3072.f * rm);
    if (size_f < 1.f) size_f = 1.f;
    scalars[0] = size_f;
  }
}

extern "C" void kernel_launch(void* const* d_in, const int* in_sizes, int n_in,
                              void* d_out, int out_size, void* d_ws, size_t ws_size,
                              hipStream_t stream){
  const float* x      = (const float*)d_in[0];
  const float* w_qkv  = (const float*)d_in[1];
  const float* w_out  = (const float*)d_in[2];
  const float* g1     = (const float*)d_in[3];
  const float* g2     = (const float*)d_in[4];
  const float* w_dp1  = (const float*)d_in[5];
  const float* w_dp2  = (const float*)d_in[6];
  const float* w_gate = (const float*)d_in[7];
  const float* w_up   = (const float*)d_in[8];
  const float* w_down = (const float*)d_in[9];
  const float* g_hid  = (const float*)d_in[10];
  float* out = (float*)d_out;

  char* w = (char*)d_ws;
  size_t o = 0;
  auto alloc = [&](size_t bytes)->char*{ char* p = w + o; o += (bytes + 255) & ~255ull; return p; };
  unsigned short* R1   = (unsigned short*)alloc((size_t)8192*1024*2);   // h/attn/h2 bf16
  float*          x2   = (float*)alloc((size_t)8192*1024*4);            // post-attn residual fp32
  char*           R2   = alloc((size_t)8192*4608*2);                    // qkv bf16 then hidden
  unsigned short* qkvT = (unsigned short*)alloc((size_t)3072*1024*2);
  unsigned short* outT = (unsigned short*)alloc((size_t)1024*1024*2);
  char*           W2   = alloc((size_t)3*4608*1024*2);                  // Ssum/Spre then gateT/upT/downT
  float*       partial = (float*)alloc((size_t)64*1024*4);
  float*         xmean = (float*)alloc(2048*4);
  float*          scal = (float*)alloc(64);
  float*         sumsq = (float*)alloc(8192*4);

  unsigned short* qkv    = (unsigned short*)R2;
  unsigned short* hidden = (unsigned short*)R2;
  float* Ssum = (float*)W2;
  float* Spre = Ssum + (size_t)512*4160;
  unsigned short* gateT = (unsigned short*)W2;
  unsigned short* upT   = gateT + (size_t)4608*1024;
  unsigned short* downT = upT   + (size_t)4608*1024;

  wconv_kernel<<<dim3(3072/64, 1024/64),256,0,stream>>>(w_qkv, qkvT, 1024, 3072, nullptr);
  wconv_kernel<<<dim3(1024/64, 1024/64),256,0,stream>>>(w_out, outT, 1024, 1024, nullptr);

  rmsnorm_kernel<<<8192,256,0,stream>>>(x, g1, R1);
  gemm_kernel<0><<<dim3(3072/128, 8192/256),512,0,stream>>>(R1, qkvT, qkv,
      8192,3072,1024, nullptr,nullptr,nullptr);
  rope_kernel<<<16384,256,0,stream>>>(qkv);
  chunksum_kernel<<<dim3(NCc,Bb*Hh),256,0,stream>>>(qkv, Ssum);
  prefix_kernel<<<Bb*Hh,256,0,stream>>>(Ssum, Spre);
  attnout_kernel<<<dim3(NCc,Bb*Hh),256,0,stream>>>(qkv, Spre, R1);

  wconv_kernel<<<dim3(4608/64, 1024/64),256,0,stream>>>(w_gate, gateT, 1024, 4608, nullptr);
  wconv_kernel<<<dim3(4608/64, 1024/64),256,0,stream>>>(w_up,   upT,   1024, 4608, nullptr);
  wconv_kernel<<<dim3(1024/64, 4608/64),256,0,stream>>>(w_down, downT, 4608, 1024, g_hid);

  gemm_kernel<1><<<dim3(1024/128, 8192/256),512,0,stream>>>(R1, outT, x2,
      8192,1024,1024, x,nullptr,nullptr);
  rmsnorm_kernel<<<8192,256,0,stream>>>(x2, g2, R1);
  colmean1_kernel<<<dim3(4,32,2),256,0,stream>>>(R1, partial);
  colmean2_kernel<<<dim3(4,2),256,0,stream>>>(partial, xmean);
  dimpred_kernel<<<1,256,0,stream>>>(xmean, w_dp1, w_dp2, scal);
  hipMemsetAsync(sumsq, 0, 8192*sizeof(float), stream);
  gateup_kernel<<<dim3(4608/128, 8192/256),512,0,stream>>>(R1, gateT, upT, hidden, scal, sumsq);
  gemm_kernel<2><<<dim3(1024/128, 8192/256),512,0,stream>>>(hidden, downT, out,
      8192,1024,4608, x2, sumsq, scal);
}

// Round 10
// 482.603 us; speedup vs baseline: 2.7253x; 1.0138x over previous
//
#include <hip/hip_runtime.h>
#include <hip/hip_bf16.h>

#define Ee 1024
#define Hh 16
#define Ff 4608
#define Ll 4096
#define Bb 2
#define NCc 16
#define CHk 256

typedef short bf16x8 __attribute__((ext_vector_type(8)));
typedef float f32x4 __attribute__((ext_vector_type(4)));

#define GLD16(g, l) __builtin_amdgcn_global_load_lds( \
    (const __attribute__((address_space(1))) unsigned int*)(g), \
    (__attribute__((address_space(3))) unsigned int*)(l), 16, 0, 0)
#define SCHED0() __builtin_amdgcn_sched_barrier(0)
#define SBAR()   __builtin_amdgcn_s_barrier()

__device__ __forceinline__ unsigned short f2bf(float f){
  unsigned int u = __builtin_bit_cast(unsigned int, f);
  u += 0x7fffu + ((u >> 16) & 1u);
  return (unsigned short)(u >> 16);
}
__device__ __forceinline__ float bf2f(unsigned short h){
  unsigned int u = ((unsigned int)h) << 16;
  return __builtin_bit_cast(float, u);
}
__device__ __forceinline__ float fixv(float v){
  return (__builtin_isnan(v) || __builtin_isinf(v)) ? 0.f : v;
}

// ---------------- weight convert+transpose: W[K][N] fp32 -> WT[N][K] bf16 ----------------
__global__ __launch_bounds__(256) void wconv_kernel(const float* __restrict__ W,
    unsigned short* __restrict__ WT, int K, int N, const float* __restrict__ scale){
  __shared__ unsigned short T[64][72];
  int k0 = blockIdx.y*64, n0 = blockIdx.x*64;
  int t = threadIdx.x;
  int kr = t>>4, n4 = (t&15)*4;
  #pragma unroll
  for (int it=0; it<4; it++){
    int k = kr + it*16;
    float s = scale ? scale[k0+k] : 1.f;
    float4 v = *(const float4*)(W + (size_t)(k0+k)*N + n0 + n4);
    T[n4+0][k] = f2bf(v.x*s);
    T[n4+1][k] = f2bf(v.y*s);
    T[n4+2][k] = f2bf(v.z*s);
    T[n4+3][k] = f2bf(v.w*s);
  }
  __syncthreads();
  int u = t&7;
  #pragma unroll
  for (int it=0; it<2; it++){
    int n = (t>>3) + it*32;
    *(bf16x8*)(WT + (size_t)(n0+n)*K + k0 + u*8) = *(const bf16x8*)&T[n][u*8];
  }
}

// ---------------- RMSNorm fp32 in -> bf16 out ----------------
__global__ __launch_bounds__(256) void rmsnorm_kernel(const float* __restrict__ x,
    const float* __restrict__ g, unsigned short* __restrict__ out){
  int row = blockIdx.x; int t = threadIdx.x;
  float4 v = ((const float4*)(x + (size_t)row*Ee))[t];
  v.x=fixv(v.x); v.y=fixv(v.y); v.z=fixv(v.z); v.w=fixv(v.w);
  float ss = v.x*v.x + v.y*v.y + v.z*v.z + v.w*v.w;
  #pragma unroll
  for (int off=32; off>0; off>>=1) ss += __shfl_down(ss, off);
  __shared__ float red[4];
  if ((t&63)==0) red[t>>6] = ss;
  __syncthreads();
  float tot = red[0]+red[1]+red[2]+red[3];
  float rms = sqrtf(tot*(1.f/Ee) + 1e-6f);
  rms = fminf(fmaxf(rms, 1e-6f), 1e6f);
  float inv = 1.f/rms;
  float4 gv = ((const float4*)g)[t];
  uint2 o;
  o.x = (unsigned)f2bf(v.x*inv*gv.x) | ((unsigned)f2bf(v.y*inv*gv.y)<<16);
  o.y = (unsigned)f2bf(v.z*inv*gv.z) | ((unsigned)f2bf(v.w*inv*gv.w)<<16);
  ((uint2*)(out + (size_t)row*Ee))[t] = o;
}

// ---------------- bf16 GEMM: C[M,N] = A[M,K] @ Bt[N,K]^T ----------------
// 256x128 tile, 512 thr, BK=32, 3-buffer LDS rotation (72KB) with COUNTED vmcnt
// across raw s_barrier (never drains prefetch in main loop).
// MODE 0: C bf16. MODE 1: C fp32 = acc + res.
// MODE 2: C fp32 = acc*inv_rms(sumsq[row], klim[0]) + res; K truncated to round32(klim[0]).
template<int MODE>
__global__ __launch_bounds__(512) void gemm_kernel(
    const unsigned short* __restrict__ A, const unsigned short* __restrict__ Bt,
    void* __restrict__ Cv, int M, int N, int K,
    const float* __restrict__ res, const float* __restrict__ rowscale,
    const float* __restrict__ klim){
  __shared__ __align__(16) unsigned short S[36864];   // 3 bufs x 12288 (A 8192 | B 4096)
  int tid = threadIdx.x;
  int nbx = gridDim.x;
  int id = blockIdx.y * nbx + blockIdx.x;
  int chunk = (nbx * gridDim.y) >> 3;
  int wg = (id & 7) * chunk + (id >> 3);
  int m0 = (wg / nbx) * 256, n0 = (wg % nbx) * 128;
  int lane = tid & 63, wave = tid >> 6;
  int wm = (wave>>1)*64, wn = (wave&1)*64;
  int lrow = lane & 15;
  int lksw = (((lane>>4) ^ ((lrow>>1)&3)))*8;
  float klim0 = (MODE==2 && klim) ? klim[0] : 0.f;
  int kend = K;
  if (MODE==2 && klim){
    int sz = (int)klim0;
    int ke = ((sz + 31) >> 5) << 5;
    kend = ke < K ? ke : K;
  }
  int nk = kend >> 5;
  int segr = lane >> 2;
  int cg = (((lane&3) ^ ((lane>>3)&3))) * 8;
  const unsigned short* gp[3];
  int loff[3];
  #pragma unroll
  for (int i=0;i<3;i++){
    int g = wave*3 + i;
    if (g < 16){ gp[i] = A  + (size_t)(m0 + g*16 + segr)*K + cg;       loff[i] = g*512; }
    else       { gp[i] = Bt + (size_t)(n0 + (g-16)*16 + segr)*K + cg;  loff[i] = 8192 + (g-16)*512; }
  }
  f32x4 acc[4][4] = {};
  // prologue: stage t=0 -> buf0, t=1 -> buf1
  #pragma unroll
  for (int i=0;i<3;i++) GLD16(gp[i], &S[loff[i]]);
  if (nk > 1){
    #pragma unroll
    for (int i=0;i<3;i++) GLD16(gp[i]+32, &S[12288 + loff[i]]);
  }
  SCHED0();
  if (nk > 1) asm volatile("s_waitcnt vmcnt(3)" ::: "memory");
  else        asm volatile("s_waitcnt vmcnt(0)" ::: "memory");
  SBAR(); SCHED0();
  int cur = 0;
  for (int t=0; t<nk; ++t){
    if (t+2 < nk){
      int stg = cur+2; if (stg>=3) stg-=3;
      int ko = (t+2) << 5;
      #pragma unroll
      for (int i=0;i<3;i++) GLD16(gp[i]+ko, &S[stg*12288 + loff[i]]);
    }
    int base = cur*12288;
    bf16x8 af[4], bfr[4];
    #pragma unroll
    for (int i=0;i<4;i++){
      af[i]  = *(const bf16x8*)&S[base + (wm + i*16 + lrow)*32 + lksw];
      bfr[i] = *(const bf16x8*)&S[base + 8192 + (wn + i*16 + lrow)*32 + lksw];
    }
    __builtin_amdgcn_s_setprio(1);
    #pragma unroll
    for (int mi=0;mi<4;mi++)
      #pragma unroll
      for (int ni=0;ni<4;ni++)
        acc[mi][ni] = __builtin_amdgcn_mfma_f32_16x16x32_bf16(af[mi], bfr[ni], acc[mi][ni], 0,0,0);
    __builtin_amdgcn_s_setprio(0);
    if (t+1 < nk){
      SCHED0();
      if (t+2 < nk) asm volatile("s_waitcnt vmcnt(3)" ::: "memory");
      else          asm volatile("s_waitcnt vmcnt(0)" ::: "memory");
      SBAR(); SCHED0();
    }
    cur = (cur==2) ? 0 : cur+1;
  }
  int lg = lane >> 4;
  int rbase = m0 + wm + (lg<<2);
  int cbase = n0 + wn + lrow;
  #pragma unroll
  for (int mi=0;mi<4;mi++){
    #pragma unroll
    for (int r=0;r<4;r++){
      int row = rbase + mi*16 + r;
      float rs = 1.f;
      if (MODE==2){
        float rms = sqrtf(rowscale[row]/klim0 + 1e-6f);
        rms = fminf(fmaxf(rms, 1e-6f), 1e6f);
        rs = 1.f/rms;
      }
      #pragma unroll
      for (int ni=0;ni<4;ni++){
        int col = cbase + ni*16;
        float v = acc[mi][ni][r];
        if (MODE==0){
          ((unsigned short*)Cv)[(size_t)row*N + col] = f2bf(v);
        } else if (MODE==1){
          ((float*)Cv)[(size_t)row*N + col] = v + res[(size_t)row*N + col];
        } else {
          ((float*)Cv)[(size_t)row*N + col] = v*rs + res[(size_t)row*N + col];
        }
      }
    }
  }
}

// ---------------- fused gate+up GEMM (256x128, BK=32, 3-buffer counted vmcnt) ----------------
// hidden = silu(g)*u masked; accumulates per-row sumsq (fp32 atomics).
__global__ __launch_bounds__(512) void gateup_kernel(
    const unsigned short* __restrict__ A, const unsigned short* __restrict__ Gt,
    const unsigned short* __restrict__ Ut, unsigned short* __restrict__ Hid,
    const float* __restrict__ scal, float* __restrict__ sumsq){
  __shared__ __align__(16) unsigned short S[49152];  // 3 bufs x 16384 (A 8192|G 4096|U 4096)
  int tid = threadIdx.x;
  int nbx = gridDim.x;
  int id = blockIdx.y * nbx + blockIdx.x;
  int chunk = (nbx * gridDim.y) >> 3;
  int wg = (id & 7) * chunk + (id >> 3);
  int m0 = (wg / nbx) * 256, n0 = (wg % nbx) * 128;
  int size = (int)scal[0];
  if (n0 >= size){
    int r = tid >> 1, cb = n0 + (tid&1)*64;
    unsigned short* hp = Hid + (size_t)(m0+r)*Ff + cb;
    bf16x8 z = {};
    #pragma unroll
    for (int i=0;i<8;i++) *(bf16x8*)(hp + i*8) = z;
    return;
  }
  int lane = tid & 63, wave = tid >> 6;
  int wm = (wave>>1)*64, wn = (wave&1)*64;
  int lrow = lane & 15;
  int lksw = (((lane>>4) ^ ((lrow>>1)&3)))*8;
  int segr = lane >> 2;
  int cg = (((lane&3) ^ ((lane>>3)&3))) * 8;
  const unsigned short* gp[4];
  int loff[4];
  #pragma unroll
  for (int i=0;i<4;i++){
    int g = wave*4 + i;
    if (g < 16)      { gp[i] = A  + (size_t)(m0 + g*16 + segr)*Ee + cg;       loff[i] = g*512; }
    else if (g < 24) { gp[i] = Gt + (size_t)(n0 + (g-16)*16 + segr)*Ee + cg;  loff[i] = 8192 + (g-16)*512; }
    else             { gp[i] = Ut + (size_t)(n0 + (g-24)*16 + segr)*Ee + cg;  loff[i] = 12288 + (g-24)*512; }
  }
  f32x4 ag[4][4] = {}, au[4][4] = {};
  #pragma unroll
  for (int i=0;i<4;i++) GLD16(gp[i], &S[loff[i]]);
  #pragma unroll
  for (int i=0;i<4;i++) GLD16(gp[i]+32, &S[16384 + loff[i]]);
  SCHED0();
  asm volatile("s_waitcnt vmcnt(4)" ::: "memory");
  SBAR(); SCHED0();
  int cur = 0;
  for (int t=0; t<32; ++t){
    if (t+2 < 32){
      int stg = cur+2; if (stg>=3) stg-=3;
      int ko = (t+2) << 5;
      #pragma unroll
      for (int i=0;i<4;i++) GLD16(gp[i]+ko, &S[stg*16384 + loff[i]]);
    }
    int base = cur*16384;
    bf16x8 af[4], bg4[4], bu4[4];
    #pragma unroll
    for (int i=0;i<4;i++){
      af[i]  = *(const bf16x8*)&S[base + (wm + i*16 + lrow)*32 + lksw];
      bg4[i] = *(const bf16x8*)&S[base + 8192  + (wn + i*16 + lrow)*32 + lksw];
      bu4[i] = *(const bf16x8*)&S[base + 12288 + (wn + i*16 + lrow)*32 + lksw];
    }
    __builtin_amdgcn_s_setprio(1);
    #pragma unroll
    for (int mi=0;mi<4;mi++)
      #pragma unroll
      for (int ni=0;ni<4;ni++){
        ag[mi][ni] = __builtin_amdgcn_mfma_f32_16x16x32_bf16(af[mi], bg4[ni], ag[mi][ni], 0,0,0);
        au[mi][ni] = __builtin_amdgcn_mfma_f32_16x16x32_bf16(af[mi], bu4[ni], au[mi][ni], 0,0,0);
      }
    __builtin_amdgcn_s_setprio(0);
    if (t+1 < 32){
      SCHED0();
      if (t+2 < 32) asm volatile("s_waitcnt vmcnt(4)" ::: "memory");
      else          asm volatile("s_waitcnt vmcnt(0)" ::: "memory");
      SBAR(); SCHED0();
    }
    cur = (cur==2) ? 0 : cur+1;
  }
  int lg = lane >> 4;
  int lr = lrow;
  int rbase = m0 + wm + (lg<<2);
  int cbase = n0 + wn + lr;
  #pragma unroll
  for (int mi=0;mi<4;mi++){
    #pragma unroll
    for (int r=0;r<4;r++){
      int row = rbase + mi*16 + r;
      float s4 = 0.f;
      #pragma unroll
      for (int ni=0;ni<4;ni++){
        int col = cbase + ni*16;
        float g = ag[mi][ni][r], u = au[mi][ni][r];
        float hv = (g * (1.f/(1.f+expf(-g)))) * u;
        if (col >= size) hv = 0.f;
        if (__builtin_isnan(hv) || __builtin_isinf(hv)) hv = 0.f;
        Hid[(size_t)row*Ff + col] = f2bf(hv);
        s4 += hv*hv;
      }
      s4 += __shfl_xor(s4, 1);
      s4 += __shfl_xor(s4, 2);
      s4 += __shfl_xor(s4, 4);
      s4 += __shfl_xor(s4, 8);
      if (lr == 0) atomicAdd(&sumsq[row], s4);
    }
  }
}

// ---------------- RoPE + ELU+1 on q,k in bf16 qkv ----------------
__global__ __launch_bounds__(256) void rope_kernel(unsigned short* __restrict__ qkv){
  size_t idx = (size_t)blockIdx.x*256 + threadIdx.x;    // B*L*H*32
  int i = (int)(idx & 31);
  int h = (int)((idx>>5) & 15);
  size_t bl = idx >> 9;
  int pos = (int)(bl & (Ll-1));
  int d0 = 2*i, d1 = d0+1;
  size_t base = bl*3072 + (size_t)h*64 + d0;
  const float LOG1E4_D32 = 0.2878231366242557f;  // ln(10000)/32
  float e0 = (float)(d0 < 32 ? d0 : d0-32);
  float e1 = (float)(d1 < 32 ? d1 : d1-32);
  float f0 = pos * expf(-e0*LOG1E4_D32);
  float f1 = pos * expf(-e1*LOG1E4_D32);
  float s0,c0,s1,c1;
  sincosf(f0,&s0,&c0); sincosf(f1,&s1,&c1);
  unsigned int* qp = (unsigned int*)(qkv + base);
  unsigned int qv = *qp;
  float q0 = bf2f((unsigned short)(qv&0xffff)), q1 = bf2f((unsigned short)(qv>>16));
  float r0 = q0*c0 - q1*s0;
  float r1 = q1*c1 + q0*s1;
  r0 = r0>0.f ? r0+1.f : expf(r0);
  r1 = r1>0.f ? r1+1.f : expf(r1);
  *qp = (unsigned)f2bf(r0) | ((unsigned)f2bf(r1)<<16);
  unsigned int* kp = (unsigned int*)(qkv + base + 1024);
  unsigned int kv = *kp;
  float k0v = bf2f((unsigned short)(kv&0xffff)), k1v = bf2f((unsigned short)(kv>>16));
  float t0 = k0v*c0 - k1v*s0;
  float t1 = k1v*c1 + k0v*s1;
  t0 = t0>0.f ? t0+1.f : expf(t0);
  t1 = t1>0.f ? t1+1.f : expf(t1);
  *kp = (unsigned)f2bf(t0) | ((unsigned)f2bf(t1)<<16);
}

// ---------------- per-chunk K^T V + K col sums via MFMA (ones-column trick) ----------------
__global__ __launch_bounds__(256) void chunksum_kernel(const unsigned short* __restrict__ qkv,
    float* __restrict__ Ssum){
  __shared__ __align__(16) unsigned short Kt[64][72];   // K^T[j][m]
  __shared__ __align__(16) unsigned short Vt[80][72];   // V^T[e][m]; row64=1.0, 65..79=0
  int c = blockIdx.x, bh = blockIdx.y;
  int b = bh >> 4, h = bh & 15;
  int tid = threadIdx.x, lane = tid & 63, wave = tid >> 6;
  int lr = lane & 15, lg = lane >> 4;
  f32x4 acc[5] = {};
  {
    int r16 = tid >> 4, m4 = (tid & 15) * 4;
    unsigned short val = (r16 == 0) ? (unsigned short)0x3F80 : (unsigned short)0;
    #pragma unroll
    for (int u=0; u<4; u++) Vt[64 + r16][m4 + u] = val;
  }
  for (int t=0; t<4; ++t){
    __syncthreads();
    #pragma unroll
    for (int i=0; i<2; i++){
      int tau = tid + i*256;
      int m = tau & 63, dg = (tau >> 6) * 8;
      size_t g = ((size_t)(b*Ll + c*CHk + t*64 + m))*3072 + h*64 + dg;
      bf16x8 kv = *(const bf16x8*)(qkv + g + 1024);
      bf16x8 vv = *(const bf16x8*)(qkv + g + 2048);
      #pragma unroll
      for (int u=0; u<8; u++){
        Kt[dg+u][m] = (unsigned short)kv[u];
        Vt[dg+u][m] = (unsigned short)vv[u];
      }
    }
    __syncthreads();
    #pragma unroll
    for (int kk=0; kk<2; kk++){
      bf16x8 af = *(const bf16x8*)&Kt[wave*16 + lr][kk*32 + lg*8];
      #pragma unroll
      for (int ni=0; ni<5; ni++){
        bf16x8 vf = *(const bf16x8*)&Vt[ni*16 + lr][kk*32 + lg*8];
        acc[ni] = __builtin_amdgcn_mfma_f32_16x16x32_bf16(af, vf, acc[ni], 0,0,0);
      }
    }
  }
  float* S = Ssum + ((size_t)bh*NCc + c)*4160;
  int j = wave*16 + lg*4;
  #pragma unroll
  for (int ni=0; ni<4; ni++)
    #pragma unroll
    for (int r=0; r<4; r++)
      S[(size_t)(j+r)*64 + ni*16 + lr] = acc[ni][r];
  if (lr == 0){
    #pragma unroll
    for (int r=0; r<4; r++) S[4096 + j + r] = acc[4][r];
  }
}

// ---------------- exclusive prefix over chunks ----------------
__global__ __launch_bounds__(256) void prefix_kernel(const float* __restrict__ Ssum,
    float* __restrict__ Spre){
  int bh = blockIdx.x; int t = threadIdx.x;
  size_t base = (size_t)bh*NCc*4160;
  for (int e=t; e<4160; e+=256){
    float acc = 0.f;
    #pragma unroll
    for (int c=0;c<NCc;c++){
      Spre[base + (size_t)c*4160 + e] = acc;
      acc += Ssum[base + (size_t)c*4160 + e];
    }
  }
}

// ---------------- per-chunk causal attention via MFMA ----------------
__global__ __launch_bounds__(256, 2) void attnout_kernel(const unsigned short* __restrict__ qkv,
    const float* __restrict__ Spre, unsigned short* __restrict__ attn){
  __shared__ __align__(16) unsigned short SpT[64][72];     // Spre^T[e][j] bf16
  __shared__ __align__(16) unsigned short Ks[64][72];      // K[m][d]
  __shared__ __align__(16) unsigned short Vt[64][72];      // V^T[d][m]
  __shared__ __align__(16) unsigned short P[4][64][72];    // per-wave masked S bf16
  __shared__ float qZd[256];
  int c = blockIdx.x, bh = blockIdx.y;
  int b = bh >> 4, h = bh & 15;
  int tid = threadIdx.x, lane = tid & 63, wave = tid >> 6;
  int lr = lane & 15, lg = lane >> 4;
  const float* Sp = Spre + ((size_t)bh*NCc + c)*4160;

  {
    float zacc = 0.f;
    const unsigned short* qp = qkv + ((size_t)(b*Ll + c*CHk + tid))*3072 + (size_t)h*64;
    #pragma unroll
    for (int g8=0; g8<8; g8++){
      bf16x8 qv = *(const bf16x8*)(qp + g8*8);
      #pragma unroll
      for (int u=0; u<8; u++) zacc += bf2f((unsigned short)qv[u]) * Sp[4096 + g8*8 + u];
    }
    qZd[tid] = zacc;
  }
  #pragma unroll
  for (int i=0; i<2; i++){
    int tau = tid + i*256;
    int j = tau & 63, dg = (tau >> 6) * 8;
    const float* sp = Sp + j*64 + dg;
    #pragma unroll
    for (int u=0; u<8; u++) SpT[dg+u][j] = f2bf(sp[u]);
  }
  bf16x8 af[4][2];
  #pragma unroll
  for (int mi=0; mi<4; mi++){
    size_t qrow = ((size_t)(b*Ll + c*CHk + wave*64 + mi*16 + lr))*3072 + (size_t)h*64;
    #pragma unroll
    for (int kk=0; kk<2; kk++)
      af[mi][kk] = *(const bf16x8*)(qkv + qrow + kk*32 + lg*8);
  }
  __syncthreads();
  f32x4 accO[4][4] = {};
  #pragma unroll
  for (int kk=0; kk<2; kk++){
    #pragma unroll
    for (int ni=0; ni<4; ni++){
      bf16x8 bsp = *(const bf16x8*)&SpT[ni*16 + lr][kk*32 + lg*8];
      #pragma unroll
      for (int mi=0; mi<4; mi++)
        accO[mi][ni] = __builtin_amdgcn_mfma_f32_16x16x32_bf16(af[mi][kk], bsp, accO[mi][ni], 0,0,0);
    }
  }
  f32x4 den4[4] = {};
  for (int t=0; t<4; ++t){
    __syncthreads();
    #pragma unroll
    for (int i=0; i<2; i++){
      int tau = tid + i*256;
      int m = tau & 63, dg = (tau >> 6) * 8;
      size_t g = ((size_t)(b*Ll + c*CHk + t*64 + m))*3072 + h*64 + dg;
      *(bf16x8*)&Ks[m][dg] = *(const bf16x8*)(qkv + g + 1024);
      bf16x8 vv = *(const bf16x8*)(qkv + g + 2048);
      #pragma unroll
      for (int u=0; u<8; u++) Vt[dg+u][m] = (unsigned short)vv[u];
    }
    __syncthreads();
    if (wave < t) continue;
    f32x4 sacc[4][4] = {};
    #pragma unroll
    for (int kk=0; kk<2; kk++){
      #pragma unroll
      for (int ni=0; ni<4; ni++){
        bf16x8 kf = *(const bf16x8*)&Ks[ni*16 + lr][kk*32 + lg*8];
        #pragma unroll
        for (int mi=0; mi<4; mi++)
          sacc[mi][ni] = __builtin_amdgcn_mfma_f32_16x16x32_bf16(af[mi][kk], kf, sacc[mi][ni], 0,0,0);
      }
    }
    unsigned short (*Pw)[72] = P[wave];
    bool diag = (t == wave);
    #pragma unroll
    for (int mi=0; mi<4; mi++){
      #pragma unroll
      for (int r=0; r<4; r++){
        int q_l = mi*16 + lg*4 + r;
        float rs = 0.f;
        #pragma unroll
        for (int ni=0; ni<4; ni++){
          int m_l = ni*16 + lr;
          float v = sacc[mi][ni][r];
          if (diag && m_l > q_l) v = 0.f;
          rs += v;
          Pw[q_l][m_l] = f2bf(v);
        }
        rs += __shfl_xor(rs, 1);
        rs += __shfl_xor(rs, 2);
        rs += __shfl_xor(rs, 4);
        rs += __shfl_xor(rs, 8);
        den4[mi][r] += rs;
      }
    }
    #pragma unroll
    for (int kk=0; kk<2; kk++){
      bf16x8 pa[4], vf[4];
      #pragma unroll
      for (int mi=0; mi<4; mi++) pa[mi] = *(const bf16x8*)&Pw[mi*16 + lr][kk*32 + lg*8];
      #pragma unroll
      for (int ni=0; ni<4; ni++) vf[ni] = *(const bf16x8*)&Vt[ni*16 + lr][kk*32 + lg*8];
      #pragma unroll
      for (int mi=0; mi<4; mi++)
        #pragma unroll
        for (int ni=0; ni<4; ni++)
          accO[mi][ni] = __builtin_amdgcn_mfma_f32_16x16x32_bf16(pa[mi], vf[ni], accO[mi][ni], 0,0,0);
    }
  }
  #pragma unroll
  for (int mi=0; mi<4; mi++){
    #pragma unroll
    for (int r=0; r<4; r++){
      int q_l = mi*16 + lg*4 + r;
      float dtot = den4[mi][r] + qZd[wave*64 + q_l];
      float inv = 1.f / fmaxf(dtot, 1e-6f);
      size_t l = (size_t)(b*Ll + c*CHk + wave*64 + q_l);
      unsigned short* op = attn + l*Ee + h*64 + lr;
      #pragma unroll
      for (int ni=0; ni<4; ni++)
        op[ni*16] = f2bf(accO[mi][ni][r] * inv);
    }
  }
}

// ---------------- column mean over L, deterministic 2-stage ----------------
__global__ __launch_bounds__(256) void colmean1_kernel(const unsigned short* __restrict__ h2,
    float* __restrict__ partial){
  int e = blockIdx.x*256 + threadIdx.x;
  int ly = blockIdx.y;
  int b = blockIdx.z;
  int l0 = ly * 128;
  float s = 0.f;
  for (int l=l0; l<l0+128; l++) s += bf2f(h2[((size_t)(b*Ll + l))*Ee + e]);
  partial[((size_t)(b*32 + ly))*Ee + e] = s;
}
__global__ __launch_bounds__(256) void colmean2_kernel(const float* __restrict__ partial,
    float* __restrict__ xmean){
  int e = blockIdx.x*256 + threadIdx.x;
  int b = blockIdx.y;
  float s = 0.f;
  #pragma unroll
  for (int ly=0; ly<32; ly++) s += partial[((size_t)(b*32 + ly))*Ee + e];
  xmean[b*Ee + e] = s * (1.f/Ll);
}

// ---------------- dim predictor -> floored size ----------------
__global__ __launch_bounds__(256) void dimpred_kernel(const float* __restrict__ xmean,
    const float* __restrict__ w_dp1, const float* __restrict__ w_dp2,
    float* __restrict__ scalars){
  __shared__ float red[256];
  __shared__ float ratio_s[2];
  int t = threadIdx.x;
  for (int b=0;b<2;b++){
    float s = 0.f;
    for (int k=0;k<1024;k++) s += xmean[b*Ee + k] * w_dp1[k*256 + t];
    float sil = s * (1.f/(1.f+expf(-s)));
    red[t] = sil * w_dp2[t];
    __syncthreads();
    for (int off=128; off>0; off>>=1){
      if (t<off) red[t] += red[t+off];
      __syncthreads();
    }
    if (t==0){
      float dr = 1.f/(1.f+expf(-red[0]));
      float ratio = 1.f + (dr-0.5f)*1.0f;       // 2*ADAPT = 1
      ratio = fminf(fmaxf(ratio, 0.5f), 1.5f);
      ratio_s[b] = ratio;
    }
    __syncthreads();
  }
  if (t==0){
    float rm = 0.5f*(ratio_s[0]+ratio_s[1]);
    float size_f = floorf(3072.f * rm);
    if (size_f < 1.f) size_f = 1.f;
    scalars[0] = size_f;
  }
}

extern "C" void kernel_launch(void* const* d_in, const int* in_sizes, int n_in,
                              void* d_out, int out_size, void* d_ws, size_t ws_size,
                              hipStream_t stream){
  const float* x      = (const float*)d_in[0];
  const float* w_qkv  = (const float*)d_in[1];
  const float* w_out  = (const float*)d_in[2];
  const float* g1     = (const float*)d_in[3];
  const float* g2     = (const float*)d_in[4];
  const float* w_dp1  = (const float*)d_in[5];
  const float* w_dp2  = (const float*)d_in[6];
  const float* w_gate = (const float*)d_in[7];
  const float* w_up   = (const float*)d_in[8];
  const float* w_down = (const float*)d_in[9];
  const float* g_hid  = (const float*)d_in[10];
  float* out = (float*)d_out;

  char* w = (char*)d_ws;
  size_t o = 0;
  auto alloc = [&](size_t bytes)->char*{ char* p = w + o; o += (bytes + 255) & ~255ull; return p; };
  unsigned short* R1   = (unsigned short*)alloc((size_t)8192*1024*2);   // h/attn/h2 bf16
  float*          x2   = (float*)alloc((size_t)8192*1024*4);            // post-attn residual fp32
  char*           R2   = alloc((size_t)8192*4608*2);                    // qkv bf16 then hidden
  unsigned short* qkvT = (unsigned short*)alloc((size_t)3072*1024*2);
  unsigned short* outT = (unsigned short*)alloc((size_t)1024*1024*2);
  char*           W2   = alloc((size_t)3*4608*1024*2);                  // Ssum/Spre then gateT/upT/downT
  float*       partial = (float*)alloc((size_t)64*1024*4);
  float*         xmean = (float*)alloc(2048*4);
  float*          scal = (float*)alloc(64);
  float*         sumsq = (float*)alloc(8192*4);

  unsigned short* qkv    = (unsigned short*)R2;
  unsigned short* hidden = (unsigned short*)R2;
  float* Ssum = (float*)W2;
  float* Spre = Ssum + (size_t)512*4160;
  unsigned short* gateT = (unsigned short*)W2;
  unsigned short* upT   = gateT + (size_t)4608*1024;
  unsigned short* downT = upT   + (size_t)4608*1024;

  wconv_kernel<<<dim3(3072/64, 1024/64),256,0,stream>>>(w_qkv, qkvT, 1024, 3072, nullptr);
  wconv_kernel<<<dim3(1024/64, 1024/64),256,0,stream>>>(w_out, outT, 1024, 1024, nullptr);

  rmsnorm_kernel<<<8192,256,0,stream>>>(x, g1, R1);
  gemm_kernel<0><<<dim3(3072/128, 8192/256),512,0,stream>>>(R1, qkvT, qkv,
      8192,3072,1024, nullptr,nullptr,nullptr);
  rope_kernel<<<16384,256,0,stream>>>(qkv);
  chunksum_kernel<<<dim3(NCc,Bb*Hh),256,0,stream>>>(qkv, Ssum);
  prefix_kernel<<<Bb*Hh,256,0,stream>>>(Ssum, Spre);
  attnout_kernel<<<dim3(NCc,Bb*Hh),256,0,stream>>>(qkv, Spre, R1);

  wconv_kernel<<<dim3(4608/64, 1024/64),256,0,stream>>>(w_gate, gateT, 1024, 4608, nullptr);
  wconv_kernel<<<dim3(4608/64, 1024/64),256,0,stream>>>(w_up,   upT,   1024, 4608, nullptr);
  wconv_kernel<<<dim3(1024/64, 4608/64),256,0,stream>>>(w_down, downT, 4608, 1024, g_hid);

  gemm_kernel<1><<<dim3(1024/128, 8192/256),512,0,stream>>>(R1, outT, x2,
      8192,1024,1024, x,nullptr,nullptr);
  rmsnorm_kernel<<<8192,256,0,stream>>>(x2, g2, R1);
  colmean1_kernel<<<dim3(4,32,2),256,0,stream>>>(R1, partial);
  colmean2_kernel<<<dim3(4,2),256,0,stream>>>(partial, xmean);
  dimpred_kernel<<<1,256,0,stream>>>(xmean, w_dp1, w_dp2, scal);
  hipMemsetAsync(sumsq, 0, 8192*sizeof(float), stream);
  gateup_kernel<<<dim3(4608/128, 8192/256),512,0,stream>>>(R1, gateT, upT, hidden, scal, sumsq);
  gemm_kernel<2><<<dim3(1024/128, 8192/256),512,0,stream>>>(hidden, downT, out,
      8192,1024,4608, x2, sumsq, scal);
}